// Round 11
// baseline (448.001 us; speedup 1.0000x reference)
//
#include <hip/hip_runtime.h>
#include <cstdint>
#include <cstddef>

typedef __bf16 bf16;
typedef __bf16 bf16x8 __attribute__((ext_vector_type(8)));
typedef float f32x4 __attribute__((ext_vector_type(4)));

#define BDIM 4
#define TDIM 2048
#define DDIM 2048
#define HDIM 8
#define DHD 256
#define MTOT 8192
#define NCHUNK 64
#define LCHUNK 32

// async 16B global->LDS; LDS dest = wave-uniform base + lane*16
__device__ __forceinline__ void stage16(const bf16* g, bf16* l) {
  __builtin_amdgcn_global_load_lds(
      (const __attribute__((address_space(1))) void*)g,
      (__attribute__((address_space(3))) void*)l, 16, 0, 0);
}

// intrinsic barrier (no implicit drain); BARE asm waitcnt (no "memory"
// clobber -> no compiler-inserted full drain; round-6 lesson).
#define BARX() __builtin_amdgcn_s_barrier()
#define SCHB() __builtin_amdgcn_sched_barrier(0)
#define WAITVM(N) asm volatile("s_waitcnt vmcnt(" #N ")")

__device__ __forceinline__ float sigmoid_f(float x) {
  return __fdividef(1.f, 1.f + __expf(-x));
}
__device__ __forceinline__ float gelu_tanh(float v) {
  float u = 0.7978845608028654f * (v + 0.044715f * v * v * v);
  u = fminf(fmaxf(u, -15.f), 15.f);
  float t = __expf(2.f * u);                       // tanh(u) = (t-1)/(t+1)
  return 0.5f * v * (1.f + __fdividef(t - 1.f, t + 1.f));
}
__device__ __forceinline__ float softplus_f(float x) {
  return __logf(1.f + __expf(x));                  // x in [-1.2, 0.4] here
}

// ---------------------------------------------------------------------------
// fp32 -> bf16 bulk convert, 8 elem/thread (count must be /2048)
// ---------------------------------------------------------------------------
__global__ __launch_bounds__(256) void f2b(const float* __restrict__ src,
                                           bf16* __restrict__ dst) {
  size_t i = ((size_t)blockIdx.x * 256 + threadIdx.x) * 8;
  const float4 a = *(const float4*)(src + i);
  const float4 b = *(const float4*)(src + i + 4);
  bf16x8 r;
  r[0] = (bf16)a.x; r[1] = (bf16)a.y; r[2] = (bf16)a.z; r[3] = (bf16)a.w;
  r[4] = (bf16)b.x; r[5] = (bf16)b.y; r[6] = (bf16)b.z; r[7] = (bf16)b.w;
  *(bf16x8*)(dst + i) = r;
}

// ---------------------------------------------------------------------------
// gemm256: round-7 kernel VERBATIM (measured 77.5 us/GEMM, best single-GEMM).
// 256x256 tile, BK=64, 8 waves, four distinct 32 KiB LDS buffers, XOR-8
// swizzle (0 conflicts), 4 phases/tile, read-ahead ping-pong frags, one
// barrier per phase, counted vmcnt(4)/(6) never draining in-loop.
// ---------------------------------------------------------------------------
template <typename TO, int EPI>
__global__ __launch_bounds__(512, 2) void gemm256(
    const bf16* __restrict__ A, const bf16* __restrict__ Bm,
    const float* __restrict__ bias, TO* __restrict__ C,
    int K, int lda, int ldb, int ldc) {
  const int gx = gridDim.x, gy = gridDim.y;
  const int nwg = gx * gy;
  const int did = blockIdx.x + gx * blockIdx.y;
  const int cpx = nwg >> 3;                       // chunk per XCD
  const int lid = (did & 7) * cpx + (did >> 3);
  const int n0 = (lid % gx) * 256;
  const int m0 = (lid / gx) * 256;

  __shared__ bf16 sA0[256 * 64];
  __shared__ bf16 sA1[256 * 64];
  __shared__ bf16 sB0[256 * 64];
  __shared__ bf16 sB1[256 * 64];
  const int tid = threadIdx.x;
  const int lane = tid & 63;
  const int wid = tid >> 6;         // 0..7
  const int wr = wid >> 2;          // M-half of tile (128 rows)
  const int wc = wid & 3;           // N-quarter (64 cols)
  const int quad = lane >> 4;
  const int l15 = lane & 15;

  const int sr = tid >> 3;                        // 0..63
  const int ks8 = ((tid & 7) ^ (sr & 7)) << 3;    // element offset in 64-wide row
  const bf16* Ag = A + (size_t)(m0 + sr) * lda + ks8;
  const bf16* Bg = Bm + (size_t)(n0 + sr) * ldb + ks8;

  const int swz0 = ((quad) ^ (l15 & 7)) << 3;
  const int swz1 = ((4 + quad) ^ (l15 & 7)) << 3;

  f32x4 acc[8][4];
#pragma unroll
  for (int i = 0; i < 8; ++i)
#pragma unroll
    for (int j = 0; j < 4; ++j)
#pragma unroll
      for (int r = 0; r < 4; ++r) acc[i][j][r] = 0.f;

  const int NT = K >> 6;

#define STG_A(ARR, H, TK)                                                     \
  do {                                                                        \
    _Pragma("unroll") for (int j_ = 0; j_ < 2; ++j_) {                        \
      const int c_ = (H) * 2 + j_;                                            \
      stage16(Ag + (size_t)(c_ * 64) * lda + (size_t)(TK) * 64,               \
              &ARR[(c_ * 64 + wid * 8) * 64]);                                \
    }                                                                         \
  } while (0)
#define STG_B(ARR, H, TK)                                                     \
  do {                                                                        \
    _Pragma("unroll") for (int j_ = 0; j_ < 2; ++j_) {                        \
      const int c_ = (H) * 2 + j_;                                            \
      stage16(Bg + (size_t)(c_ * 64) * ldb + (size_t)(TK) * 64,               \
              &ARR[(c_ * 64 + wid * 8) * 64]);                                \
    }                                                                         \
  } while (0)

  bf16x8 aq0[4][2], aq1[4][2], b0[2][2], b1[2][2];

#define RDA(DST, MH, ARR)                                                     \
  do {                                                                        \
    _Pragma("unroll") for (int mi_ = 0; mi_ < 4; ++mi_) {                     \
      const int arow_ = wr * 128 + (MH) * 64 + mi_ * 16 + l15;                \
      DST[mi_][0] = *(const bf16x8*)(&ARR[arow_ * 64] + swz0);                \
      DST[mi_][1] = *(const bf16x8*)(&ARR[arow_ * 64] + swz1);                \
    }                                                                         \
  } while (0)
#define RDB(DST, NH, ARR)                                                     \
  do {                                                                        \
    _Pragma("unroll") for (int ni_ = 0; ni_ < 2; ++ni_) {                     \
      const int brow_ = wc * 64 + (NH) * 32 + ni_ * 16 + l15;                 \
      DST[ni_][0] = *(const bf16x8*)(&ARR[brow_ * 64] + swz0);                \
      DST[ni_][1] = *(const bf16x8*)(&ARR[brow_ * 64] + swz1);                \
    }                                                                         \
  } while (0)
#define MFMAQ(MH, NH, AA, BB)                                                 \
  do {                                                                        \
    __builtin_amdgcn_s_setprio(1);                                            \
    _Pragma("unroll") for (int mi_ = 0; mi_ < 4; ++mi_)                       \
        _Pragma("unroll") for (int ni_ = 0; ni_ < 2; ++ni_) {                 \
      acc[(MH)*4 + mi_][(NH)*2 + ni_] = __builtin_amdgcn_mfma_f32_16x16x32_bf16( \
          AA[mi_][0], BB[ni_][0], acc[(MH)*4 + mi_][(NH)*2 + ni_], 0, 0, 0);  \
      acc[(MH)*4 + mi_][(NH)*2 + ni_] = __builtin_amdgcn_mfma_f32_16x16x32_bf16( \
          AA[mi_][1], BB[ni_][1], acc[(MH)*4 + mi_][(NH)*2 + ni_], 0, 0, 0);  \
    }                                                                         \
    __builtin_amdgcn_s_setprio(0);                                            \
  } while (0)

#define TILE(SAs, SBs, SAo, SBo, T)                                           \
  do {                                                                        \
    const int tn_ = ((T) + 1 < NT) ? (T) + 1 : NT - 1;                        \
    const int tnn_ = ((T) + 2 < NT) ? (T) + 2 : NT - 1;                       \
    /* ph1 */                                                                 \
    WAITVM(4);                                                                \
    SCHB();                                                                   \
    STG_B(SBo, 1, tn_);                                                       \
    RDB(b1, 1, SBs);                                                          \
    MFMAQ(0, 0, aq0, b0);                                                     \
    BARX();                                                                   \
    /* ph2 */                                                                 \
    STG_A(SAo, 1, tn_);                                                       \
    RDA(aq1, 1, SAs);                                                         \
    MFMAQ(0, 1, aq0, b1);                                                     \
    BARX();                                                                   \
    /* ph3 */                                                                 \
    STG_B(SBs, 0, tnn_);                                                      \
    MFMAQ(1, 0, aq1, b0);                                                     \
    BARX();                                                                   \
    /* ph4 */                                                                 \
    WAITVM(6);                                                                \
    SCHB();                                                                   \
    if (T + 1 < NT) {                                                         \
      RDA(aq0, 0, SAo);                                                       \
      RDB(b0, 0, SBo);                                                        \
    }                                                                         \
    STG_A(SAs, 0, tnn_);                                                      \
    MFMAQ(1, 1, aq1, b1);                                                     \
    BARX();                                                                   \
  } while (0)

  // prologue: tile0 fully + tile1 khalf0 (12 loads, chronological order)
  STG_B(sB0, 0, 0); STG_A(sA0, 0, 0);
  STG_B(sB0, 1, 0); STG_A(sA0, 1, 0);
  STG_B(sB1, 0, 1); STG_A(sA1, 0, 1);
  WAITVM(8);                          // retire HB0(0), HA0(0)
  SCHB();
  BARX();
  RDA(aq0, 0, sA0);                   // sub0(0)
  RDB(b0, 0, sB0);                    // nh0(0)

  for (int t = 0; t < NT; t += 2) {   // NT even (K%128==0)
    TILE(sA0, sB0, sA1, sB1, t);
    TILE(sA1, sB1, sA0, sB0, t + 1);
  }
  WAITVM(0);                          // drain tail stages (hygiene)

#undef STG_A
#undef STG_B
#undef RDA
#undef RDB
#undef MFMAQ
#undef TILE

  // epilogue: row-major store bursts — 4 consecutive stores per quad-row
  float bv[4];
#pragma unroll
  for (int nn = 0; nn < 4; ++nn) bv[nn] = bias[n0 + wc * 64 + nn * 16 + l15];
#pragma unroll
  for (int mm = 0; mm < 8; ++mm) {
#pragma unroll
    for (int r = 0; r < 4; ++r) {
      const int m = m0 + wr * 128 + mm * 16 + quad * 4 + r;
      TO* Crow = C + (size_t)m * ldc + n0 + wc * 64 + l15;
#pragma unroll
      for (int nn = 0; nn < 4; ++nn) {
        float v = acc[mm][nn][r] + bv[nn];
        if (EPI == 1) v = gelu_tanh(v);
        Crow[nn * 16] = (TO)v;
      }
    }
  }
}

// ---------------------------------------------------------------------------
// gemm128: round-10 kernel VERBATIM (dual-z launch = 151 us for BOTH
// projection GEMMs, MfmaUtil 41%). 128x128 tile, 4 waves, 64 KiB LDS ->
// 2 blocks/CU inter-block TLP; blockIdx.z selects GEMM.
// ---------------------------------------------------------------------------
template <typename TO>
__global__ __launch_bounds__(256, 2) void gemm128(
    const bf16* __restrict__ A,
    const bf16* __restrict__ B0m, const bf16* __restrict__ B1m,
    const float* __restrict__ bias0, const float* __restrict__ bias1,
    TO* __restrict__ C0, TO* __restrict__ C1, int epi1,
    int K, int lda, int ldb, int ldc) {
  const bf16* Bm = blockIdx.z ? B1m : B0m;
  const float* bias = blockIdx.z ? bias1 : bias0;
  TO* C = blockIdx.z ? C1 : C0;
  const int EPI = blockIdx.z ? epi1 : 0;

  const int gx = gridDim.x, gy = gridDim.y;
  const int nwg = gx * gy;
  const int did = blockIdx.x + gx * blockIdx.y;
  const int cpx = nwg >> 3;                       // chunk per XCD
  const int lid = (did & 7) * cpx + (did >> 3);
  const int n0 = (lid % gx) * 128;
  const int m0 = (lid / gx) * 128;

  __shared__ bf16 sA0[128 * 64];
  __shared__ bf16 sA1[128 * 64];
  __shared__ bf16 sB0[128 * 64];
  __shared__ bf16 sB1[128 * 64];
  const int tid = threadIdx.x;
  const int lane = tid & 63;
  const int wid = tid >> 6;         // 0..3
  const int wr = wid >> 1;          // M-half (64 rows)
  const int wc = wid & 1;           // N-half (64 cols)
  const int quad = lane >> 4;
  const int l15 = lane & 15;

  const int sr = tid >> 3;                        // 0..31
  const int ks8 = ((tid & 7) ^ (sr & 7)) << 3;
  const bf16* Ag = A + (size_t)(m0 + sr) * lda + ks8;
  const bf16* Bg = Bm + (size_t)(n0 + sr) * ldb + ks8;

  const int swz0 = ((quad) ^ (l15 & 7)) << 3;
  const int swz1 = ((4 + quad) ^ (l15 & 7)) << 3;

  f32x4 acc[4][4];
#pragma unroll
  for (int i = 0; i < 4; ++i)
#pragma unroll
    for (int j = 0; j < 4; ++j)
#pragma unroll
      for (int r = 0; r < 4; ++r) acc[i][j][r] = 0.f;

  const int NT = K >> 6;

#define STG_A(ARR, TK)                                                        \
  do {                                                                        \
    _Pragma("unroll") for (int c_ = 0; c_ < 4; ++c_)                          \
        stage16(Ag + (size_t)(c_ * 32) * lda + (size_t)(TK) * 64,             \
                &ARR[(c_ * 32 + wid * 8) * 64]);                              \
  } while (0)
#define STG_B(ARR, TK)                                                        \
  do {                                                                        \
    _Pragma("unroll") for (int c_ = 0; c_ < 4; ++c_)                          \
        stage16(Bg + (size_t)(c_ * 32) * ldb + (size_t)(TK) * 64,             \
                &ARR[(c_ * 32 + wid * 8) * 64]);                              \
  } while (0)

  bf16x8 af[4][2], b0[2][2], b1[2][2];

#define RDA(ARR)                                                              \
  do {                                                                        \
    _Pragma("unroll") for (int mi_ = 0; mi_ < 4; ++mi_) {                     \
      const int arow_ = wr * 64 + mi_ * 16 + l15;                             \
      af[mi_][0] = *(const bf16x8*)(&ARR[arow_ * 64] + swz0);                 \
      af[mi_][1] = *(const bf16x8*)(&ARR[arow_ * 64] + swz1);                 \
    }                                                                         \
  } while (0)
#define RDB(DST, NH, ARR)                                                     \
  do {                                                                        \
    _Pragma("unroll") for (int ni_ = 0; ni_ < 2; ++ni_) {                     \
      const int brow_ = wc * 64 + (NH) * 32 + ni_ * 16 + l15;                 \
      DST[ni_][0] = *(const bf16x8*)(&ARR[brow_ * 64] + swz0);                \
      DST[ni_][1] = *(const bf16x8*)(&ARR[brow_ * 64] + swz1);                \
    }                                                                         \
  } while (0)
#define MFMAQ(NH, BB)                                                         \
  do {                                                                        \
    __builtin_amdgcn_s_setprio(1);                                            \
    _Pragma("unroll") for (int mi_ = 0; mi_ < 4; ++mi_)                       \
        _Pragma("unroll") for (int ni_ = 0; ni_ < 2; ++ni_) {                 \
      acc[mi_][(NH)*2 + ni_] = __builtin_amdgcn_mfma_f32_16x16x32_bf16(       \
          af[mi_][0], BB[ni_][0], acc[mi_][(NH)*2 + ni_], 0, 0, 0);           \
      acc[mi_][(NH)*2 + ni_] = __builtin_amdgcn_mfma_f32_16x16x32_bf16(       \
          af[mi_][1], BB[ni_][1], acc[mi_][(NH)*2 + ni_], 0, 0, 0);           \
    }                                                                         \
    __builtin_amdgcn_s_setprio(0);                                            \
  } while (0)

#define TILE(SAs, SBs, SAo, SBo, T)                                           \
  do {                                                                        \
    const int tn_ = ((T) + 1 < NT) ? (T) + 1 : NT - 1;                        \
    const int tnn_ = ((T) + 2 < NT) ? (T) + 2 : NT - 1;                       \
    /* ph1 */                                                                 \
    RDA(SAs);                                                                 \
    RDB(b0, 0, SBs);                                                          \
    STG_B(SBo, tn_);                                                          \
    MFMAQ(0, b0);                                                             \
    BARX();                                                                   \
    /* ph2 */                                                                 \
    RDB(b1, 1, SBs);                                                          \
    STG_A(SAs, tnn_);                                                         \
    MFMAQ(1, b1);                                                             \
    WAITVM(4);                                                                \
    BARX();                                                                   \
  } while (0)

  // prologue: tiles 0,1 (16 loads, chronological); WAITVM(4) leaves A(1)
  const int t1 = (NT > 1) ? 1 : 0;
  STG_B(sB0, 0); STG_A(sA0, 0);
  STG_B(sB1, t1); STG_A(sA1, t1);
  WAITVM(4);
  SCHB();
  BARX();

  for (int t = 0; t < NT; t += 2) {   // NT even (K%128==0)
    TILE(sA0, sB0, sA1, sB1, t);
    TILE(sA1, sB1, sA0, sB0, t + 1);
  }
  WAITVM(0);                          // drain tail stages (hygiene)

#undef STG_A
#undef STG_B
#undef RDA
#undef RDB
#undef MFMAQ
#undef TILE

  float bv[4];
#pragma unroll
  for (int nn = 0; nn < 4; ++nn) bv[nn] = bias[n0 + wc * 64 + nn * 16 + l15];
#pragma unroll
  for (int mm = 0; mm < 4; ++mm) {
#pragma unroll
    for (int r = 0; r < 4; ++r) {
      const int m = m0 + wr * 64 + mm * 16 + quad * 4 + r;
      TO* Crow = C + (size_t)m * ldc + n0 + wc * 64 + l15;
#pragma unroll
      for (int nn = 0; nn < 4; ++nn) {
        float v = acc[mm][nn][r] + bv[nn];
        if (EPI == 1) v = gelu_tanh(v);
        Crow[nn * 16] = (TO)v;
      }
    }
  }
}

// ---------------------------------------------------------------------------
// gate pre-activation GEMM: one gate per block (z = h*2+g), 128x128 tile,
// K = DH = 256. out[m, h*DHD + n] = sum_k xconv[m, h*DHD+k] * W[g][h][n][k]
// ---------------------------------------------------------------------------
__global__ __launch_bounds__(256) void gate_gemm(
    const bf16* __restrict__ xconv,
    const bf16* __restrict__ gxT, const bf16* __restrict__ gaT,
    bf16* __restrict__ gxr, bf16* __restrict__ gar) {
  const int h = blockIdx.z >> 1;
  const int g = blockIdx.z & 1;
  const bf16* A = xconv + h * DHD;                       // lda = DDIM
  const bf16* Bm = (g ? gaT : gxT) + (size_t)h * DHD * DHD;  // ldb = DHD
  bf16* C = (g ? gar : gxr) + h * DHD;                   // ldc = DDIM
  const int n0 = blockIdx.x * 128;
  const int m0 = blockIdx.y * 128;
  __shared__ bf16 As[128 * 32];
  __shared__ bf16 Bs[128 * 32];
  const int tid = threadIdx.x;
  const int lane = tid & 63;
  const int wid = tid >> 6;
  const int waveM = wid >> 1, waveN = wid & 1;
  const int quad = lane >> 4;
  const int l15 = lane & 15;
  const int srow = lane >> 2;
  const int scol = (lane & 3) * 8;

  f32x4 acc[4][4];
#pragma unroll
  for (int i = 0; i < 4; ++i)
#pragma unroll
    for (int j = 0; j < 4; ++j)
#pragma unroll
      for (int r = 0; r < 4; ++r) acc[i][j][r] = 0.f;

  for (int k0 = 0; k0 < DHD; k0 += 32) {
    if (k0) __syncthreads();
#pragma unroll
    for (int cc = 0; cc < 2; ++cc) {
      const int q = wid * 2 + cc;
      const int row = q * 16 + srow;
      stage16(A + (size_t)(m0 + row) * DDIM + k0 + scol, As + q * 512);
      stage16(Bm + (size_t)(n0 + row) * DHD + k0 + scol, Bs + q * 512);
    }
    __syncthreads();
    bf16x8 af[4], bfr[4];
#pragma unroll
    for (int i = 0; i < 4; ++i) {
      af[i]  = *(const bf16x8*)&As[(waveM * 64 + i * 16 + l15) * 32 + quad * 8];
      bfr[i] = *(const bf16x8*)&Bs[(waveN * 64 + i * 16 + l15) * 32 + quad * 8];
    }
#pragma unroll
    for (int i = 0; i < 4; ++i)
#pragma unroll
      for (int j = 0; j < 4; ++j)
        acc[i][j] = __builtin_amdgcn_mfma_f32_16x16x32_bf16(af[i], bfr[j], acc[i][j], 0, 0, 0);
  }

#pragma unroll
  for (int j = 0; j < 4; ++j) {
    const int n = n0 + waveN * 64 + j * 16 + l15;
#pragma unroll
    for (int i = 0; i < 4; ++i) {
#pragma unroll
      for (int r = 0; r < 4; ++r) {
        const int m = m0 + waveM * 64 + i * 16 + quad * 4 + r;
        C[(size_t)m * DDIM + n] = (bf16)acc[i][j][r];
      }
    }
  }
}

// ---------------------------------------------------------------------------
// depthwise causal conv, TW=4; bf16 data, fp32 weights
// ---------------------------------------------------------------------------
__global__ __launch_bounds__(256) void conv_kernel(
    const bf16* __restrict__ xp, const float* __restrict__ cw,
    const float* __restrict__ cb, const int* __restrict__ segp,
    bf16* __restrict__ xc) {
  int v = blockIdx.x * 256 + threadIdx.x;
  int dv = v & (DDIM / 8 - 1);
  int m = v >> 8;
  int d0 = dv * 8;
  int t = m & (TDIM - 1);
  int sp = segp[m];
  float acc[8];
#pragma unroll
  for (int j = 0; j < 8; ++j) acc[j] = cb[d0 + j];
#pragma unroll
  for (int i = 0; i < 4; ++i) {
    int shift = 3 - i;
    if (t >= shift && sp >= shift) {
      bf16x8 xv = *(const bf16x8*)&xp[(size_t)(m - shift) * DDIM + d0];
#pragma unroll
      for (int j = 0; j < 8; ++j) acc[j] = fmaf((float)xv[j], cw[i * DDIM + d0 + j], acc[j]);
    }
  }
  bf16x8 o;
#pragma unroll
  for (int j = 0; j < 8; ++j) o[j] = (bf16)acc[j];
  *(bf16x8*)&xc[(size_t)m * DDIM + d0] = o;
}

// ---------------------------------------------------------------------------
// transpose + convert gate weights: dst[h][j][i] = (bf16)src[h][i][j]
// ---------------------------------------------------------------------------
__global__ __launch_bounds__(256) void transpose_gates(
    const float* __restrict__ gxw, const float* __restrict__ gaw,
    bf16* __restrict__ gxT, bf16* __restrict__ gaT) {
  __shared__ bf16 tile[32][33];
  int zz = blockIdx.z;
  int h = zz >> 1;
  const float* src = (zz & 1) ? gaw : gxw;
  bf16* dst = (zz & 1) ? gaT : gxT;
  int j0 = blockIdx.x * 32;
  int i0 = blockIdx.y * 32;
  int r = threadIdx.x >> 5;
  int c = threadIdx.x & 31;
  for (int rr = r; rr < 32; rr += 8)
    tile[rr][c] = (bf16)src[(size_t)(h * DHD + i0 + rr) * DHD + j0 + c];
  __syncthreads();
  for (int rr = r; rr < 32; rr += 8)
    dst[(size_t)(h * DHD + j0 + rr) * DHD + i0 + c] = tile[c][rr];
}

// ---------------------------------------------------------------------------
// RG-LRU elementwise recompute, shared by scan phases
// ---------------------------------------------------------------------------
__device__ __forceinline__ void lru_elem(float pgx, float pga, float xc,
                                         float spv, bool reset,
                                         float& a, float& nr) {
  const float gx = sigmoid_f(pgx);
  const float ga = sigmoid_f(pga);
  const float la = -8.f * ga * spv;
  a = reset ? 0.f : __expf(la);
  const float mult = reset ? 1.f : sqrtf(fmaxf(1.f - __expf(2.f * la), 0.f));
  nr = xc * gx * mult;
}

// chunked scan phase 1 — VECTORIZED x8 (G13: bf16x8 loads, 16 B/lane).
// Each thread owns 8 consecutive d; one block covers all 2048 d of one (b,c).
__global__ __launch_bounds__(256) void scan_phase1(
    const bf16* __restrict__ gxr, const bf16* __restrict__ gar,
    const bf16* __restrict__ xconv,
    const float* __restrict__ gxb, const float* __restrict__ gab,
    const float* __restrict__ apar, const int* __restrict__ segp,
    float* __restrict__ chA, float* __restrict__ chH) {
  int idx = blockIdx.x * 256 + threadIdx.x;     // B*NCHUNK*(DDIM/8) = 65536
  int dv = idx & (DDIM / 8 - 1);
  int c = (idx >> 8) & (NCHUNK - 1);
  int b = idx >> 14;
  int d0 = dv * 8;
  float gxbv[8], gabv[8], spv[8];
  const float4 gx0 = *(const float4*)(gxb + d0), gx1 = *(const float4*)(gxb + d0 + 4);
  const float4 ga0 = *(const float4*)(gab + d0), ga1 = *(const float4*)(gab + d0 + 4);
  const float4 ap0 = *(const float4*)(apar + d0), ap1 = *(const float4*)(apar + d0 + 4);
  gxbv[0]=gx0.x;gxbv[1]=gx0.y;gxbv[2]=gx0.z;gxbv[3]=gx0.w;
  gxbv[4]=gx1.x;gxbv[5]=gx1.y;gxbv[6]=gx1.z;gxbv[7]=gx1.w;
  gabv[0]=ga0.x;gabv[1]=ga0.y;gabv[2]=ga0.z;gabv[3]=ga0.w;
  gabv[4]=ga1.x;gabv[5]=ga1.y;gabv[6]=ga1.z;gabv[7]=ga1.w;
  spv[0]=softplus_f(ap0.x);spv[1]=softplus_f(ap0.y);spv[2]=softplus_f(ap0.z);spv[3]=softplus_f(ap0.w);
  spv[4]=softplus_f(ap1.x);spv[5]=softplus_f(ap1.y);spv[6]=softplus_f(ap1.z);spv[7]=softplus_f(ap1.w);
  const int mrow = b * TDIM + c * LCHUNK;
  size_t base = (size_t)mrow * DDIM + d0;
  float A[8], hh[8];
#pragma unroll
  for (int j = 0; j < 8; ++j) { A[j] = 1.f; hh[j] = 0.f; }
  for (int i = 0; i < LCHUNK; ++i) {
    size_t o = base + (size_t)i * DDIM;
    bf16x8 g1 = *(const bf16x8*)&gxr[o];
    bf16x8 g2 = *(const bf16x8*)&gar[o];
    bf16x8 xv = *(const bf16x8*)&xconv[o];
    bool rst = (segp[mrow + i] == 0);
#pragma unroll
    for (int j = 0; j < 8; ++j) {
      float a, nr;
      lru_elem((float)g1[j] + gxbv[j], (float)g2[j] + gabv[j], (float)xv[j],
               spv[j], rst, a, nr);
      hh[j] = fmaf(a, hh[j], nr);
      A[j] *= a;
    }
  }
  size_t ci = (size_t)(b * NCHUNK + c) * DDIM + d0;
  *(f32x4*)&chA[ci]     = f32x4{A[0], A[1], A[2], A[3]};
  *(f32x4*)&chA[ci + 4] = f32x4{A[4], A[5], A[6], A[7]};
  *(f32x4*)&chH[ci]     = f32x4{hh[0], hh[1], hh[2], hh[3]};
  *(f32x4*)&chH[ci + 4] = f32x4{hh[4], hh[5], hh[6], hh[7]};
}

__global__ __launch_bounds__(256) void scan_phase2(
    const float* __restrict__ chA, const float* __restrict__ chH,
    float* __restrict__ hst) {
  int idx = blockIdx.x * 256 + threadIdx.x;
  int d = idx & (DDIM - 1);
  int b = idx >> 11;
  float s = 0.f;
  for (int c = 0; c < NCHUNK; ++c) {
    int ci = (b * NCHUNK + c) * DDIM + d;
    hst[ci] = s;
    s = fmaf(chA[ci], s, chH[ci]);
  }
}

// phase 3 — VECTORIZED x8: replay with chunk-start state; z = h*y over y
__global__ __launch_bounds__(256) void scan_phase3(
    const bf16* __restrict__ gxr, const bf16* __restrict__ gar,
    const bf16* __restrict__ xconv,
    const float* __restrict__ gxb, const float* __restrict__ gab,
    const float* __restrict__ apar, const int* __restrict__ segp,
    const float* __restrict__ hst, bf16* __restrict__ yz) {
  int idx = blockIdx.x * 256 + threadIdx.x;
  int dv = idx & (DDIM / 8 - 1);
  int c = (idx >> 8) & (NCHUNK - 1);
  int b = idx >> 14;
  int d0 = dv * 8;
  float gxbv[8], gabv[8], spv[8];
  const float4 gx0 = *(const float4*)(gxb + d0), gx1 = *(const float4*)(gxb + d0 + 4);
  const float4 ga0 = *(const float4*)(gab + d0), ga1 = *(const float4*)(gab + d0 + 4);
  const float4 ap0 = *(const float4*)(apar + d0), ap1 = *(const float4*)(apar + d0 + 4);
  gxbv[0]=gx0.x;gxbv[1]=gx0.y;gxbv[2]=gx0.z;gxbv[3]=gx0.w;
  gxbv[4]=gx1.x;gxbv[5]=gx1.y;gxbv[6]=gx1.z;gxbv[7]=gx1.w;
  gabv[0]=ga0.x;gabv[1]=ga0.y;gabv[2]=ga0.z;gabv[3]=ga0.w;
  gabv[4]=ga1.x;gabv[5]=ga1.y;gabv[6]=ga1.z;gabv[7]=ga1.w;
  spv[0]=softplus_f(ap0.x);spv[1]=softplus_f(ap0.y);spv[2]=softplus_f(ap0.z);spv[3]=softplus_f(ap0.w);
  spv[4]=softplus_f(ap1.x);spv[5]=softplus_f(ap1.y);spv[6]=softplus_f(ap1.z);spv[7]=softplus_f(ap1.w);
  const int mrow = b * TDIM + c * LCHUNK;
  size_t base = (size_t)mrow * DDIM + d0;
  size_t ci = (size_t)(b * NCHUNK + c) * DDIM + d0;
  float hh[8];
  const float4 h0 = *(const float4*)(hst + ci), h1 = *(const float4*)(hst + ci + 4);
  hh[0]=h0.x;hh[1]=h0.y;hh[2]=h0.z;hh[3]=h0.w;
  hh[4]=h1.x;hh[5]=h1.y;hh[6]=h1.z;hh[7]=h1.w;
  for (int i = 0; i < LCHUNK; ++i) {
    size_t o = base + (size_t)i * DDIM;
    bf16x8 g1 = *(const bf16x8*)&gxr[o];
    bf16x8 g2 = *(const bf16x8*)&gar[o];
    bf16x8 xv = *(const bf16x8*)&xconv[o];
    bf16x8 y8 = *(const bf16x8*)&yz[o];
    bool rst = (segp[mrow + i] == 0);
    bf16x8 out;
#pragma unroll
    for (int j = 0; j < 8; ++j) {
      float a, nr;
      lru_elem((float)g1[j] + gxbv[j], (float)g2[j] + gabv[j], (float)xv[j],
               spv[j], rst, a, nr);
      hh[j] = fmaf(a, hh[j], nr);
      out[j] = (bf16)(hh[j] * (float)y8[j]);
    }
    *(bf16x8*)&yz[o] = out;
  }
}

// ---------------------------------------------------------------------------
extern "C" void kernel_launch(void* const* d_in, const int* in_sizes, int n_in,
                              void* d_out, int out_size, void* d_ws, size_t ws_size,
                              hipStream_t stream) {
  const float* x    = (const float*)d_in[0];
  const int*   segp = (const int*)d_in[1];
  const float* Wy   = (const float*)d_in[2];
  const float* by   = (const float*)d_in[3];
  const float* Wx   = (const float*)d_in[4];
  const float* bx   = (const float*)d_in[5];
  const float* cw   = (const float*)d_in[6];
  const float* cb   = (const float*)d_in[7];
  const float* gxw  = (const float*)d_in[8];
  const float* gxb  = (const float*)d_in[9];
  const float* gaw  = (const float*)d_in[10];
  const float* gab  = (const float*)d_in[11];
  const float* apar = (const float*)d_in[12];
  const float* Wout = (const float*)d_in[13];
  const float* bout = (const float*)d_in[14];

  const size_t MD = (size_t)MTOT * DDIM;       // 16.78M elements
  const size_t WD = (size_t)DDIM * DDIM;       // 4.19M elements
  // d_out (fp32, 67 MB) as bf16 scratch until the final GEMM:
  bf16* xb    = (bf16*)d_out;                   // lower: xb -> xconv
  bf16* xproj = (bf16*)((char*)d_out + MD * 2); // upper: xproj -> gxr
  bf16* xconv = xb;
  bf16* gxr   = xproj;

  // ws (~92 MB): gar | W1 | WB1 | WB2 | gxT | gaT | chA | chH | hst
  char* ws = (char*)d_ws;
  bf16*  gar = (bf16*)ws;                        // 33.5 MB
  bf16*  W1  = (bf16*)(ws + MD * 2);             // y -> z (33.5 MB)
  bf16*  WB1 = (bf16*)(ws + 2 * MD * 2);         // Wxb, later Woutb (8.4 MB)
  bf16*  WB2 = (bf16*)(ws + 2 * MD * 2 + WD * 2);// Wyb (8.4 MB)
  char*  tail = ws + 2 * MD * 2 + 2 * WD * 2;
  const size_t GW = (size_t)HDIM * DHD * DHD * 2;      // 1 MiB
  const size_t CH = (size_t)BDIM * NCHUNK * DDIM * 4;  // 2 MiB
  bf16*  gxT = (bf16*)tail;
  bf16*  gaT = (bf16*)(tail + GW);
  float* chA = (float*)(tail + 2 * GW);
  float* chH = (float*)(tail + 2 * GW + CH);
  float* hst = (float*)(tail + 2 * GW + 2 * CH);

  dim3 blk(256);
  f2b<<<dim3(MD / 2048), blk, 0, stream>>>(x, xb);
  f2b<<<dim3(WD / 2048), blk, 0, stream>>>(Wx, WB1);
  f2b<<<dim3(WD / 2048), blk, 0, stream>>>(Wy, WB2);
  transpose_gates<<<dim3(8, 8, 16), blk, 0, stream>>>(gxw, gaw, gxT, gaT);

  // DUAL GEMM (z=0: xproj = x@Wx^T+bx ; z=1: y = gelu(x@Wy^T+by)) —
  // measured 151 us for both (round 10, MfmaUtil 41%).
  gemm128<bf16><<<dim3(16, 64, 2), blk, 0, stream>>>(
      xb, WB1, WB2, bx, by, xproj, W1, 1, DDIM, DDIM, DDIM, DDIM);

  // xconv in-place over xb (reads xproj; xb dead after the dual GEMM)
  conv_kernel<<<dim3(MTOT * (DDIM / 8) / 256), blk, 0, stream>>>(xproj, cw, cb, segp, xconv);

  // gate pre-activations: gxr over xproj (dead), gar in ws
  gate_gemm<<<dim3(2, 64, 16), blk, 0, stream>>>(xconv, gxT, gaT, gxr, gar);

  // chunked scan, vectorized x8
  scan_phase1<<<dim3(BDIM * NCHUNK * (DDIM / 8) / 256), blk, 0, stream>>>(
      gxr, gar, xconv, gxb, gab, apar, segp, chA, chH);
  scan_phase2<<<dim3(BDIM * DDIM / 256), blk, 0, stream>>>(chA, chH, hst);
  scan_phase3<<<dim3(BDIM * NCHUNK * (DDIM / 8) / 256), blk, 0, stream>>>(
      gxr, gar, xconv, gxb, gab, apar, segp, hst, W1);

  // out = z @ Wout^T + bout — round-7 gemm256 (measured 77.5-85 us)
  f2b<<<dim3(WD / 2048), blk, 0, stream>>>(Wout, WB1);
  gemm256<float, 0><<<dim3(8, 32), dim3(512), 0, stream>>>(
      W1, WB1, bout, (float*)d_out, DDIM, DDIM, DDIM, DDIM);
}

// Round 12
// 416.586 us; speedup vs baseline: 1.0754x; 1.0754x over previous
//
#include <hip/hip_runtime.h>
#include <cstdint>
#include <cstddef>

typedef __bf16 bf16;
typedef __bf16 bf16x8 __attribute__((ext_vector_type(8)));
typedef __bf16 bf16x4 __attribute__((ext_vector_type(4)));
typedef float f32x4 __attribute__((ext_vector_type(4)));

#define BDIM 4
#define TDIM 2048
#define DDIM 2048
#define HDIM 8
#define DHD 256
#define MTOT 8192
#define NCHUNK 64
#define LCHUNK 32

// async 16B global->LDS; LDS dest = wave-uniform base + lane*16
__device__ __forceinline__ void stage16(const bf16* g, bf16* l) {
  __builtin_amdgcn_global_load_lds(
      (const __attribute__((address_space(1))) void*)g,
      (__attribute__((address_space(3))) void*)l, 16, 0, 0);
}

// intrinsic barrier (no implicit drain); BARE asm waitcnt (no "memory"
// clobber -> no compiler-inserted full drain; round-6 lesson).
#define BARX() __builtin_amdgcn_s_barrier()
#define SCHB() __builtin_amdgcn_sched_barrier(0)
#define WAITVM(N) asm volatile("s_waitcnt vmcnt(" #N ")")

__device__ __forceinline__ float sigmoid_f(float x) {
  return __fdividef(1.f, 1.f + __expf(-x));
}
__device__ __forceinline__ float gelu_tanh(float v) {
  float u = 0.7978845608028654f * (v + 0.044715f * v * v * v);
  u = fminf(fmaxf(u, -15.f), 15.f);
  float t = __expf(2.f * u);                       // tanh(u) = (t-1)/(t+1)
  return 0.5f * v * (1.f + __fdividef(t - 1.f, t + 1.f));
}
__device__ __forceinline__ float softplus_f(float x) {
  return __logf(1.f + __expf(x));                  // x in [-1.2, 0.4] here
}

// ---------------------------------------------------------------------------
// fp32 -> bf16 bulk convert, 8 elem/thread (count must be /2048)
// ---------------------------------------------------------------------------
__global__ __launch_bounds__(256) void f2b(const float* __restrict__ src,
                                           bf16* __restrict__ dst) {
  size_t i = ((size_t)blockIdx.x * 256 + threadIdx.x) * 8;
  const float4 a = *(const float4*)(src + i);
  const float4 b = *(const float4*)(src + i + 4);
  bf16x8 r;
  r[0] = (bf16)a.x; r[1] = (bf16)a.y; r[2] = (bf16)a.z; r[3] = (bf16)a.w;
  r[4] = (bf16)b.x; r[5] = (bf16)b.y; r[6] = (bf16)b.z; r[7] = (bf16)b.w;
  *(bf16x8*)(dst + i) = r;
}

// dual-source variant: converts two weight matrices in one launch (z picks)
__global__ __launch_bounds__(256) void f2b2(const float* __restrict__ s0,
                                            const float* __restrict__ s1,
                                            bf16* __restrict__ d0,
                                            bf16* __restrict__ d1) {
  const float* src = blockIdx.y ? s1 : s0;
  bf16* dst = blockIdx.y ? d1 : d0;
  size_t i = ((size_t)blockIdx.x * 256 + threadIdx.x) * 8;
  const float4 a = *(const float4*)(src + i);
  const float4 b = *(const float4*)(src + i + 4);
  bf16x8 r;
  r[0] = (bf16)a.x; r[1] = (bf16)a.y; r[2] = (bf16)a.z; r[3] = (bf16)a.w;
  r[4] = (bf16)b.x; r[5] = (bf16)b.y; r[6] = (bf16)b.z; r[7] = (bf16)b.w;
  *(bf16x8*)(dst + i) = r;
}

// ---------------------------------------------------------------------------
// gemm256: round-7 kernel VERBATIM (measured 77.5 us/GEMM, best single-GEMM).
// 256x256 tile, BK=64, 8 waves, four distinct 32 KiB LDS buffers, XOR-8
// swizzle (0 conflicts), 4 phases/tile, read-ahead ping-pong frags, one
// barrier per phase, counted vmcnt(4)/(6) never draining in-loop.
// ---------------------------------------------------------------------------
template <typename TO, int EPI>
__global__ __launch_bounds__(512, 2) void gemm256(
    const bf16* __restrict__ A, const bf16* __restrict__ Bm,
    const float* __restrict__ bias, TO* __restrict__ C,
    int K, int lda, int ldb, int ldc) {
  const int gx = gridDim.x, gy = gridDim.y;
  const int nwg = gx * gy;
  const int did = blockIdx.x + gx * blockIdx.y;
  const int cpx = nwg >> 3;                       // chunk per XCD
  const int lid = (did & 7) * cpx + (did >> 3);
  const int n0 = (lid % gx) * 256;
  const int m0 = (lid / gx) * 256;

  __shared__ bf16 sA0[256 * 64];
  __shared__ bf16 sA1[256 * 64];
  __shared__ bf16 sB0[256 * 64];
  __shared__ bf16 sB1[256 * 64];
  const int tid = threadIdx.x;
  const int lane = tid & 63;
  const int wid = tid >> 6;         // 0..7
  const int wr = wid >> 2;          // M-half of tile (128 rows)
  const int wc = wid & 3;           // N-quarter (64 cols)
  const int quad = lane >> 4;
  const int l15 = lane & 15;

  const int sr = tid >> 3;                        // 0..63
  const int ks8 = ((tid & 7) ^ (sr & 7)) << 3;    // element offset in 64-wide row
  const bf16* Ag = A + (size_t)(m0 + sr) * lda + ks8;
  const bf16* Bg = Bm + (size_t)(n0 + sr) * ldb + ks8;

  const int swz0 = ((quad) ^ (l15 & 7)) << 3;
  const int swz1 = ((4 + quad) ^ (l15 & 7)) << 3;

  f32x4 acc[8][4];
#pragma unroll
  for (int i = 0; i < 8; ++i)
#pragma unroll
    for (int j = 0; j < 4; ++j)
#pragma unroll
      for (int r = 0; r < 4; ++r) acc[i][j][r] = 0.f;

  const int NT = K >> 6;

#define STG_A(ARR, H, TK)                                                     \
  do {                                                                        \
    _Pragma("unroll") for (int j_ = 0; j_ < 2; ++j_) {                        \
      const int c_ = (H) * 2 + j_;                                            \
      stage16(Ag + (size_t)(c_ * 64) * lda + (size_t)(TK) * 64,               \
              &ARR[(c_ * 64 + wid * 8) * 64]);                                \
    }                                                                         \
  } while (0)
#define STG_B(ARR, H, TK)                                                     \
  do {                                                                        \
    _Pragma("unroll") for (int j_ = 0; j_ < 2; ++j_) {                        \
      const int c_ = (H) * 2 + j_;                                            \
      stage16(Bg + (size_t)(c_ * 64) * ldb + (size_t)(TK) * 64,               \
              &ARR[(c_ * 64 + wid * 8) * 64]);                                \
    }                                                                         \
  } while (0)

  bf16x8 aq0[4][2], aq1[4][2], b0[2][2], b1[2][2];

#define RDA(DST, MH, ARR)                                                     \
  do {                                                                        \
    _Pragma("unroll") for (int mi_ = 0; mi_ < 4; ++mi_) {                     \
      const int arow_ = wr * 128 + (MH) * 64 + mi_ * 16 + l15;                \
      DST[mi_][0] = *(const bf16x8*)(&ARR[arow_ * 64] + swz0);                \
      DST[mi_][1] = *(const bf16x8*)(&ARR[arow_ * 64] + swz1);                \
    }                                                                         \
  } while (0)
#define RDB(DST, NH, ARR)                                                     \
  do {                                                                        \
    _Pragma("unroll") for (int ni_ = 0; ni_ < 2; ++ni_) {                     \
      const int brow_ = wc * 64 + (NH) * 32 + ni_ * 16 + l15;                 \
      DST[ni_][0] = *(const bf16x8*)(&ARR[brow_ * 64] + swz0);                \
      DST[ni_][1] = *(const bf16x8*)(&ARR[brow_ * 64] + swz1);                \
    }                                                                         \
  } while (0)
#define MFMAQ(MH, NH, AA, BB)                                                 \
  do {                                                                        \
    __builtin_amdgcn_s_setprio(1);                                            \
    _Pragma("unroll") for (int mi_ = 0; mi_ < 4; ++mi_)                       \
        _Pragma("unroll") for (int ni_ = 0; ni_ < 2; ++ni_) {                 \
      acc[(MH)*4 + mi_][(NH)*2 + ni_] = __builtin_amdgcn_mfma_f32_16x16x32_bf16( \
          AA[mi_][0], BB[ni_][0], acc[(MH)*4 + mi_][(NH)*2 + ni_], 0, 0, 0);  \
      acc[(MH)*4 + mi_][(NH)*2 + ni_] = __builtin_amdgcn_mfma_f32_16x16x32_bf16( \
          AA[mi_][1], BB[ni_][1], acc[(MH)*4 + mi_][(NH)*2 + ni_], 0, 0, 0);  \
    }                                                                         \
    __builtin_amdgcn_s_setprio(0);                                            \
  } while (0)

#define TILE(SAs, SBs, SAo, SBo, T)                                           \
  do {                                                                        \
    const int tn_ = ((T) + 1 < NT) ? (T) + 1 : NT - 1;                        \
    const int tnn_ = ((T) + 2 < NT) ? (T) + 2 : NT - 1;                       \
    /* ph1 */                                                                 \
    WAITVM(4);                                                                \
    SCHB();                                                                   \
    STG_B(SBo, 1, tn_);                                                       \
    RDB(b1, 1, SBs);                                                          \
    MFMAQ(0, 0, aq0, b0);                                                     \
    BARX();                                                                   \
    /* ph2 */                                                                 \
    STG_A(SAo, 1, tn_);                                                       \
    RDA(aq1, 1, SAs);                                                         \
    MFMAQ(0, 1, aq0, b1);                                                     \
    BARX();                                                                   \
    /* ph3 */                                                                 \
    STG_B(SBs, 0, tnn_);                                                      \
    MFMAQ(1, 0, aq1, b0);                                                     \
    BARX();                                                                   \
    /* ph4 */                                                                 \
    WAITVM(6);                                                                \
    SCHB();                                                                   \
    if (T + 1 < NT) {                                                         \
      RDA(aq0, 0, SAo);                                                       \
      RDB(b0, 0, SBo);                                                        \
    }                                                                         \
    STG_A(SAs, 0, tnn_);                                                      \
    MFMAQ(1, 1, aq1, b1);                                                     \
    BARX();                                                                   \
  } while (0)

  // prologue: tile0 fully + tile1 khalf0 (12 loads, chronological order)
  STG_B(sB0, 0, 0); STG_A(sA0, 0, 0);
  STG_B(sB0, 1, 0); STG_A(sA0, 1, 0);
  STG_B(sB1, 0, 1); STG_A(sA1, 0, 1);
  WAITVM(8);                          // retire HB0(0), HA0(0)
  SCHB();
  BARX();
  RDA(aq0, 0, sA0);                   // sub0(0)
  RDB(b0, 0, sB0);                    // nh0(0)

  for (int t = 0; t < NT; t += 2) {   // NT even (K%128==0)
    TILE(sA0, sB0, sA1, sB1, t);
    TILE(sA1, sB1, sA0, sB0, t + 1);
  }
  WAITVM(0);                          // drain tail stages (hygiene)

#undef STG_A
#undef STG_B
#undef RDA
#undef RDB
#undef MFMAQ
#undef TILE

  // epilogue: row-major store bursts — 4 consecutive stores per quad-row
  float bv[4];
#pragma unroll
  for (int nn = 0; nn < 4; ++nn) bv[nn] = bias[n0 + wc * 64 + nn * 16 + l15];
#pragma unroll
  for (int mm = 0; mm < 8; ++mm) {
#pragma unroll
    for (int r = 0; r < 4; ++r) {
      const int m = m0 + wr * 128 + mm * 16 + quad * 4 + r;
      TO* Crow = C + (size_t)m * ldc + n0 + wc * 64 + l15;
#pragma unroll
      for (int nn = 0; nn < 4; ++nn) {
        float v = acc[mm][nn][r] + bv[nn];
        if (EPI == 1) v = gelu_tanh(v);
        Crow[nn * 16] = (TO)v;
      }
    }
  }
}

// ---------------------------------------------------------------------------
// gemm128: round-10 kernel VERBATIM (dual-z launch = 151 us for BOTH
// projection GEMMs, MfmaUtil 41%). 128x128 tile, 4 waves, 64 KiB LDS ->
// 2 blocks/CU inter-block TLP; blockIdx.z selects GEMM.
// ---------------------------------------------------------------------------
template <typename TO>
__global__ __launch_bounds__(256, 2) void gemm128(
    const bf16* __restrict__ A,
    const bf16* __restrict__ B0m, const bf16* __restrict__ B1m,
    const float* __restrict__ bias0, const float* __restrict__ bias1,
    TO* __restrict__ C0, TO* __restrict__ C1, int epi1,
    int K, int lda, int ldb, int ldc) {
  const bf16* Bm = blockIdx.z ? B1m : B0m;
  const float* bias = blockIdx.z ? bias1 : bias0;
  TO* C = blockIdx.z ? C1 : C0;
  const int EPI = blockIdx.z ? epi1 : 0;

  const int gx = gridDim.x, gy = gridDim.y;
  const int nwg = gx * gy;
  const int did = blockIdx.x + gx * blockIdx.y;
  const int cpx = nwg >> 3;                       // chunk per XCD
  const int lid = (did & 7) * cpx + (did >> 3);
  const int n0 = (lid % gx) * 128;
  const int m0 = (lid / gx) * 128;

  __shared__ bf16 sA0[128 * 64];
  __shared__ bf16 sA1[128 * 64];
  __shared__ bf16 sB0[128 * 64];
  __shared__ bf16 sB1[128 * 64];
  const int tid = threadIdx.x;
  const int lane = tid & 63;
  const int wid = tid >> 6;         // 0..3
  const int wr = wid >> 1;          // M-half (64 rows)
  const int wc = wid & 1;           // N-half (64 cols)
  const int quad = lane >> 4;
  const int l15 = lane & 15;

  const int sr = tid >> 3;                        // 0..31
  const int ks8 = ((tid & 7) ^ (sr & 7)) << 3;
  const bf16* Ag = A + (size_t)(m0 + sr) * lda + ks8;
  const bf16* Bg = Bm + (size_t)(n0 + sr) * ldb + ks8;

  const int swz0 = ((quad) ^ (l15 & 7)) << 3;
  const int swz1 = ((4 + quad) ^ (l15 & 7)) << 3;

  f32x4 acc[4][4];
#pragma unroll
  for (int i = 0; i < 4; ++i)
#pragma unroll
    for (int j = 0; j < 4; ++j)
#pragma unroll
      for (int r = 0; r < 4; ++r) acc[i][j][r] = 0.f;

  const int NT = K >> 6;

#define STG_A(ARR, TK)                                                        \
  do {                                                                        \
    _Pragma("unroll") for (int c_ = 0; c_ < 4; ++c_)                          \
        stage16(Ag + (size_t)(c_ * 32) * lda + (size_t)(TK) * 64,             \
                &ARR[(c_ * 32 + wid * 8) * 64]);                              \
  } while (0)
#define STG_B(ARR, TK)                                                        \
  do {                                                                        \
    _Pragma("unroll") for (int c_ = 0; c_ < 4; ++c_)                          \
        stage16(Bg + (size_t)(c_ * 32) * ldb + (size_t)(TK) * 64,             \
                &ARR[(c_ * 32 + wid * 8) * 64]);                              \
  } while (0)

  bf16x8 af[4][2], b0[2][2], b1[2][2];

#define RDA(ARR)                                                              \
  do {                                                                        \
    _Pragma("unroll") for (int mi_ = 0; mi_ < 4; ++mi_) {                     \
      const int arow_ = wr * 64 + mi_ * 16 + l15;                             \
      af[mi_][0] = *(const bf16x8*)(&ARR[arow_ * 64] + swz0);                 \
      af[mi_][1] = *(const bf16x8*)(&ARR[arow_ * 64] + swz1);                 \
    }                                                                         \
  } while (0)
#define RDB(DST, NH, ARR)                                                     \
  do {                                                                        \
    _Pragma("unroll") for (int ni_ = 0; ni_ < 2; ++ni_) {                     \
      const int brow_ = wc * 64 + (NH) * 32 + ni_ * 16 + l15;                 \
      DST[ni_][0] = *(const bf16x8*)(&ARR[brow_ * 64] + swz0);                \
      DST[ni_][1] = *(const bf16x8*)(&ARR[brow_ * 64] + swz1);                \
    }                                                                         \
  } while (0)
#define MFMAQ(NH, BB)                                                         \
  do {                                                                        \
    __builtin_amdgcn_s_setprio(1);                                            \
    _Pragma("unroll") for (int mi_ = 0; mi_ < 4; ++mi_)                       \
        _Pragma("unroll") for (int ni_ = 0; ni_ < 2; ++ni_) {                 \
      acc[mi_][(NH)*2 + ni_] = __builtin_amdgcn_mfma_f32_16x16x32_bf16(       \
          af[mi_][0], BB[ni_][0], acc[mi_][(NH)*2 + ni_], 0, 0, 0);           \
      acc[mi_][(NH)*2 + ni_] = __builtin_amdgcn_mfma_f32_16x16x32_bf16(       \
          af[mi_][1], BB[ni_][1], acc[mi_][(NH)*2 + ni_], 0, 0, 0);           \
    }                                                                         \
    __builtin_amdgcn_s_setprio(0);                                            \
  } while (0)

#define TILE(SAs, SBs, SAo, SBo, T)                                           \
  do {                                                                        \
    const int tn_ = ((T) + 1 < NT) ? (T) + 1 : NT - 1;                        \
    const int tnn_ = ((T) + 2 < NT) ? (T) + 2 : NT - 1;                       \
    /* ph1 */                                                                 \
    RDA(SAs);                                                                 \
    RDB(b0, 0, SBs);                                                          \
    STG_B(SBo, tn_);                                                          \
    MFMAQ(0, b0);                                                             \
    BARX();                                                                   \
    /* ph2 */                                                                 \
    RDB(b1, 1, SBs);                                                          \
    STG_A(SAs, tnn_);                                                         \
    MFMAQ(1, b1);                                                             \
    WAITVM(4);                                                                \
    BARX();                                                                   \
  } while (0)

  // prologue: tiles 0,1 (16 loads, chronological); WAITVM(4) leaves A(1)
  const int t1 = (NT > 1) ? 1 : 0;
  STG_B(sB0, 0); STG_A(sA0, 0);
  STG_B(sB1, t1); STG_A(sA1, t1);
  WAITVM(4);
  SCHB();
  BARX();

  for (int t = 0; t < NT; t += 2) {   // NT even (K%128==0)
    TILE(sA0, sB0, sA1, sB1, t);
    TILE(sA1, sB1, sA0, sB0, t + 1);
  }
  WAITVM(0);                          // drain tail stages (hygiene)

#undef STG_A
#undef STG_B
#undef RDA
#undef RDB
#undef MFMAQ
#undef TILE

  float bv[4];
#pragma unroll
  for (int nn = 0; nn < 4; ++nn) bv[nn] = bias[n0 + wc * 64 + nn * 16 + l15];
#pragma unroll
  for (int mm = 0; mm < 4; ++mm) {
#pragma unroll
    for (int r = 0; r < 4; ++r) {
      const int m = m0 + wr * 64 + mm * 16 + quad * 4 + r;
      TO* Crow = C + (size_t)m * ldc + n0 + wc * 64 + l15;
#pragma unroll
      for (int nn = 0; nn < 4; ++nn) {
        float v = acc[mm][nn][r] + bv[nn];
        if (EPI == 1) v = gelu_tanh(v);
        Crow[nn * 16] = (TO)v;
      }
    }
  }
}

// ---------------------------------------------------------------------------
// gate pre-activation GEMM: one gate per block (z = h*2+g), 128x128 tile,
// K = DH = 256. out[m, h*DHD + n] = sum_k xconv[m, h*DHD+k] * W[g][h][n][k]
// ---------------------------------------------------------------------------
__global__ __launch_bounds__(256) void gate_gemm(
    const bf16* __restrict__ xconv,
    const bf16* __restrict__ gxT, const bf16* __restrict__ gaT,
    bf16* __restrict__ gxr, bf16* __restrict__ gar) {
  const int h = blockIdx.z >> 1;
  const int g = blockIdx.z & 1;
  const bf16* A = xconv + h * DHD;                       // lda = DDIM
  const bf16* Bm = (g ? gaT : gxT) + (size_t)h * DHD * DHD;  // ldb = DHD
  bf16* C = (g ? gar : gxr) + h * DHD;                   // ldc = DDIM
  const int n0 = blockIdx.x * 128;
  const int m0 = blockIdx.y * 128;
  __shared__ bf16 As[128 * 32];
  __shared__ bf16 Bs[128 * 32];
  const int tid = threadIdx.x;
  const int lane = tid & 63;
  const int wid = tid >> 6;
  const int waveM = wid >> 1, waveN = wid & 1;
  const int quad = lane >> 4;
  const int l15 = lane & 15;
  const int srow = lane >> 2;
  const int scol = (lane & 3) * 8;

  f32x4 acc[4][4];
#pragma unroll
  for (int i = 0; i < 4; ++i)
#pragma unroll
    for (int j = 0; j < 4; ++j)
#pragma unroll
      for (int r = 0; r < 4; ++r) acc[i][j][r] = 0.f;

  for (int k0 = 0; k0 < DHD; k0 += 32) {
    if (k0) __syncthreads();
#pragma unroll
    for (int cc = 0; cc < 2; ++cc) {
      const int q = wid * 2 + cc;
      const int row = q * 16 + srow;
      stage16(A + (size_t)(m0 + row) * DDIM + k0 + scol, As + q * 512);
      stage16(Bm + (size_t)(n0 + row) * DHD + k0 + scol, Bs + q * 512);
    }
    __syncthreads();
    bf16x8 af[4], bfr[4];
#pragma unroll
    for (int i = 0; i < 4; ++i) {
      af[i]  = *(const bf16x8*)&As[(waveM * 64 + i * 16 + l15) * 32 + quad * 8];
      bfr[i] = *(const bf16x8*)&Bs[(waveN * 64 + i * 16 + l15) * 32 + quad * 8];
    }
#pragma unroll
    for (int i = 0; i < 4; ++i)
#pragma unroll
      for (int j = 0; j < 4; ++j)
        acc[i][j] = __builtin_amdgcn_mfma_f32_16x16x32_bf16(af[i], bfr[j], acc[i][j], 0, 0, 0);
  }

#pragma unroll
  for (int j = 0; j < 4; ++j) {
    const int n = n0 + waveN * 64 + j * 16 + l15;
#pragma unroll
    for (int i = 0; i < 4; ++i) {
#pragma unroll
      for (int r = 0; r < 4; ++r) {
        const int m = m0 + waveM * 64 + i * 16 + quad * 4 + r;
        C[(size_t)m * DDIM + n] = (bf16)acc[i][j][r];
      }
    }
  }
}

// ---------------------------------------------------------------------------
// depthwise causal conv, TW=4; bf16 data, fp32 weights
// ---------------------------------------------------------------------------
__global__ __launch_bounds__(256) void conv_kernel(
    const bf16* __restrict__ xp, const float* __restrict__ cw,
    const float* __restrict__ cb, const int* __restrict__ segp,
    bf16* __restrict__ xc) {
  int v = blockIdx.x * 256 + threadIdx.x;
  int dv = v & (DDIM / 8 - 1);
  int m = v >> 8;
  int d0 = dv * 8;
  int t = m & (TDIM - 1);
  int sp = segp[m];
  float acc[8];
#pragma unroll
  for (int j = 0; j < 8; ++j) acc[j] = cb[d0 + j];
#pragma unroll
  for (int i = 0; i < 4; ++i) {
    int shift = 3 - i;
    if (t >= shift && sp >= shift) {
      bf16x8 xv = *(const bf16x8*)&xp[(size_t)(m - shift) * DDIM + d0];
#pragma unroll
      for (int j = 0; j < 8; ++j) acc[j] = fmaf((float)xv[j], cw[i * DDIM + d0 + j], acc[j]);
    }
  }
  bf16x8 o;
#pragma unroll
  for (int j = 0; j < 8; ++j) o[j] = (bf16)acc[j];
  *(bf16x8*)&xc[(size_t)m * DDIM + d0] = o;
}

// ---------------------------------------------------------------------------
// transpose + convert gate weights: dst[h][j][i] = (bf16)src[h][i][j]
// ---------------------------------------------------------------------------
__global__ __launch_bounds__(256) void transpose_gates(
    const float* __restrict__ gxw, const float* __restrict__ gaw,
    bf16* __restrict__ gxT, bf16* __restrict__ gaT) {
  __shared__ bf16 tile[32][33];
  int zz = blockIdx.z;
  int h = zz >> 1;
  const float* src = (zz & 1) ? gaw : gxw;
  bf16* dst = (zz & 1) ? gaT : gxT;
  int j0 = blockIdx.x * 32;
  int i0 = blockIdx.y * 32;
  int r = threadIdx.x >> 5;
  int c = threadIdx.x & 31;
  for (int rr = r; rr < 32; rr += 8)
    tile[rr][c] = (bf16)src[(size_t)(h * DHD + i0 + rr) * DHD + j0 + c];
  __syncthreads();
  for (int rr = r; rr < 32; rr += 8)
    dst[(size_t)(h * DHD + j0 + rr) * DHD + i0 + c] = tile[c][rr];
}

// ---------------------------------------------------------------------------
// RG-LRU elementwise recompute, shared by scan phases
// ---------------------------------------------------------------------------
__device__ __forceinline__ void lru_elem(float pgx, float pga, float xc,
                                         float spv, bool reset,
                                         float& a, float& nr) {
  const float gx = sigmoid_f(pgx);
  const float ga = sigmoid_f(pga);
  const float la = -8.f * ga * spv;
  a = reset ? 0.f : __expf(la);
  const float mult = reset ? 1.f : sqrtf(fmaxf(1.f - __expf(2.f * la), 0.f));
  nr = xc * gx * mult;
}

// chunked scan phase 1 — VEC=4 (8 B/lane loads, G13 sweet spot) at 512
// blocks = 2 blocks/CU (8 waves/CU): same in-flight bytes as scalar but
// 4x fewer VMEM issue slots. (Round-11 VEC=8 at 1 wave/SIMD was
// latency-bound and regressed.)
__global__ __launch_bounds__(256) void scan_phase1(
    const bf16* __restrict__ gxr, const bf16* __restrict__ gar,
    const bf16* __restrict__ xconv,
    const float* __restrict__ gxb, const float* __restrict__ gab,
    const float* __restrict__ apar, const int* __restrict__ segp,
    float* __restrict__ chA, float* __restrict__ chH) {
  int idx = blockIdx.x * 256 + threadIdx.x;     // B*NCHUNK*(DDIM/4) = 131072
  int dv = idx & (DDIM / 4 - 1);
  int c = (idx >> 9) & (NCHUNK - 1);
  int b = idx >> 15;
  int d0 = dv * 4;
  const float4 gx4 = *(const float4*)(gxb + d0);
  const float4 ga4 = *(const float4*)(gab + d0);
  const float4 ap4 = *(const float4*)(apar + d0);
  float gxbv[4] = {gx4.x, gx4.y, gx4.z, gx4.w};
  float gabv[4] = {ga4.x, ga4.y, ga4.z, ga4.w};
  float spv[4]  = {softplus_f(ap4.x), softplus_f(ap4.y),
                   softplus_f(ap4.z), softplus_f(ap4.w)};
  const int mrow = b * TDIM + c * LCHUNK;
  size_t base = (size_t)mrow * DDIM + d0;
  float A[4] = {1.f, 1.f, 1.f, 1.f}, hh[4] = {0.f, 0.f, 0.f, 0.f};
  for (int i = 0; i < LCHUNK; ++i) {
    size_t o = base + (size_t)i * DDIM;
    bf16x4 g1 = *(const bf16x4*)&gxr[o];
    bf16x4 g2 = *(const bf16x4*)&gar[o];
    bf16x4 xv = *(const bf16x4*)&xconv[o];
    bool rst = (segp[mrow + i] == 0);
#pragma unroll
    for (int j = 0; j < 4; ++j) {
      float a, nr;
      lru_elem((float)g1[j] + gxbv[j], (float)g2[j] + gabv[j], (float)xv[j],
               spv[j], rst, a, nr);
      hh[j] = fmaf(a, hh[j], nr);
      A[j] *= a;
    }
  }
  size_t ci = (size_t)(b * NCHUNK + c) * DDIM + d0;
  *(f32x4*)&chA[ci] = f32x4{A[0], A[1], A[2], A[3]};
  *(f32x4*)&chH[ci] = f32x4{hh[0], hh[1], hh[2], hh[3]};
}

__global__ __launch_bounds__(256) void scan_phase2(
    const float* __restrict__ chA, const float* __restrict__ chH,
    float* __restrict__ hst) {
  int idx = blockIdx.x * 64 + threadIdx.x;   // 64-thread blocks -> 128 CUs
  int d = idx & (DDIM - 1);
  int b = idx >> 11;
  float s = 0.f;
  for (int c = 0; c < NCHUNK; ++c) {
    int ci = (b * NCHUNK + c) * DDIM + d;
    hst[ci] = s;
    s = fmaf(chA[ci], s, chH[ci]);
  }
}

// phase 3 — VEC=4: replay with chunk-start state; z = h*y in-place over y
__global__ __launch_bounds__(256) void scan_phase3(
    const bf16* __restrict__ gxr, const bf16* __restrict__ gar,
    const bf16* __restrict__ xconv,
    const float* __restrict__ gxb, const float* __restrict__ gab,
    const float* __restrict__ apar, const int* __restrict__ segp,
    const float* __restrict__ hst, bf16* __restrict__ yz) {
  int idx = blockIdx.x * 256 + threadIdx.x;
  int dv = idx & (DDIM / 4 - 1);
  int c = (idx >> 9) & (NCHUNK - 1);
  int b = idx >> 15;
  int d0 = dv * 4;
  const float4 gx4 = *(const float4*)(gxb + d0);
  const float4 ga4 = *(const float4*)(gab + d0);
  const float4 ap4 = *(const float4*)(apar + d0);
  float gxbv[4] = {gx4.x, gx4.y, gx4.z, gx4.w};
  float gabv[4] = {ga4.x, ga4.y, ga4.z, ga4.w};
  float spv[4]  = {softplus_f(ap4.x), softplus_f(ap4.y),
                   softplus_f(ap4.z), softplus_f(ap4.w)};
  const int mrow = b * TDIM + c * LCHUNK;
  size_t base = (size_t)mrow * DDIM + d0;
  size_t ci = (size_t)(b * NCHUNK + c) * DDIM + d0;
  const float4 h4 = *(const float4*)(hst + ci);
  float hh[4] = {h4.x, h4.y, h4.z, h4.w};
  for (int i = 0; i < LCHUNK; ++i) {
    size_t o = base + (size_t)i * DDIM;
    bf16x4 g1 = *(const bf16x4*)&gxr[o];
    bf16x4 g2 = *(const bf16x4*)&gar[o];
    bf16x4 xv = *(const bf16x4*)&xconv[o];
    bf16x4 y4 = *(const bf16x4*)&yz[o];
    bool rst = (segp[mrow + i] == 0);
    bf16x4 out;
#pragma unroll
    for (int j = 0; j < 4; ++j) {
      float a, nr;
      lru_elem((float)g1[j] + gxbv[j], (float)g2[j] + gabv[j], (float)xv[j],
               spv[j], rst, a, nr);
      hh[j] = fmaf(a, hh[j], nr);
      out[j] = (bf16)(hh[j] * (float)y4[j]);
    }
    *(bf16x4*)&yz[o] = out;
  }
}

// ---------------------------------------------------------------------------
extern "C" void kernel_launch(void* const* d_in, const int* in_sizes, int n_in,
                              void* d_out, int out_size, void* d_ws, size_t ws_size,
                              hipStream_t stream) {
  const float* x    = (const float*)d_in[0];
  const int*   segp = (const int*)d_in[1];
  const float* Wy   = (const float*)d_in[2];
  const float* by   = (const float*)d_in[3];
  const float* Wx   = (const float*)d_in[4];
  const float* bx   = (const float*)d_in[5];
  const float* cw   = (const float*)d_in[6];
  const float* cb   = (const float*)d_in[7];
  const float* gxw  = (const float*)d_in[8];
  const float* gxb  = (const float*)d_in[9];
  const float* gaw  = (const float*)d_in[10];
  const float* gab  = (const float*)d_in[11];
  const float* apar = (const float*)d_in[12];
  const float* Wout = (const float*)d_in[13];
  const float* bout = (const float*)d_in[14];

  const size_t MD = (size_t)MTOT * DDIM;       // 16.78M elements
  const size_t WD = (size_t)DDIM * DDIM;       // 4.19M elements
  // d_out (fp32, 67 MB) as bf16 scratch until the final GEMM:
  bf16* xb    = (bf16*)d_out;                   // lower: xb -> xconv
  bf16* xproj = (bf16*)((char*)d_out + MD * 2); // upper: xproj -> gxr
  bf16* xconv = xb;
  bf16* gxr   = xproj;

  // ws (~92 MB): gar | W1 | WB1 | WB2 | gxT | gaT | chA | chH | hst
  char* ws = (char*)d_ws;
  bf16*  gar = (bf16*)ws;                        // 33.5 MB
  bf16*  W1  = (bf16*)(ws + MD * 2);             // y -> z (33.5 MB)
  bf16*  WB1 = (bf16*)(ws + 2 * MD * 2);         // Wxb, later Woutb (8.4 MB)
  bf16*  WB2 = (bf16*)(ws + 2 * MD * 2 + WD * 2);// Wyb (8.4 MB)
  char*  tail = ws + 2 * MD * 2 + 2 * WD * 2;
  const size_t GW = (size_t)HDIM * DHD * DHD * 2;      // 1 MiB
  const size_t CH = (size_t)BDIM * NCHUNK * DDIM * 4;  // 2 MiB
  bf16*  gxT = (bf16*)tail;
  bf16*  gaT = (bf16*)(tail + GW);
  float* chA = (float*)(tail + 2 * GW);
  float* chH = (float*)(tail + 2 * GW + CH);
  float* hst = (float*)(tail + 2 * GW + 2 * CH);

  dim3 blk(256);
  f2b<<<dim3(MD / 2048), blk, 0, stream>>>(x, xb);
  f2b2<<<dim3(WD / 2048, 2), blk, 0, stream>>>(Wx, Wy, WB1, WB2);
  transpose_gates<<<dim3(8, 8, 16), blk, 0, stream>>>(gxw, gaw, gxT, gaT);

  // DUAL GEMM (z=0: xproj = x@Wx^T+bx ; z=1: y = gelu(x@Wy^T+by)) —
  // measured 151 us for both (rounds 10/11, MfmaUtil 41%).
  gemm128<bf16><<<dim3(16, 64, 2), blk, 0, stream>>>(
      xb, WB1, WB2, bx, by, xproj, W1, 1, DDIM, DDIM, DDIM, DDIM);

  // xconv in-place over xb (reads xproj; xb dead after the dual GEMM)
  conv_kernel<<<dim3(MTOT * (DDIM / 8) / 256), blk, 0, stream>>>(xproj, cw, cb, segp, xconv);

  // gate pre-activations: gxr over xproj (dead), gar in ws
  gate_gemm<<<dim3(2, 64, 16), blk, 0, stream>>>(xconv, gxT, gaT, gxr, gar);

  // chunked scan, VEC=4 (512 blocks = 2 blocks/CU for phases 1/3)
  scan_phase1<<<dim3(BDIM * NCHUNK * (DDIM / 4) / 256), blk, 0, stream>>>(
      gxr, gar, xconv, gxb, gab, apar, segp, chA, chH);
  scan_phase2<<<dim3(BDIM * DDIM / 64), dim3(64), 0, stream>>>(chA, chH, hst);
  scan_phase3<<<dim3(BDIM * NCHUNK * (DDIM / 4) / 256), blk, 0, stream>>>(
      gxr, gar, xconv, gxb, gab, apar, segp, hst, W1);

  // out = z @ Wout^T + bout — round-7 gemm256 (measured 77.5-85 us)
  f2b<<<dim3(WD / 2048), blk, 0, stream>>>(Wout, WB1);
  gemm256<float, 0><<<dim3(8, 32), dim3(512), 0, stream>>>(
      W1, WB1, bout, (float*)d_out, DDIM, DDIM, DDIM, DDIM);
}

// Round 14
// 412.476 us; speedup vs baseline: 1.0861x; 1.0100x over previous
//
#include <hip/hip_runtime.h>
#include <cstdint>
#include <cstddef>

typedef __bf16 bf16;
typedef __bf16 bf16x8 __attribute__((ext_vector_type(8)));
typedef __bf16 bf16x4 __attribute__((ext_vector_type(4)));
typedef float f32x4 __attribute__((ext_vector_type(4)));

#define BDIM 4
#define TDIM 2048
#define DDIM 2048
#define HDIM 8
#define DHD 256
#define MTOT 8192
#define NCHUNK 64
#define LCHUNK 32

// async 16B global->LDS; LDS dest = wave-uniform base + lane*16
__device__ __forceinline__ void stage16(const bf16* g, bf16* l) {
  __builtin_amdgcn_global_load_lds(
      (const __attribute__((address_space(1))) void*)g,
      (__attribute__((address_space(3))) void*)l, 16, 0, 0);
}

// intrinsic barrier (no implicit drain); BARE asm waitcnt (no "memory"
// clobber -> no compiler-inserted full drain; round-6 lesson).
#define BARX() __builtin_amdgcn_s_barrier()
#define SCHB() __builtin_amdgcn_sched_barrier(0)
#define WAITVM(N) asm volatile("s_waitcnt vmcnt(" #N ")")

__device__ __forceinline__ float sigmoid_f(float x) {
  return __fdividef(1.f, 1.f + __expf(-x));
}
__device__ __forceinline__ float gelu_tanh(float v) {
  float u = 0.7978845608028654f * (v + 0.044715f * v * v * v);
  u = fminf(fmaxf(u, -15.f), 15.f);
  float t = __expf(2.f * u);                       // tanh(u) = (t-1)/(t+1)
  return 0.5f * v * (1.f + __fdividef(t - 1.f, t + 1.f));
}
__device__ __forceinline__ float softplus_f(float x) {
  return __logf(1.f + __expf(x));                  // x in [-1.2, 0.4] here
}

__device__ __forceinline__ void f2b_body(const float* __restrict__ src,
                                         bf16* __restrict__ dst, int vb) {
  size_t i = ((size_t)vb * 256 + threadIdx.x) * 8;
  const float4 a = *(const float4*)(src + i);
  const float4 b = *(const float4*)(src + i + 4);
  bf16x8 r;
  r[0] = (bf16)a.x; r[1] = (bf16)a.y; r[2] = (bf16)a.z; r[3] = (bf16)a.w;
  r[4] = (bf16)b.x; r[5] = (bf16)b.y; r[6] = (bf16)b.z; r[7] = (bf16)b.w;
  *(bf16x8*)(dst + i) = r;
}

// ---------------------------------------------------------------------------
// fused fp32->bf16 convert: x (8192 blk) | Wx (2048 blk) | Wy (2048 blk)
// ---------------------------------------------------------------------------
__global__ __launch_bounds__(256) void f2b3(
    const float* __restrict__ x, bf16* __restrict__ xb,
    const float* __restrict__ Wx, bf16* __restrict__ WB1,
    const float* __restrict__ Wy, bf16* __restrict__ WB2) {
  int b = blockIdx.x;
  if (b < 8192)       f2b_body(x, xb, b);
  else if (b < 10240) f2b_body(Wx, WB1, b - 8192);
  else                f2b_body(Wy, WB2, b - 10240);
}

// ---------------------------------------------------------------------------
// gemm256: round-7 kernel VERBATIM (measured 77.5-86 us, final GEMM).
// ---------------------------------------------------------------------------
template <typename TO, int EPI>
__global__ __launch_bounds__(512, 2) void gemm256(
    const bf16* __restrict__ A, const bf16* __restrict__ Bm,
    const float* __restrict__ bias, TO* __restrict__ C,
    int K, int lda, int ldb, int ldc) {
  const int gx = gridDim.x, gy = gridDim.y;
  const int nwg = gx * gy;
  const int did = blockIdx.x + gx * blockIdx.y;
  const int cpx = nwg >> 3;                       // chunk per XCD
  const int lid = (did & 7) * cpx + (did >> 3);
  const int n0 = (lid % gx) * 256;
  const int m0 = (lid / gx) * 256;

  __shared__ bf16 sA0[256 * 64];
  __shared__ bf16 sA1[256 * 64];
  __shared__ bf16 sB0[256 * 64];
  __shared__ bf16 sB1[256 * 64];
  const int tid = threadIdx.x;
  const int lane = tid & 63;
  const int wid = tid >> 6;         // 0..7
  const int wr = wid >> 2;          // M-half of tile (128 rows)
  const int wc = wid & 3;           // N-quarter (64 cols)
  const int quad = lane >> 4;
  const int l15 = lane & 15;

  const int sr = tid >> 3;                        // 0..63
  const int ks8 = ((tid & 7) ^ (sr & 7)) << 3;    // element offset in 64-wide row
  const bf16* Ag = A + (size_t)(m0 + sr) * lda + ks8;
  const bf16* Bg = Bm + (size_t)(n0 + sr) * ldb + ks8;

  const int swz0 = ((quad) ^ (l15 & 7)) << 3;
  const int swz1 = ((4 + quad) ^ (l15 & 7)) << 3;

  f32x4 acc[8][4];
#pragma unroll
  for (int i = 0; i < 8; ++i)
#pragma unroll
    for (int j = 0; j < 4; ++j)
#pragma unroll
      for (int r = 0; r < 4; ++r) acc[i][j][r] = 0.f;

  const int NT = K >> 6;

#define STG_A(ARR, H, TK)                                                     \
  do {                                                                        \
    _Pragma("unroll") for (int j_ = 0; j_ < 2; ++j_) {                        \
      const int c_ = (H) * 2 + j_;                                            \
      stage16(Ag + (size_t)(c_ * 64) * lda + (size_t)(TK) * 64,               \
              &ARR[(c_ * 64 + wid * 8) * 64]);                                \
    }                                                                         \
  } while (0)
#define STG_B(ARR, H, TK)                                                     \
  do {                                                                        \
    _Pragma("unroll") for (int j_ = 0; j_ < 2; ++j_) {                        \
      const int c_ = (H) * 2 + j_;                                            \
      stage16(Bg + (size_t)(c_ * 64) * ldb + (size_t)(TK) * 64,               \
              &ARR[(c_ * 64 + wid * 8) * 64]);                                \
    }                                                                         \
  } while (0)

  bf16x8 aq0[4][2], aq1[4][2], b0[2][2], b1[2][2];

#define RDA(DST, MH, ARR)                                                     \
  do {                                                                        \
    _Pragma("unroll") for (int mi_ = 0; mi_ < 4; ++mi_) {                     \
      const int arow_ = wr * 128 + (MH) * 64 + mi_ * 16 + l15;                \
      DST[mi_][0] = *(const bf16x8*)(&ARR[arow_ * 64] + swz0);                \
      DST[mi_][1] = *(const bf16x8*)(&ARR[arow_ * 64] + swz1);                \
    }                                                                         \
  } while (0)
#define RDB(DST, NH, ARR)                                                     \
  do {                                                                        \
    _Pragma("unroll") for (int ni_ = 0; ni_ < 2; ++ni_) {                     \
      const int brow_ = wc * 64 + (NH) * 32 + ni_ * 16 + l15;                 \
      DST[ni_][0] = *(const bf16x8*)(&ARR[brow_ * 64] + swz0);                \
      DST[ni_][1] = *(const bf16x8*)(&ARR[brow_ * 64] + swz1);                \
    }                                                                         \
  } while (0)
#define MFMAQ(MH, NH, AA, BB)                                                 \
  do {                                                                        \
    __builtin_amdgcn_s_setprio(1);                                            \
    _Pragma("unroll") for (int mi_ = 0; mi_ < 4; ++mi_)                       \
        _Pragma("unroll") for (int ni_ = 0; ni_ < 2; ++ni_) {                 \
      acc[(MH)*4 + mi_][(NH)*2 + ni_] = __builtin_amdgcn_mfma_f32_16x16x32_bf16( \
          AA[mi_][0], BB[ni_][0], acc[(MH)*4 + mi_][(NH)*2 + ni_], 0, 0, 0);  \
      acc[(MH)*4 + mi_][(NH)*2 + ni_] = __builtin_amdgcn_mfma_f32_16x16x32_bf16( \
          AA[mi_][1], BB[ni_][1], acc[(MH)*4 + mi_][(NH)*2 + ni_], 0, 0, 0);  \
    }                                                                         \
    __builtin_amdgcn_s_setprio(0);                                            \
  } while (0)

#define TILE(SAs, SBs, SAo, SBo, T)                                           \
  do {                                                                        \
    const int tn_ = ((T) + 1 < NT) ? (T) + 1 : NT - 1;                        \
    const int tnn_ = ((T) + 2 < NT) ? (T) + 2 : NT - 1;                       \
    /* ph1 */                                                                 \
    WAITVM(4);                                                                \
    SCHB();                                                                   \
    STG_B(SBo, 1, tn_);                                                       \
    RDB(b1, 1, SBs);                                                          \
    MFMAQ(0, 0, aq0, b0);                                                     \
    BARX();                                                                   \
    /* ph2 */                                                                 \
    STG_A(SAo, 1, tn_);                                                       \
    RDA(aq1, 1, SAs);                                                         \
    MFMAQ(0, 1, aq0, b1);                                                     \
    BARX();                                                                   \
    /* ph3 */                                                                 \
    STG_B(SBs, 0, tnn_);                                                      \
    MFMAQ(1, 0, aq1, b0);                                                     \
    BARX();                                                                   \
    /* ph4 */                                                                 \
    WAITVM(6);                                                                \
    SCHB();                                                                   \
    if (T + 1 < NT) {                                                         \
      RDA(aq0, 0, SAo);                                                       \
      RDB(b0, 0, SBo);                                                        \
    }                                                                         \
    STG_A(SAs, 0, tnn_);                                                      \
    MFMAQ(1, 1, aq1, b1);                                                     \
    BARX();                                                                   \
  } while (0)

  // prologue: tile0 fully + tile1 khalf0 (12 loads, chronological order)
  STG_B(sB0, 0, 0); STG_A(sA0, 0, 0);
  STG_B(sB0, 1, 0); STG_A(sA0, 1, 0);
  STG_B(sB1, 0, 1); STG_A(sA1, 0, 1);
  WAITVM(8);                          // retire HB0(0), HA0(0)
  SCHB();
  BARX();
  RDA(aq0, 0, sA0);                   // sub0(0)
  RDB(b0, 0, sB0);                    // nh0(0)

  for (int t = 0; t < NT; t += 2) {   // NT even (K%128==0)
    TILE(sA0, sB0, sA1, sB1, t);
    TILE(sA1, sB1, sA0, sB0, t + 1);
  }
  WAITVM(0);                          // drain tail stages (hygiene)

#undef STG_A
#undef STG_B
#undef RDA
#undef RDB
#undef MFMAQ
#undef TILE

  // epilogue: row-major store bursts — 4 consecutive stores per quad-row
  float bv[4];
#pragma unroll
  for (int nn = 0; nn < 4; ++nn) bv[nn] = bias[n0 + wc * 64 + nn * 16 + l15];
#pragma unroll
  for (int mm = 0; mm < 8; ++mm) {
#pragma unroll
    for (int r = 0; r < 4; ++r) {
      const int m = m0 + wr * 128 + mm * 16 + quad * 4 + r;
      TO* Crow = C + (size_t)m * ldc + n0 + wc * 64 + l15;
#pragma unroll
      for (int nn = 0; nn < 4; ++nn) {
        float v = acc[mm][nn][r] + bv[nn];
        if (EPI == 1) v = gelu_tanh(v);
        Crow[nn * 16] = (TO)v;
      }
    }
  }
}

// ---------------------------------------------------------------------------
// gemm128: round-10 kernel VERBATIM (dual-z = 151 us for both projections).
// ---------------------------------------------------------------------------
template <typename TO>
__global__ __launch_bounds__(256, 2) void gemm128(
    const bf16* __restrict__ A,
    const bf16* __restrict__ B0m, const bf16* __restrict__ B1m,
    const float* __restrict__ bias0, const float* __restrict__ bias1,
    TO* __restrict__ C0, TO* __restrict__ C1, int epi1,
    int K, int lda, int ldb, int ldc) {
  const bf16* Bm = blockIdx.z ? B1m : B0m;
  const float* bias = blockIdx.z ? bias1 : bias0;
  TO* C = blockIdx.z ? C1 : C0;
  const int EPI = blockIdx.z ? epi1 : 0;

  const int gx = gridDim.x, gy = gridDim.y;
  const int nwg = gx * gy;
  const int did = blockIdx.x + gx * blockIdx.y;
  const int cpx = nwg >> 3;                       // chunk per XCD
  const int lid = (did & 7) * cpx + (did >> 3);
  const int n0 = (lid % gx) * 128;
  const int m0 = (lid / gx) * 128;

  __shared__ bf16 sA0[128 * 64];
  __shared__ bf16 sA1[128 * 64];
  __shared__ bf16 sB0[128 * 64];
  __shared__ bf16 sB1[128 * 64];
  const int tid = threadIdx.x;
  const int lane = tid & 63;
  const int wid = tid >> 6;         // 0..3
  const int wr = wid >> 1;          // M-half (64 rows)
  const int wc = wid & 1;           // N-half (64 cols)
  const int quad = lane >> 4;
  const int l15 = lane & 15;

  const int sr = tid >> 3;                        // 0..31
  const int ks8 = ((tid & 7) ^ (sr & 7)) << 3;
  const bf16* Ag = A + (size_t)(m0 + sr) * lda + ks8;
  const bf16* Bg = Bm + (size_t)(n0 + sr) * ldb + ks8;

  const int swz0 = ((quad) ^ (l15 & 7)) << 3;
  const int swz1 = ((4 + quad) ^ (l15 & 7)) << 3;

  f32x4 acc[4][4];
#pragma unroll
  for (int i = 0; i < 4; ++i)
#pragma unroll
    for (int j = 0; j < 4; ++j)
#pragma unroll
      for (int r = 0; r < 4; ++r) acc[i][j][r] = 0.f;

  const int NT = K >> 6;

#define STG_A(ARR, TK)                                                        \
  do {                                                                        \
    _Pragma("unroll") for (int c_ = 0; c_ < 4; ++c_)                          \
        stage16(Ag + (size_t)(c_ * 32) * lda + (size_t)(TK) * 64,             \
                &ARR[(c_ * 32 + wid * 8) * 64]);                              \
  } while (0)
#define STG_B(ARR, TK)                                                        \
  do {                                                                        \
    _Pragma("unroll") for (int c_ = 0; c_ < 4; ++c_)                          \
        stage16(Bg + (size_t)(c_ * 32) * ldb + (size_t)(TK) * 64,             \
                &ARR[(c_ * 32 + wid * 8) * 64]);                              \
  } while (0)

  bf16x8 af[4][2], b0[2][2], b1[2][2];

#define RDA(ARR)                                                              \
  do {                                                                        \
    _Pragma("unroll") for (int mi_ = 0; mi_ < 4; ++mi_) {                     \
      const int arow_ = wr * 64 + mi_ * 16 + l15;                             \
      af[mi_][0] = *(const bf16x8*)(&ARR[arow_ * 64] + swz0);                 \
      af[mi_][1] = *(const bf16x8*)(&ARR[arow_ * 64] + swz1);                 \
    }                                                                         \
  } while (0)
#define RDB(DST, NH, ARR)                                                     \
  do {                                                                        \
    _Pragma("unroll") for (int ni_ = 0; ni_ < 2; ++ni_) {                     \
      const int brow_ = wc * 64 + (NH) * 32 + ni_ * 16 + l15;                 \
      DST[ni_][0] = *(const bf16x8*)(&ARR[brow_ * 64] + swz0);                \
      DST[ni_][1] = *(const bf16x8*)(&ARR[brow_ * 64] + swz1);                \
    }                                                                         \
  } while (0)
#define MFMAQ(NH, BB)                                                         \
  do {                                                                        \
    __builtin_amdgcn_s_setprio(1);                                            \
    _Pragma("unroll") for (int mi_ = 0; mi_ < 4; ++mi_)                       \
        _Pragma("unroll") for (int ni_ = 0; ni_ < 2; ++ni_) {                 \
      acc[mi_][(NH)*2 + ni_] = __builtin_amdgcn_mfma_f32_16x16x32_bf16(       \
          af[mi_][0], BB[ni_][0], acc[mi_][(NH)*2 + ni_], 0, 0, 0);           \
      acc[mi_][(NH)*2 + ni_] = __builtin_amdgcn_mfma_f32_16x16x32_bf16(       \
          af[mi_][1], BB[ni_][1], acc[mi_][(NH)*2 + ni_], 0, 0, 0);           \
    }                                                                         \
    __builtin_amdgcn_s_setprio(0);                                            \
  } while (0)

#define TILE(SAs, SBs, SAo, SBo, T)                                           \
  do {                                                                        \
    const int tn_ = ((T) + 1 < NT) ? (T) + 1 : NT - 1;                        \
    const int tnn_ = ((T) + 2 < NT) ? (T) + 2 : NT - 1;                       \
    /* ph1 */                                                                 \
    RDA(SAs);                                                                 \
    RDB(b0, 0, SBs);                                                          \
    STG_B(SBo, tn_);                                                          \
    MFMAQ(0, b0);                                                             \
    BARX();                                                                   \
    /* ph2 */                                                                 \
    RDB(b1, 1, SBs);                                                          \
    STG_A(SAs, tnn_);                                                         \
    MFMAQ(1, b1);                                                             \
    WAITVM(4);                                                                \
    BARX();                                                                   \
  } while (0)

  // prologue: tiles 0,1 (16 loads, chronological); WAITVM(4) leaves A(1)
  const int t1 = (NT > 1) ? 1 : 0;
  STG_B(sB0, 0); STG_A(sA0, 0);
  STG_B(sB1, t1); STG_A(sA1, t1);
  WAITVM(4);
  SCHB();
  BARX();

  for (int t = 0; t < NT; t += 2) {   // NT even (K%128==0)
    TILE(sA0, sB0, sA1, sB1, t);
    TILE(sA1, sB1, sA0, sB0, t + 1);
  }
  WAITVM(0);                          // drain tail stages (hygiene)

#undef STG_A
#undef STG_B
#undef RDA
#undef RDB
#undef MFMAQ
#undef TILE

  float bv[4];
#pragma unroll
  for (int nn = 0; nn < 4; ++nn) bv[nn] = bias[n0 + wc * 64 + nn * 16 + l15];
#pragma unroll
  for (int mm = 0; mm < 4; ++mm) {
#pragma unroll
    for (int r = 0; r < 4; ++r) {
      const int m = m0 + wr * 64 + mm * 16 + quad * 4 + r;
      TO* Crow = C + (size_t)m * ldc + n0 + wc * 64 + l15;
#pragma unroll
      for (int nn = 0; nn < 4; ++nn) {
        float v = acc[mm][nn][r] + bv[nn];
        if (EPI == 1) v = gelu_tanh(v);
        Crow[nn * 16] = (TO)v;
      }
    }
  }
}

// ---------------------------------------------------------------------------
// gate128: gate pre-activation GEMM in the gemm128 2-phase counted-vmcnt
// structure (replaces old 2-syncthreads/K-step gate_gemm). z = h*2+g,
// K = DHD = 256 -> NT = 4 (even; ledger induction holds for NT>=2 even).
// out[m, h*DHD+n] = sum_k xconv[m, h*DHD+k] * W[g][h][n][k], no bias.
// ---------------------------------------------------------------------------
__global__ __launch_bounds__(256, 2) void gate128(
    const bf16* __restrict__ xconv,
    const bf16* __restrict__ gxT, const bf16* __restrict__ gaT,
    bf16* __restrict__ gxr, bf16* __restrict__ gar) {
  const int h = blockIdx.z >> 1;
  const int g = blockIdx.z & 1;
  const bf16* A = xconv + h * DHD;                           // lda = DDIM
  const bf16* Bm = (g ? gaT : gxT) + (size_t)h * DHD * DHD;  // ldb = DHD
  bf16* C = (g ? gar : gxr) + h * DHD;                       // ldc = DDIM

  const int gx = gridDim.x, gy = gridDim.y;
  const int nwg = gx * gy;                        // 128, %8==0
  const int did = blockIdx.x + gx * blockIdx.y;
  const int cpx = nwg >> 3;
  const int lid = (did & 7) * cpx + (did >> 3);
  const int n0 = (lid % gx) * 128;
  const int m0 = (lid / gx) * 128;

  __shared__ bf16 sA0[128 * 64];
  __shared__ bf16 sA1[128 * 64];
  __shared__ bf16 sB0[128 * 64];
  __shared__ bf16 sB1[128 * 64];
  const int tid = threadIdx.x;
  const int lane = tid & 63;
  const int wid = tid >> 6;
  const int wr = wid >> 1;
  const int wc = wid & 1;
  const int quad = lane >> 4;
  const int l15 = lane & 15;

  const int sr = tid >> 3;
  const int ks8 = ((tid & 7) ^ (sr & 7)) << 3;
  const bf16* Ag = A + (size_t)(m0 + sr) * DDIM + ks8;
  const bf16* Bg = Bm + (size_t)(n0 + sr) * DHD + ks8;

  const int swz0 = ((quad) ^ (l15 & 7)) << 3;
  const int swz1 = ((4 + quad) ^ (l15 & 7)) << 3;

  f32x4 acc[4][4];
#pragma unroll
  for (int i = 0; i < 4; ++i)
#pragma unroll
    for (int j = 0; j < 4; ++j)
#pragma unroll
      for (int r = 0; r < 4; ++r) acc[i][j][r] = 0.f;

  const int NT = 4;                                // K = 256

#define STG_A(ARR, TK)                                                        \
  do {                                                                        \
    _Pragma("unroll") for (int c_ = 0; c_ < 4; ++c_)                          \
        stage16(Ag + (size_t)(c_ * 32) * DDIM + (size_t)(TK) * 64,            \
                &ARR[(c_ * 32 + wid * 8) * 64]);                              \
  } while (0)
#define STG_B(ARR, TK)                                                        \
  do {                                                                        \
    _Pragma("unroll") for (int c_ = 0; c_ < 4; ++c_)                          \
        stage16(Bg + (size_t)(c_ * 32) * DHD + (size_t)(TK) * 64,             \
                &ARR[(c_ * 32 + wid * 8) * 64]);                              \
  } while (0)

  bf16x8 af[4][2], b0[2][2], b1[2][2];

#define RDA(ARR)                                                              \
  do {                                                                        \
    _Pragma("unroll") for (int mi_ = 0; mi_ < 4; ++mi_) {                     \
      const int arow_ = wr * 64 + mi_ * 16 + l15;                             \
      af[mi_][0] = *(const bf16x8*)(&ARR[arow_ * 64] + swz0);                 \
      af[mi_][1] = *(const bf16x8*)(&ARR[arow_ * 64] + swz1);                 \
    }                                                                         \
  } while (0)
#define RDB(DST, NH, ARR)                                                     \
  do {                                                                        \
    _Pragma("unroll") for (int ni_ = 0; ni_ < 2; ++ni_) {                     \
      const int brow_ = wc * 64 + (NH) * 32 + ni_ * 16 + l15;                 \
      DST[ni_][0] = *(const bf16x8*)(&ARR[brow_ * 64] + swz0);                \
      DST[ni_][1] = *(const bf16x8*)(&ARR[brow_ * 64] + swz1);                \
    }                                                                         \
  } while (0)
#define MFMAQ(NH, BB)                                                         \
  do {                                                                        \
    __builtin_amdgcn_s_setprio(1);                                            \
    _Pragma("unroll") for (int mi_ = 0; mi_ < 4; ++mi_)                       \
        _Pragma("unroll") for (int ni_ = 0; ni_ < 2; ++ni_) {                 \
      acc[mi_][(NH)*2 + ni_] = __builtin_amdgcn_mfma_f32_16x16x32_bf16(       \
          af[mi_][0], BB[ni_][0], acc[mi_][(NH)*2 + ni_], 0, 0, 0);           \
      acc[mi_][(NH)*2 + ni_] = __builtin_amdgcn_mfma_f32_16x16x32_bf16(       \
          af[mi_][1], BB[ni_][1], acc[mi_][(NH)*2 + ni_], 0, 0, 0);           \
    }                                                                         \
    __builtin_amdgcn_s_setprio(0);                                            \
  } while (0)

#define TILE(SAs, SBs, SAo, SBo, T)                                           \
  do {                                                                        \
    const int tn_ = ((T) + 1 < NT) ? (T) + 1 : NT - 1;                        \
    const int tnn_ = ((T) + 2 < NT) ? (T) + 2 : NT - 1;                       \
    RDA(SAs);                                                                 \
    RDB(b0, 0, SBs);                                                          \
    STG_B(SBo, tn_);                                                          \
    MFMAQ(0, b0);                                                             \
    BARX();                                                                   \
    RDB(b1, 1, SBs);                                                          \
    STG_A(SAs, tnn_);                                                         \
    MFMAQ(1, b1);                                                             \
    WAITVM(4);                                                                \
    BARX();                                                                   \
  } while (0)

  STG_B(sB0, 0); STG_A(sA0, 0);
  STG_B(sB1, 1); STG_A(sA1, 1);
  WAITVM(4);
  SCHB();
  BARX();

  for (int t = 0; t < NT; t += 2) {
    TILE(sA0, sB0, sA1, sB1, t);
    TILE(sA1, sB1, sA0, sB0, t + 1);
  }
  WAITVM(0);

#undef STG_A
#undef STG_B
#undef RDA
#undef RDB
#undef MFMAQ
#undef TILE

#pragma unroll
  for (int mm = 0; mm < 4; ++mm) {
#pragma unroll
    for (int r = 0; r < 4; ++r) {
      const int m = m0 + wr * 64 + mm * 16 + quad * 4 + r;
      bf16* Crow = C + (size_t)m * DDIM + n0 + wc * 64 + l15;
#pragma unroll
      for (int nn = 0; nn < 4; ++nn)
        Crow[nn * 16] = (bf16)acc[mm][nn][r];
    }
  }
}

// ---------------------------------------------------------------------------
// depthwise causal conv, TW=4 (blocks 0..8191) + Wout f2b rider (2048 blocks;
// WB1 is dead after the dual projection GEMM, which precedes this launch).
// ---------------------------------------------------------------------------
__global__ __launch_bounds__(256) void conv_kernel(
    const bf16* __restrict__ xp, const float* __restrict__ cw,
    const float* __restrict__ cb, const int* __restrict__ segp,
    bf16* __restrict__ xc,
    const float* __restrict__ Wout, bf16* __restrict__ WB1) {
  if (blockIdx.x >= 8192) {
    f2b_body(Wout, WB1, blockIdx.x - 8192);
    return;
  }
  int v = blockIdx.x * 256 + threadIdx.x;
  int dv = v & (DDIM / 8 - 1);
  int m = v >> 8;
  int d0 = dv * 8;
  int t = m & (TDIM - 1);
  int sp = segp[m];
  float acc[8];
#pragma unroll
  for (int j = 0; j < 8; ++j) acc[j] = cb[d0 + j];
#pragma unroll
  for (int i = 0; i < 4; ++i) {
    int shift = 3 - i;
    if (t >= shift && sp >= shift) {
      bf16x8 xv = *(const bf16x8*)&xp[(size_t)(m - shift) * DDIM + d0];
#pragma unroll
      for (int j = 0; j < 8; ++j) acc[j] = fmaf((float)xv[j], cw[i * DDIM + d0 + j], acc[j]);
    }
  }
  bf16x8 o;
#pragma unroll
  for (int j = 0; j < 8; ++j) o[j] = (bf16)acc[j];
  *(bf16x8*)&xc[(size_t)m * DDIM + d0] = o;
}

// ---------------------------------------------------------------------------
// transpose + convert gate weights: dst[h][j][i] = (bf16)src[h][i][j]
// ---------------------------------------------------------------------------
__global__ __launch_bounds__(256) void transpose_gates(
    const float* __restrict__ gxw, const float* __restrict__ gaw,
    bf16* __restrict__ gxT, bf16* __restrict__ gaT) {
  __shared__ bf16 tile[32][33];
  int zz = blockIdx.z;
  int h = zz >> 1;
  const float* src = (zz & 1) ? gaw : gxw;
  bf16* dst = (zz & 1) ? gaT : gxT;
  int j0 = blockIdx.x * 32;
  int i0 = blockIdx.y * 32;
  int r = threadIdx.x >> 5;
  int c = threadIdx.x & 31;
  for (int rr = r; rr < 32; rr += 8)
    tile[rr][c] = (bf16)src[(size_t)(h * DHD + i0 + rr) * DHD + j0 + c];
  __syncthreads();
  for (int rr = r; rr < 32; rr += 8)
    dst[(size_t)(h * DHD + j0 + rr) * DHD + i0 + c] = tile[c][rr];
}

// ---------------------------------------------------------------------------
// RG-LRU elementwise recompute, shared by scan phases
// ---------------------------------------------------------------------------
__device__ __forceinline__ void lru_elem(float pgx, float pga, float xc,
                                         float spv, bool reset,
                                         float& a, float& nr) {
  const float gx = sigmoid_f(pgx);
  const float ga = sigmoid_f(pga);
  const float la = -8.f * ga * spv;
  a = reset ? 0.f : __expf(la);
  const float mult = reset ? 1.f : sqrtf(fmaxf(1.f - __expf(2.f * la), 0.f));
  nr = xc * gx * mult;
}

// chunked scan phase 1 — VEC=4 at 512 blocks = 2 blocks/CU (round-12 winner)
__global__ __launch_bounds__(256) void scan_phase1(
    const bf16* __restrict__ gxr, const bf16* __restrict__ gar,
    const bf16* __restrict__ xconv,
    const float* __restrict__ gxb, const float* __restrict__ gab,
    const float* __restrict__ apar, const int* __restrict__ segp,
    float* __restrict__ chA, float* __restrict__ chH) {
  int idx = blockIdx.x * 256 + threadIdx.x;     // B*NCHUNK*(DDIM/4) = 131072
  int dv = idx & (DDIM / 4 - 1);
  int c = (idx >> 9) & (NCHUNK - 1);
  int b = idx >> 15;
  int d0 = dv * 4;
  const float4 gx4 = *(const float4*)(gxb + d0);
  const float4 ga4 = *(const float4*)(gab + d0);
  const float4 ap4 = *(const float4*)(apar + d0);
  float gxbv[4] = {gx4.x, gx4.y, gx4.z, gx4.w};
  float gabv[4] = {ga4.x, ga4.y, ga4.z, ga4.w};
  float spv[4]  = {softplus_f(ap4.x), softplus_f(ap4.y),
                   softplus_f(ap4.z), softplus_f(ap4.w)};
  const int mrow = b * TDIM + c * LCHUNK;
  size_t base = (size_t)mrow * DDIM + d0;
  float A[4] = {1.f, 1.f, 1.f, 1.f}, hh[4] = {0.f, 0.f, 0.f, 0.f};
  for (int i = 0; i < LCHUNK; ++i) {
    size_t o = base + (size_t)i * DDIM;
    bf16x4 g1 = *(const bf16x4*)&gxr[o];
    bf16x4 g2 = *(const bf16x4*)&gar[o];
    bf16x4 xv = *(const bf16x4*)&xconv[o];
    bool rst = (segp[mrow + i] == 0);
#pragma unroll
    for (int j = 0; j < 4; ++j) {
      float a, nr;
      lru_elem((float)g1[j] + gxbv[j], (float)g2[j] + gabv[j], (float)xv[j],
               spv[j], rst, a, nr);
      hh[j] = fmaf(a, hh[j], nr);
      A[j] *= a;
    }
  }
  size_t ci = (size_t)(b * NCHUNK + c) * DDIM + d0;
  *(f32x4*)&chA[ci] = f32x4{A[0], A[1], A[2], A[3]};
  *(f32x4*)&chH[ci] = f32x4{hh[0], hh[1], hh[2], hh[3]};
}

__global__ __launch_bounds__(256) void scan_phase2(
    const float* __restrict__ chA, const float* __restrict__ chH,
    float* __restrict__ hst) {
  int idx = blockIdx.x * 64 + threadIdx.x;   // 64-thread blocks -> 128 CUs
  int d = idx & (DDIM - 1);
  int b = idx >> 11;
  float s = 0.f;
  for (int c = 0; c < NCHUNK; ++c) {
    int ci = (b * NCHUNK + c) * DDIM + d;
    hst[ci] = s;
    s = fmaf(chA[ci], s, chH[ci]);
  }
}

// phase 3 — VEC=4: replay with chunk-start state; z = h*y in-place over y
__global__ __launch_bounds__(256) void scan_phase3(
    const bf16* __restrict__ gxr, const bf16* __restrict__ gar,
    const bf16* __restrict__ xconv,
    const float* __restrict__ gxb, const float* __restrict__ gab,
    const float* __restrict__ apar, const int* __restrict__ segp,
    const float* __restrict__ hst, bf16* __restrict__ yz) {
  int idx = blockIdx.x * 256 + threadIdx.x;
  int dv = idx & (DDIM / 4 - 1);
  int c = (idx >> 9) & (NCHUNK - 1);
  int b = idx >> 15;
  int d0 = dv * 4;
  const float4 gx4 = *(const float4*)(gxb + d0);
  const float4 ga4 = *(const float4*)(gab + d0);
  const float4 ap4 = *(const float4*)(apar + d0);
  float gxbv[4] = {gx4.x, gx4.y, gx4.z, gx4.w};
  float gabv[4] = {ga4.x, ga4.y, ga4.z, ga4.w};
  float spv[4]  = {softplus_f(ap4.x), softplus_f(ap4.y),
                   softplus_f(ap4.z), softplus_f(ap4.w)};
  const int mrow = b * TDIM + c * LCHUNK;
  size_t base = (size_t)mrow * DDIM + d0;
  size_t ci = (size_t)(b * NCHUNK + c) * DDIM + d0;
  const float4 h4 = *(const float4*)(hst + ci);
  float hh[4] = {h4.x, h4.y, h4.z, h4.w};
  for (int i = 0; i < LCHUNK; ++i) {
    size_t o = base + (size_t)i * DDIM;
    bf16x4 g1 = *(const bf16x4*)&gxr[o];
    bf16x4 g2 = *(const bf16x4*)&gar[o];
    bf16x4 xv = *(const bf16x4*)&xconv[o];
    bf16x4 y4 = *(const bf16x4*)&yz[o];
    bool rst = (segp[mrow + i] == 0);
    bf16x4 out;
#pragma unroll
    for (int j = 0; j < 4; ++j) {
      float a, nr;
      lru_elem((float)g1[j] + gxbv[j], (float)g2[j] + gabv[j], (float)xv[j],
               spv[j], rst, a, nr);
      hh[j] = fmaf(a, hh[j], nr);
      out[j] = (bf16)(hh[j] * (float)y4[j]);
    }
    *(bf16x4*)&yz[o] = out;
  }
}

// ---------------------------------------------------------------------------
extern "C" void kernel_launch(void* const* d_in, const int* in_sizes, int n_in,
                              void* d_out, int out_size, void* d_ws, size_t ws_size,
                              hipStream_t stream) {
  const float* x    = (const float*)d_in[0];
  const int*   segp = (const int*)d_in[1];
  const float* Wy   = (const float*)d_in[2];
  const float* by   = (const float*)d_in[3];
  const float* Wx   = (const float*)d_in[4];
  const float* bx   = (const float*)d_in[5];
  const float* cw   = (const float*)d_in[6];
  const float* cb   = (const float*)d_in[7];
  const float* gxw  = (const float*)d_in[8];
  const float* gxb  = (const float*)d_in[9];
  const float* gaw  = (const float*)d_in[10];
  const float* gab  = (const float*)d_in[11];
  const float* apar = (const float*)d_in[12];
  const float* Wout = (const float*)d_in[13];
  const float* bout = (const float*)d_in[14];

  const size_t MD = (size_t)MTOT * DDIM;       // 16.78M elements
  const size_t WD = (size_t)DDIM * DDIM;       // 4.19M elements
  // d_out (fp32, 67 MB) as bf16 scratch until the final GEMM:
  bf16* xb    = (bf16*)d_out;                   // lower: xb -> xconv
  bf16* xproj = (bf16*)((char*)d_out + MD * 2); // upper: xproj -> gxr
  bf16* xconv = xb;
  bf16* gxr   = xproj;

  // ws (~92 MB): gar | W1 | WB1 | WB2 | gxT | gaT | chA | chH | hst
  char* ws = (char*)d_ws;
  bf16*  gar = (bf16*)ws;                        // 33.5 MB
  bf16*  W1  = (bf16*)(ws + MD * 2);             // y -> z (33.5 MB)
  bf16*  WB1 = (bf16*)(ws + 2 * MD * 2);         // Wxb, later Woutb (8.4 MB)
  bf16*  WB2 = (bf16*)(ws + 2 * MD * 2 + WD * 2);// Wyb (8.4 MB)
  char*  tail = ws + 2 * MD * 2 + 2 * WD * 2;
  const size_t GW = (size_t)HDIM * DHD * DHD * 2;      // 1 MiB
  const size_t CH = (size_t)BDIM * NCHUNK * DDIM * 4;  // 2 MiB
  bf16*  gxT = (bf16*)tail;
  bf16*  gaT = (bf16*)(tail + GW);
  float* chA = (float*)(tail + 2 * GW);
  float* chH = (float*)(tail + 2 * GW + CH);
  float* hst = (float*)(tail + 2 * GW + 2 * CH);

  dim3 blk(256);
  // fused conversions: x (8192 blk) + Wx (2048) + Wy (2048)
  f2b3<<<dim3(12288), blk, 0, stream>>>(x, xb, Wx, WB1, Wy, WB2);
  transpose_gates<<<dim3(8, 8, 16), blk, 0, stream>>>(gxw, gaw, gxT, gaT);

  // DUAL GEMM (z=0: xproj = x@Wx^T+bx ; z=1: y = gelu(x@Wy^T+by)) —
  // measured 151 us for both (rounds 10-12, MfmaUtil 41%).
  gemm128<bf16><<<dim3(16, 64, 2), blk, 0, stream>>>(
      xb, WB1, WB2, bx, by, xproj, W1, 1, DDIM, DDIM, DDIM, DDIM);

  // conv (xconv in-place over xb) + Wout->WB1 f2b rider (WB1 dead here)
  conv_kernel<<<dim3(8192 + 2048), blk, 0, stream>>>(
      xproj, cw, cb, segp, xconv, Wout, WB1);

  // gate pre-activations in gemm128-style structure (NT=4)
  gate128<<<dim3(2, 64, 16), blk, 0, stream>>>(xconv, gxT, gaT, gxr, gar);

  // chunked scan, VEC=4 (512 blocks = 2 blocks/CU for phases 1/3)
  scan_phase1<<<dim3(BDIM * NCHUNK * (DDIM / 4) / 256), blk, 0, stream>>>(
      gxr, gar, xconv, gxb, gab, apar, segp, chA, chH);
  scan_phase2<<<dim3(BDIM * DDIM / 64), dim3(64), 0, stream>>>(chA, chH, hst);
  scan_phase3<<<dim3(BDIM * NCHUNK * (DDIM / 4) / 256), blk, 0, stream>>>(
      gxr, gar, xconv, gxb, gab, apar, segp, hst, W1);

  // out = z @ Wout^T + bout — round-7 gemm256 (measured 77.5-86 us)
  gemm256<float, 0><<<dim3(8, 32), dim3(512), 0, stream>>>(
      W1, WB1, bout, (float*)d_out, DDIM, DDIM, DDIM, DDIM);
}

// Round 16
// 396.438 us; speedup vs baseline: 1.1301x; 1.0405x over previous
//
#include <hip/hip_runtime.h>
#include <cstdint>
#include <cstddef>

typedef __bf16 bf16;
typedef __bf16 bf16x8 __attribute__((ext_vector_type(8)));
typedef __bf16 bf16x4 __attribute__((ext_vector_type(4)));
typedef float f32x4 __attribute__((ext_vector_type(4)));

#define BDIM 4
#define TDIM 2048
#define DDIM 2048
#define HDIM 8
#define DHD 256
#define MTOT 8192
#define NCHUNK 128
#define LCHUNK 16

// async 16B global->LDS; LDS dest = wave-uniform base + lane*16
__device__ __forceinline__ void stage16(const bf16* g, bf16* l) {
  __builtin_amdgcn_global_load_lds(
      (const __attribute__((address_space(1))) void*)g,
      (__attribute__((address_space(3))) void*)l, 16, 0, 0);
}

// intrinsic barrier (no implicit drain); BARE asm waitcnt (no "memory"
// clobber -> no compiler-inserted full drain; round-6 lesson).
#define BARX() __builtin_amdgcn_s_barrier()
#define SCHB() __builtin_amdgcn_sched_barrier(0)
#define WAITVM(N) asm volatile("s_waitcnt vmcnt(" #N ")")

__device__ __forceinline__ float sigmoid_f(float x) {
  return __fdividef(1.f, 1.f + __expf(-x));
}
__device__ __forceinline__ float gelu_tanh(float v) {
  float u = 0.7978845608028654f * (v + 0.044715f * v * v * v);
  u = fminf(fmaxf(u, -15.f), 15.f);
  float t = __expf(2.f * u);                       // tanh(u) = (t-1)/(t+1)
  return 0.5f * v * (1.f + __fdividef(t - 1.f, t + 1.f));
}
__device__ __forceinline__ float softplus_f(float x) {
  return __logf(1.f + __expf(x));                  // x in [-1.2, 0.4] here
}

__device__ __forceinline__ void f2b_body(const float* __restrict__ src,
                                         bf16* __restrict__ dst, int vb) {
  size_t i = ((size_t)vb * 256 + threadIdx.x) * 8;
  const float4 a = *(const float4*)(src + i);
  const float4 b = *(const float4*)(src + i + 4);
  bf16x8 r;
  r[0] = (bf16)a.x; r[1] = (bf16)a.y; r[2] = (bf16)a.z; r[3] = (bf16)a.w;
  r[4] = (bf16)b.x; r[5] = (bf16)b.y; r[6] = (bf16)b.z; r[7] = (bf16)b.w;
  *(bf16x8*)(dst + i) = r;
}

// ---------------------------------------------------------------------------
// fused prep: x->bf16 (8192 blk) | Wx (2048) | Wy (2048) | gate-transpose
// rider (1024 blk, decoded as old dim3(8,8,16)). Branch is block-uniform,
// so the rider's __syncthreads is safe.
// ---------------------------------------------------------------------------
__global__ __launch_bounds__(256) void f2b3t(
    const float* __restrict__ x, bf16* __restrict__ xb,
    const float* __restrict__ Wx, bf16* __restrict__ WB1,
    const float* __restrict__ Wy, bf16* __restrict__ WB2,
    const float* __restrict__ gxw, const float* __restrict__ gaw,
    bf16* __restrict__ gxT, bf16* __restrict__ gaT) {
  __shared__ bf16 tile[32][33];
  int b = blockIdx.x;
  if (b < 8192) { f2b_body(x, xb, b); return; }
  if (b < 10240) { f2b_body(Wx, WB1, b - 8192); return; }
  if (b < 12288) { f2b_body(Wy, WB2, b - 10240); return; }
  // transpose rider: b2 in [0,1024): zz = b2>>6, iy = (b2>>3)&7, jx = b2&7
  int b2 = b - 12288;
  int zz = b2 >> 6;
  int h = zz >> 1;
  const float* src = (zz & 1) ? gaw : gxw;
  bf16* dst = (zz & 1) ? gaT : gxT;
  int j0 = (b2 & 7) * 32;
  int i0 = ((b2 >> 3) & 7) * 32;
  int r = threadIdx.x >> 5;
  int c = threadIdx.x & 31;
  for (int rr = r; rr < 32; rr += 8)
    tile[rr][c] = (bf16)src[(size_t)(h * DHD + i0 + rr) * DHD + j0 + c];
  __syncthreads();
  for (int rr = r; rr < 32; rr += 8)
    dst[(size_t)(h * DHD + j0 + rr) * DHD + i0 + c] = tile[c][rr];
}

// ---------------------------------------------------------------------------
// gemm256: round-7 kernel VERBATIM (measured 77.5-86 us, final GEMM).
// ---------------------------------------------------------------------------
template <typename TO, int EPI>
__global__ __launch_bounds__(512, 2) void gemm256(
    const bf16* __restrict__ A, const bf16* __restrict__ Bm,
    const float* __restrict__ bias, TO* __restrict__ C,
    int K, int lda, int ldb, int ldc) {
  const int gx = gridDim.x, gy = gridDim.y;
  const int nwg = gx * gy;
  const int did = blockIdx.x + gx * blockIdx.y;
  const int cpx = nwg >> 3;                       // chunk per XCD
  const int lid = (did & 7) * cpx + (did >> 3);
  const int n0 = (lid % gx) * 256;
  const int m0 = (lid / gx) * 256;

  __shared__ bf16 sA0[256 * 64];
  __shared__ bf16 sA1[256 * 64];
  __shared__ bf16 sB0[256 * 64];
  __shared__ bf16 sB1[256 * 64];
  const int tid = threadIdx.x;
  const int lane = tid & 63;
  const int wid = tid >> 6;         // 0..7
  const int wr = wid >> 2;          // M-half of tile (128 rows)
  const int wc = wid & 3;           // N-quarter (64 cols)
  const int quad = lane >> 4;
  const int l15 = lane & 15;

  const int sr = tid >> 3;                        // 0..63
  const int ks8 = ((tid & 7) ^ (sr & 7)) << 3;    // element offset in 64-wide row
  const bf16* Ag = A + (size_t)(m0 + sr) * lda + ks8;
  const bf16* Bg = Bm + (size_t)(n0 + sr) * ldb + ks8;

  const int swz0 = ((quad) ^ (l15 & 7)) << 3;
  const int swz1 = ((4 + quad) ^ (l15 & 7)) << 3;

  f32x4 acc[8][4];
#pragma unroll
  for (int i = 0; i < 8; ++i)
#pragma unroll
    for (int j = 0; j < 4; ++j)
#pragma unroll
      for (int r = 0; r < 4; ++r) acc[i][j][r] = 0.f;

  const int NT = K >> 6;

#define STG_A(ARR, H, TK)                                                     \
  do {                                                                        \
    _Pragma("unroll") for (int j_ = 0; j_ < 2; ++j_) {                        \
      const int c_ = (H) * 2 + j_;                                            \
      stage16(Ag + (size_t)(c_ * 64) * lda + (size_t)(TK) * 64,               \
              &ARR[(c_ * 64 + wid * 8) * 64]);                                \
    }                                                                         \
  } while (0)
#define STG_B(ARR, H, TK)                                                     \
  do {                                                                        \
    _Pragma("unroll") for (int j_ = 0; j_ < 2; ++j_) {                        \
      const int c_ = (H) * 2 + j_;                                            \
      stage16(Bg + (size_t)(c_ * 64) * ldb + (size_t)(TK) * 64,               \
              &ARR[(c_ * 64 + wid * 8) * 64]);                                \
    }                                                                         \
  } while (0)

  bf16x8 aq0[4][2], aq1[4][2], b0[2][2], b1[2][2];

#define RDA(DST, MH, ARR)                                                     \
  do {                                                                        \
    _Pragma("unroll") for (int mi_ = 0; mi_ < 4; ++mi_) {                     \
      const int arow_ = wr * 128 + (MH) * 64 + mi_ * 16 + l15;                \
      DST[mi_][0] = *(const bf16x8*)(&ARR[arow_ * 64] + swz0);                \
      DST[mi_][1] = *(const bf16x8*)(&ARR[arow_ * 64] + swz1);                \
    }                                                                         \
  } while (0)
#define RDB(DST, NH, ARR)                                                     \
  do {                                                                        \
    _Pragma("unroll") for (int ni_ = 0; ni_ < 2; ++ni_) {                     \
      const int brow_ = wc * 64 + (NH) * 32 + ni_ * 16 + l15;                 \
      DST[ni_][0] = *(const bf16x8*)(&ARR[brow_ * 64] + swz0);                \
      DST[ni_][1] = *(const bf16x8*)(&ARR[brow_ * 64] + swz1);                \
    }                                                                         \
  } while (0)
#define MFMAQ(MH, NH, AA, BB)                                                 \
  do {                                                                        \
    __builtin_amdgcn_s_setprio(1);                                            \
    _Pragma("unroll") for (int mi_ = 0; mi_ < 4; ++mi_)                       \
        _Pragma("unroll") for (int ni_ = 0; ni_ < 2; ++ni_) {                 \
      acc[(MH)*4 + mi_][(NH)*2 + ni_] = __builtin_amdgcn_mfma_f32_16x16x32_bf16( \
          AA[mi_][0], BB[ni_][0], acc[(MH)*4 + mi_][(NH)*2 + ni_], 0, 0, 0);  \
      acc[(MH)*4 + mi_][(NH)*2 + ni_] = __builtin_amdgcn_mfma_f32_16x16x32_bf16( \
          AA[mi_][1], BB[ni_][1], acc[(MH)*4 + mi_][(NH)*2 + ni_], 0, 0, 0);  \
    }                                                                         \
    __builtin_amdgcn_s_setprio(0);                                            \
  } while (0)

#define TILE(SAs, SBs, SAo, SBo, T)                                           \
  do {                                                                        \
    const int tn_ = ((T) + 1 < NT) ? (T) + 1 : NT - 1;                        \
    const int tnn_ = ((T) + 2 < NT) ? (T) + 2 : NT - 1;                       \
    /* ph1 */                                                                 \
    WAITVM(4);                                                                \
    SCHB();                                                                   \
    STG_B(SBo, 1, tn_);                                                       \
    RDB(b1, 1, SBs);                                                          \
    MFMAQ(0, 0, aq0, b0);                                                     \
    BARX();                                                                   \
    /* ph2 */                                                                 \
    STG_A(SAo, 1, tn_);                                                       \
    RDA(aq1, 1, SAs);                                                         \
    MFMAQ(0, 1, aq0, b1);                                                     \
    BARX();                                                                   \
    /* ph3 */                                                                 \
    STG_B(SBs, 0, tnn_);                                                      \
    MFMAQ(1, 0, aq1, b0);                                                     \
    BARX();                                                                   \
    /* ph4 */                                                                 \
    WAITVM(6);                                                                \
    SCHB();                                                                   \
    if (T + 1 < NT) {                                                         \
      RDA(aq0, 0, SAo);                                                       \
      RDB(b0, 0, SBo);                                                        \
    }                                                                         \
    STG_A(SAs, 0, tnn_);                                                      \
    MFMAQ(1, 1, aq1, b1);                                                     \
    BARX();                                                                   \
  } while (0)

  // prologue: tile0 fully + tile1 khalf0 (12 loads, chronological order)
  STG_B(sB0, 0, 0); STG_A(sA0, 0, 0);
  STG_B(sB0, 1, 0); STG_A(sA0, 1, 0);
  STG_B(sB1, 0, 1); STG_A(sA1, 0, 1);
  WAITVM(8);                          // retire HB0(0), HA0(0)
  SCHB();
  BARX();
  RDA(aq0, 0, sA0);                   // sub0(0)
  RDB(b0, 0, sB0);                    // nh0(0)

  for (int t = 0; t < NT; t += 2) {   // NT even (K%128==0)
    TILE(sA0, sB0, sA1, sB1, t);
    TILE(sA1, sB1, sA0, sB0, t + 1);
  }
  WAITVM(0);                          // drain tail stages (hygiene)

#undef STG_A
#undef STG_B
#undef RDA
#undef RDB
#undef MFMAQ
#undef TILE

  // epilogue: row-major store bursts — 4 consecutive stores per quad-row
  float bv[4];
#pragma unroll
  for (int nn = 0; nn < 4; ++nn) bv[nn] = bias[n0 + wc * 64 + nn * 16 + l15];
#pragma unroll
  for (int mm = 0; mm < 8; ++mm) {
#pragma unroll
    for (int r = 0; r < 4; ++r) {
      const int m = m0 + wr * 128 + mm * 16 + quad * 4 + r;
      TO* Crow = C + (size_t)m * ldc + n0 + wc * 64 + l15;
#pragma unroll
      for (int nn = 0; nn < 4; ++nn) {
        float v = acc[mm][nn][r] + bv[nn];
        if (EPI == 1) v = gelu_tanh(v);
        Crow[nn * 16] = (TO)v;
      }
    }
  }
}

// ---------------------------------------------------------------------------
// gemm128: round-10 kernel VERBATIM (dual-z = 151 us for both projections).
// ---------------------------------------------------------------------------
template <typename TO>
__global__ __launch_bounds__(256, 2) void gemm128(
    const bf16* __restrict__ A,
    const bf16* __restrict__ B0m, const bf16* __restrict__ B1m,
    const float* __restrict__ bias0, const float* __restrict__ bias1,
    TO* __restrict__ C0, TO* __restrict__ C1, int epi1,
    int K, int lda, int ldb, int ldc) {
  const bf16* Bm = blockIdx.z ? B1m : B0m;
  const float* bias = blockIdx.z ? bias1 : bias0;
  TO* C = blockIdx.z ? C1 : C0;
  const int EPI = blockIdx.z ? epi1 : 0;

  const int gx = gridDim.x, gy = gridDim.y;
  const int nwg = gx * gy;
  const int did = blockIdx.x + gx * blockIdx.y;
  const int cpx = nwg >> 3;                       // chunk per XCD
  const int lid = (did & 7) * cpx + (did >> 3);
  const int n0 = (lid % gx) * 128;
  const int m0 = (lid / gx) * 128;

  __shared__ bf16 sA0[128 * 64];
  __shared__ bf16 sA1[128 * 64];
  __shared__ bf16 sB0[128 * 64];
  __shared__ bf16 sB1[128 * 64];
  const int tid = threadIdx.x;
  const int lane = tid & 63;
  const int wid = tid >> 6;         // 0..3
  const int wr = wid >> 1;          // M-half (64 rows)
  const int wc = wid & 1;           // N-half (64 cols)
  const int quad = lane >> 4;
  const int l15 = lane & 15;

  const int sr = tid >> 3;                        // 0..31
  const int ks8 = ((tid & 7) ^ (sr & 7)) << 3;
  const bf16* Ag = A + (size_t)(m0 + sr) * lda + ks8;
  const bf16* Bg = Bm + (size_t)(n0 + sr) * ldb + ks8;

  const int swz0 = ((quad) ^ (l15 & 7)) << 3;
  const int swz1 = ((4 + quad) ^ (l15 & 7)) << 3;

  f32x4 acc[4][4];
#pragma unroll
  for (int i = 0; i < 4; ++i)
#pragma unroll
    for (int j = 0; j < 4; ++j)
#pragma unroll
      for (int r = 0; r < 4; ++r) acc[i][j][r] = 0.f;

  const int NT = K >> 6;

#define STG_A(ARR, TK)                                                        \
  do {                                                                        \
    _Pragma("unroll") for (int c_ = 0; c_ < 4; ++c_)                          \
        stage16(Ag + (size_t)(c_ * 32) * lda + (size_t)(TK) * 64,             \
                &ARR[(c_ * 32 + wid * 8) * 64]);                              \
  } while (0)
#define STG_B(ARR, TK)                                                        \
  do {                                                                        \
    _Pragma("unroll") for (int c_ = 0; c_ < 4; ++c_)                          \
        stage16(Bg + (size_t)(c_ * 32) * ldb + (size_t)(TK) * 64,             \
                &ARR[(c_ * 32 + wid * 8) * 64]);                              \
  } while (0)

  bf16x8 af[4][2], b0[2][2], b1[2][2];

#define RDA(ARR)                                                              \
  do {                                                                        \
    _Pragma("unroll") for (int mi_ = 0; mi_ < 4; ++mi_) {                     \
      const int arow_ = wr * 64 + mi_ * 16 + l15;                             \
      af[mi_][0] = *(const bf16x8*)(&ARR[arow_ * 64] + swz0);                 \
      af[mi_][1] = *(const bf16x8*)(&ARR[arow_ * 64] + swz1);                 \
    }                                                                         \
  } while (0)
#define RDB(DST, NH, ARR)                                                     \
  do {                                                                        \
    _Pragma("unroll") for (int ni_ = 0; ni_ < 2; ++ni_) {                     \
      const int brow_ = wc * 64 + (NH) * 32 + ni_ * 16 + l15;                 \
      DST[ni_][0] = *(const bf16x8*)(&ARR[brow_ * 64] + swz0);                \
      DST[ni_][1] = *(const bf16x8*)(&ARR[brow_ * 64] + swz1);                \
    }                                                                         \
  } while (0)
#define MFMAQ(NH, BB)                                                         \
  do {                                                                        \
    __builtin_amdgcn_s_setprio(1);                                            \
    _Pragma("unroll") for (int mi_ = 0; mi_ < 4; ++mi_)                       \
        _Pragma("unroll") for (int ni_ = 0; ni_ < 2; ++ni_) {                 \
      acc[mi_][(NH)*2 + ni_] = __builtin_amdgcn_mfma_f32_16x16x32_bf16(       \
          af[mi_][0], BB[ni_][0], acc[mi_][(NH)*2 + ni_], 0, 0, 0);           \
      acc[mi_][(NH)*2 + ni_] = __builtin_amdgcn_mfma_f32_16x16x32_bf16(       \
          af[mi_][1], BB[ni_][1], acc[mi_][(NH)*2 + ni_], 0, 0, 0);           \
    }                                                                         \
    __builtin_amdgcn_s_setprio(0);                                            \
  } while (0)

#define TILE(SAs, SBs, SAo, SBo, T)                                           \
  do {                                                                        \
    const int tn_ = ((T) + 1 < NT) ? (T) + 1 : NT - 1;                        \
    const int tnn_ = ((T) + 2 < NT) ? (T) + 2 : NT - 1;                       \
    /* ph1 */                                                                 \
    RDA(SAs);                                                                 \
    RDB(b0, 0, SBs);                                                          \
    STG_B(SBo, tn_);                                                          \
    MFMAQ(0, b0);                                                             \
    BARX();                                                                   \
    /* ph2 */                                                                 \
    RDB(b1, 1, SBs);                                                          \
    STG_A(SAs, tnn_);                                                         \
    MFMAQ(1, b1);                                                             \
    WAITVM(4);                                                                \
    BARX();                                                                   \
  } while (0)

  // prologue: tiles 0,1 (16 loads, chronological); WAITVM(4) leaves A(1)
  const int t1 = (NT > 1) ? 1 : 0;
  STG_B(sB0, 0); STG_A(sA0, 0);
  STG_B(sB1, t1); STG_A(sA1, t1);
  WAITVM(4);
  SCHB();
  BARX();

  for (int t = 0; t < NT; t += 2) {   // NT even (K%128==0)
    TILE(sA0, sB0, sA1, sB1, t);
    TILE(sA1, sB1, sA0, sB0, t + 1);
  }
  WAITVM(0);                          // drain tail stages (hygiene)

#undef STG_A
#undef STG_B
#undef RDA
#undef RDB
#undef MFMAQ
#undef TILE

  float bv[4];
#pragma unroll
  for (int nn = 0; nn < 4; ++nn) bv[nn] = bias[n0 + wc * 64 + nn * 16 + l15];
#pragma unroll
  for (int mm = 0; mm < 4; ++mm) {
#pragma unroll
    for (int r = 0; r < 4; ++r) {
      const int m = m0 + wr * 64 + mm * 16 + quad * 4 + r;
      TO* Crow = C + (size_t)m * ldc + n0 + wc * 64 + l15;
#pragma unroll
      for (int nn = 0; nn < 4; ++nn) {
        float v = acc[mm][nn][r] + bv[nn];
        if (EPI == 1) v = gelu_tanh(v);
        Crow[nn * 16] = (TO)v;
      }
    }
  }
}

// ---------------------------------------------------------------------------
// gate128: round-14 kernel VERBATIM (2-phase counted-vmcnt, NT=4).
// ---------------------------------------------------------------------------
__global__ __launch_bounds__(256, 2) void gate128(
    const bf16* __restrict__ xconv,
    const bf16* __restrict__ gxT, const bf16* __restrict__ gaT,
    bf16* __restrict__ gxr, bf16* __restrict__ gar) {
  const int h = blockIdx.z >> 1;
  const int g = blockIdx.z & 1;
  const bf16* A = xconv + h * DHD;                           // lda = DDIM
  const bf16* Bm = (g ? gaT : gxT) + (size_t)h * DHD * DHD;  // ldb = DHD
  bf16* C = (g ? gar : gxr) + h * DHD;                       // ldc = DDIM

  const int gx = gridDim.x, gy = gridDim.y;
  const int nwg = gx * gy;                        // 128, %8==0
  const int did = blockIdx.x + gx * blockIdx.y;
  const int cpx = nwg >> 3;
  const int lid = (did & 7) * cpx + (did >> 3);
  const int n0 = (lid % gx) * 128;
  const int m0 = (lid / gx) * 128;

  __shared__ bf16 sA0[128 * 64];
  __shared__ bf16 sA1[128 * 64];
  __shared__ bf16 sB0[128 * 64];
  __shared__ bf16 sB1[128 * 64];
  const int tid = threadIdx.x;
  const int lane = tid & 63;
  const int wid = tid >> 6;
  const int wr = wid >> 1;
  const int wc = wid & 1;
  const int quad = lane >> 4;
  const int l15 = lane & 15;

  const int sr = tid >> 3;
  const int ks8 = ((tid & 7) ^ (sr & 7)) << 3;
  const bf16* Ag = A + (size_t)(m0 + sr) * DDIM + ks8;
  const bf16* Bg = Bm + (size_t)(n0 + sr) * DHD + ks8;

  const int swz0 = ((quad) ^ (l15 & 7)) << 3;
  const int swz1 = ((4 + quad) ^ (l15 & 7)) << 3;

  f32x4 acc[4][4];
#pragma unroll
  for (int i = 0; i < 4; ++i)
#pragma unroll
    for (int j = 0; j < 4; ++j)
#pragma unroll
      for (int r = 0; r < 4; ++r) acc[i][j][r] = 0.f;

  const int NT = 4;                                // K = 256

#define STG_A(ARR, TK)                                                        \
  do {                                                                        \
    _Pragma("unroll") for (int c_ = 0; c_ < 4; ++c_)                          \
        stage16(Ag + (size_t)(c_ * 32) * DDIM + (size_t)(TK) * 64,            \
                &ARR[(c_ * 32 + wid * 8) * 64]);                              \
  } while (0)
#define STG_B(ARR, TK)                                                        \
  do {                                                                        \
    _Pragma("unroll") for (int c_ = 0; c_ < 4; ++c_)                          \
        stage16(Bg + (size_t)(c_ * 32) * DHD + (size_t)(TK) * 64,             \
                &ARR[(c_ * 32 + wid * 8) * 64]);                              \
  } while (0)

  bf16x8 af[4][2], b0[2][2], b1[2][2];

#define RDA(ARR)                                                              \
  do {                                                                        \
    _Pragma("unroll") for (int mi_ = 0; mi_ < 4; ++mi_) {                     \
      const int arow_ = wr * 64 + mi_ * 16 + l15;                             \
      af[mi_][0] = *(const bf16x8*)(&ARR[arow_ * 64] + swz0);                 \
      af[mi_][1] = *(const bf16x8*)(&ARR[arow_ * 64] + swz1);                 \
    }                                                                         \
  } while (0)
#define RDB(DST, NH, ARR)                                                     \
  do {                                                                        \
    _Pragma("unroll") for (int ni_ = 0; ni_ < 2; ++ni_) {                     \
      const int brow_ = wc * 64 + (NH) * 32 + ni_ * 16 + l15;                 \
      DST[ni_][0] = *(const bf16x8*)(&ARR[brow_ * 64] + swz0);                \
      DST[ni_][1] = *(const bf16x8*)(&ARR[brow_ * 64] + swz1);                \
    }                                                                         \
  } while (0)
#define MFMAQ(NH, BB)                                                         \
  do {                                                                        \
    __builtin_amdgcn_s_setprio(1);                                            \
    _Pragma("unroll") for (int mi_ = 0; mi_ < 4; ++mi_)                       \
        _Pragma("unroll") for (int ni_ = 0; ni_ < 2; ++ni_) {                 \
      acc[mi_][(NH)*2 + ni_] = __builtin_amdgcn_mfma_f32_16x16x32_bf16(       \
          af[mi_][0], BB[ni_][0], acc[mi_][(NH)*2 + ni_], 0, 0, 0);           \
      acc[mi_][(NH)*2 + ni_] = __builtin_amdgcn_mfma_f32_16x16x32_bf16(       \
          af[mi_][1], BB[ni_][1], acc[mi_][(NH)*2 + ni_], 0, 0, 0);           \
    }                                                                         \
    __builtin_amdgcn_s_setprio(0);                                            \
  } while (0)

#define TILE(SAs, SBs, SAo, SBo, T)                                           \
  do {                                                                        \
    const int tn_ = ((T) + 1 < NT) ? (T) + 1 : NT - 1;                        \
    const int tnn_ = ((T) + 2 < NT) ? (T) + 2 : NT - 1;                       \
    RDA(SAs);                                                                 \
    RDB(b0, 0, SBs);                                                          \
    STG_B(SBo, tn_);                                                          \
    MFMAQ(0, b0);                                                             \
    BARX();                                                                   \
    RDB(b1, 1, SBs);                                                          \
    STG_A(SAs, tnn_);                                                         \
    MFMAQ(1, b1);                                                             \
    WAITVM(4);                                                                \
    BARX();                                                                   \
  } while (0)

  STG_B(sB0, 0); STG_A(sA0, 0);
  STG_B(sB1, 1); STG_A(sA1, 1);
  WAITVM(4);
  SCHB();
  BARX();

  for (int t = 0; t < NT; t += 2) {
    TILE(sA0, sB0, sA1, sB1, t);
    TILE(sA1, sB1, sA0, sB0, t + 1);
  }
  WAITVM(0);

#undef STG_A
#undef STG_B
#undef RDA
#undef RDB
#undef MFMAQ
#undef TILE

#pragma unroll
  for (int mm = 0; mm < 4; ++mm) {
#pragma unroll
    for (int r = 0; r < 4; ++r) {
      const int m = m0 + wr * 64 + mm * 16 + quad * 4 + r;
      bf16* Crow = C + (size_t)m * DDIM + n0 + wc * 64 + l15;
#pragma unroll
      for (int nn = 0; nn < 4; ++nn)
        Crow[nn * 16] = (bf16)acc[mm][nn][r];
    }
  }
}

// ---------------------------------------------------------------------------
// depthwise causal conv, TW=4 (blocks 0..8191) + Wout f2b rider (2048 blocks;
// WB1 is dead after the dual projection GEMM, which precedes this launch).
// ---------------------------------------------------------------------------
__global__ __launch_bounds__(256) void conv_kernel(
    const bf16* __restrict__ xp, const float* __restrict__ cw,
    const float* __restrict__ cb, const int* __restrict__ segp,
    bf16* __restrict__ xc,
    const float* __restrict__ Wout, bf16* __restrict__ WB1) {
  if (blockIdx.x >= 8192) {
    f2b_body(Wout, WB1, blockIdx.x - 8192);
    return;
  }
  int v = blockIdx.x * 256 + threadIdx.x;
  int dv = v & (DDIM / 8 - 1);
  int m = v >> 8;
  int d0 = dv * 8;
  int t = m & (TDIM - 1);
  int sp = segp[m];
  float acc[8];
#pragma unroll
  for (int j = 0; j < 8; ++j) acc[j] = cb[d0 + j];
#pragma unroll
  for (int i = 0; i < 4; ++i) {
    int shift = 3 - i;
    if (t >= shift && sp >= shift) {
      bf16x8 xv = *(const bf16x8*)&xp[(size_t)(m - shift) * DDIM + d0];
#pragma unroll
      for (int j = 0; j < 8; ++j) acc[j] = fmaf((float)xv[j], cw[i * DDIM + d0 + j], acc[j]);
    }
  }
  bf16x8 o;
#pragma unroll
  for (int j = 0; j < 8; ++j) o[j] = (bf16)acc[j];
  *(bf16x8*)&xc[(size_t)m * DDIM + d0] = o;
}

// ---------------------------------------------------------------------------
// RG-LRU elementwise recompute, shared by scan phases
// ---------------------------------------------------------------------------
__device__ __forceinline__ void lru_elem(float pgx, float pga, float xc,
                                         float spv, bool reset,
                                         float& a, float& nr) {
  const float gx = sigmoid_f(pgx);
  const float ga = sigmoid_f(pga);
  const float la = -8.f * ga * spv;
  a = reset ? 0.f : __expf(la);
  const float mult = reset ? 1.f : sqrtf(fmaxf(1.f - __expf(2.f * la), 0.f));
  nr = xc * gx * mult;
}

// chunked scan phase 1 — VEC=4, LCHUNK=16 -> 1024 blocks = 4 blocks/CU
// (16 waves/CU; round-12 showed the scans are TLP-sensitive at 2 blocks/CU).
__global__ __launch_bounds__(256) void scan_phase1(
    const bf16* __restrict__ gxr, const bf16* __restrict__ gar,
    const bf16* __restrict__ xconv,
    const float* __restrict__ gxb, const float* __restrict__ gab,
    const float* __restrict__ apar, const int* __restrict__ segp,
    float* __restrict__ chA, float* __restrict__ chH) {
  int idx = blockIdx.x * 256 + threadIdx.x;     // B*NCHUNK*(DDIM/4) = 262144
  int dv = idx & (DDIM / 4 - 1);
  int c = (idx >> 9) & (NCHUNK - 1);
  int b = idx >> 16;
  int d0 = dv * 4;
  const float4 gx4 = *(const float4*)(gxb + d0);
  const float4 ga4 = *(const float4*)(gab + d0);
  const float4 ap4 = *(const float4*)(apar + d0);
  float gxbv[4] = {gx4.x, gx4.y, gx4.z, gx4.w};
  float gabv[4] = {ga4.x, ga4.y, ga4.z, ga4.w};
  float spv[4]  = {softplus_f(ap4.x), softplus_f(ap4.y),
                   softplus_f(ap4.z), softplus_f(ap4.w)};
  const int mrow = b * TDIM + c * LCHUNK;
  size_t base = (size_t)mrow * DDIM + d0;
  float A[4] = {1.f, 1.f, 1.f, 1.f}, hh[4] = {0.f, 0.f, 0.f, 0.f};
  for (int i = 0; i < LCHUNK; ++i) {
    size_t o = base + (size_t)i * DDIM;
    bf16x4 g1 = *(const bf16x4*)&gxr[o];
    bf16x4 g2 = *(const bf16x4*)&gar[o];
    bf16x4 xv = *(const bf16x4*)&xconv[o];
    bool rst = (segp[mrow + i] == 0);
#pragma unroll
    for (int j = 0; j < 4; ++j) {
      float a, nr;
      lru_elem((float)g1[j] + gxbv[j], (float)g2[j] + gabv[j], (float)xv[j],
               spv[j], rst, a, nr);
      hh[j] = fmaf(a, hh[j], nr);
      A[j] *= a;
    }
  }
  size_t ci = (size_t)(b * NCHUNK + c) * DDIM + d0;
  *(f32x4*)&chA[ci] = f32x4{A[0], A[1], A[2], A[3]};
  *(f32x4*)&chH[ci] = f32x4{hh[0], hh[1], hh[2], hh[3]};
}

__global__ __launch_bounds__(256) void scan_phase2(
    const float* __restrict__ chA, const float* __restrict__ chH,
    float* __restrict__ hst) {
  int idx = blockIdx.x * 64 + threadIdx.x;   // 64-thread blocks -> 128 CUs
  int d = idx & (DDIM - 1);
  int b = idx >> 11;
  float s = 0.f;
  for (int c = 0; c < NCHUNK; ++c) {
    int ci = (b * NCHUNK + c) * DDIM + d;
    hst[ci] = s;
    s = fmaf(chA[ci], s, chH[ci]);
  }
}

// phase 3 — VEC=4, LCHUNK=16: replay with chunk-start state; z = h*y over y
__global__ __launch_bounds__(256) void scan_phase3(
    const bf16* __restrict__ gxr, const bf16* __restrict__ gar,
    const bf16* __restrict__ xconv,
    const float* __restrict__ gxb, const float* __restrict__ gab,
    const float* __restrict__ apar, const int* __restrict__ segp,
    const float* __restrict__ hst, bf16* __restrict__ yz) {
  int idx = blockIdx.x * 256 + threadIdx.x;
  int dv = idx & (DDIM / 4 - 1);
  int c = (idx >> 9) & (NCHUNK - 1);
  int b = idx >> 16;
  int d0 = dv * 4;
  const float4 gx4 = *(const float4*)(gxb + d0);
  const float4 ga4 = *(const float4*)(gab + d0);
  const float4 ap4 = *(const float4*)(apar + d0);
  float gxbv[4] = {gx4.x, gx4.y, gx4.z, gx4.w};
  float gabv[4] = {ga4.x, ga4.y, ga4.z, ga4.w};
  float spv[4]  = {softplus_f(ap4.x), softplus_f(ap4.y),
                   softplus_f(ap4.z), softplus_f(ap4.w)};
  const int mrow = b * TDIM + c * LCHUNK;
  size_t base = (size_t)mrow * DDIM + d0;
  size_t ci = (size_t)(b * NCHUNK + c) * DDIM + d0;
  const float4 h4 = *(const float4*)(hst + ci);
  float hh[4] = {h4.x, h4.y, h4.z, h4.w};
  for (int i = 0; i < LCHUNK; ++i) {
    size_t o = base + (size_t)i * DDIM;
    bf16x4 g1 = *(const bf16x4*)&gxr[o];
    bf16x4 g2 = *(const bf16x4*)&gar[o];
    bf16x4 xv = *(const bf16x4*)&xconv[o];
    bf16x4 y4 = *(const bf16x4*)&yz[o];
    bool rst = (segp[mrow + i] == 0);
    bf16x4 out;
#pragma unroll
    for (int j = 0; j < 4; ++j) {
      float a, nr;
      lru_elem((float)g1[j] + gxbv[j], (float)g2[j] + gabv[j], (float)xv[j],
               spv[j], rst, a, nr);
      hh[j] = fmaf(a, hh[j], nr);
      out[j] = (bf16)(hh[j] * (float)y4[j]);
    }
    *(bf16x4*)&yz[o] = out;
  }
}

// ---------------------------------------------------------------------------
extern "C" void kernel_launch(void* const* d_in, const int* in_sizes, int n_in,
                              void* d_out, int out_size, void* d_ws, size_t ws_size,
                              hipStream_t stream) {
  const float* x    = (const float*)d_in[0];
  const int*   segp = (const int*)d_in[1];
  const float* Wy   = (const float*)d_in[2];
  const float* by   = (const float*)d_in[3];
  const float* Wx   = (const float*)d_in[4];
  const float* bx   = (const float*)d_in[5];
  const float* cw   = (const float*)d_in[6];
  const float* cb   = (const float*)d_in[7];
  const float* gxw  = (const float*)d_in[8];
  const float* gxb  = (const float*)d_in[9];
  const float* gaw  = (const float*)d_in[10];
  const float* gab  = (const float*)d_in[11];
  const float* apar = (const float*)d_in[12];
  const float* Wout = (const float*)d_in[13];
  const float* bout = (const float*)d_in[14];

  const size_t MD = (size_t)MTOT * DDIM;       // 16.78M elements
  const size_t WD = (size_t)DDIM * DDIM;       // 4.19M elements
  // d_out (fp32, 67 MB) as bf16 scratch until the final GEMM:
  bf16* xb    = (bf16*)d_out;                   // lower: xb -> xconv
  bf16* xproj = (bf16*)((char*)d_out + MD * 2); // upper: xproj -> gxr
  bf16* xconv = xb;
  bf16* gxr   = xproj;

  // ws layout: gar | W1 | WB1 | WB2(-> chA|chH after dual GEMM) | gxT gaT hst
  char* ws = (char*)d_ws;
  bf16*  gar = (bf16*)ws;                        // 33.5 MB
  bf16*  W1  = (bf16*)(ws + MD * 2);             // y -> z (33.5 MB)
  bf16*  WB1 = (bf16*)(ws + 2 * MD * 2);         // Wxb, later Woutb (8.4 MB)
  bf16*  WB2 = (bf16*)(ws + 2 * MD * 2 + WD * 2);// Wyb; dead after dual GEMM
  char*  tail = ws + 2 * MD * 2 + 2 * WD * 2;
  const size_t GW = (size_t)HDIM * DHD * DHD * 2;      // 1 MiB
  const size_t CH = (size_t)BDIM * NCHUNK * DDIM * 4;  // 4 MiB (LCHUNK=16)
  bf16*  gxT = (bf16*)tail;
  bf16*  gaT = (bf16*)(tail + GW);
  float* hst = (float*)(tail + 2 * GW);                // 4 MiB
  // chA/chH overlay the dead WB2 region (2*CH = 8 MiB == WD*2 bytes)
  float* chA = (float*)WB2;
  float* chH = (float*)((char*)WB2 + CH);

  dim3 blk(256);
  // fused prep: x + Wx + Wy conversions + gate-weight transpose rider
  f2b3t<<<dim3(13312), blk, 0, stream>>>(x, xb, Wx, WB1, Wy, WB2,
                                         gxw, gaw, gxT, gaT);

  // DUAL GEMM (z=0: xproj = x@Wx^T+bx ; z=1: y = gelu(x@Wy^T+by)) —
  // measured 151 us for both (rounds 10-14, MfmaUtil 41%).
  gemm128<bf16><<<dim3(16, 64, 2), blk, 0, stream>>>(
      xb, WB1, WB2, bx, by, xproj, W1, 1, DDIM, DDIM, DDIM, DDIM);

  // conv (xconv in-place over xb) + Wout->WB1 f2b rider (WB1 dead here)
  conv_kernel<<<dim3(8192 + 2048), blk, 0, stream>>>(
      xproj, cw, cb, segp, xconv, Wout, WB1);

  // gate pre-activations in gemm128-style structure (NT=4)
  gate128<<<dim3(2, 64, 16), blk, 0, stream>>>(xconv, gxT, gaT, gxr, gar);

  // chunked scan, VEC=4, LCHUNK=16 (1024 blocks = 4 blocks/CU for ph1/3;
  // chA/chH live in the dead WB2 region)
  scan_phase1<<<dim3(BDIM * NCHUNK * (DDIM / 4) / 256), blk, 0, stream>>>(
      gxr, gar, xconv, gxb, gab, apar, segp, chA, chH);
  scan_phase2<<<dim3(BDIM * DDIM / 64), dim3(64), 0, stream>>>(chA, chH, hst);
  scan_phase3<<<dim3(BDIM * NCHUNK * (DDIM / 4) / 256), blk, 0, stream>>>(
      gxr, gar, xconv, gxb, gab, apar, segp, hst, W1);

  // out = z @ Wout^T + bout — round-7 gemm256 (measured 77.5-86 us)
  gemm256<float, 0><<<dim3(8, 32), dim3(512), 0, stream>>>(
      W1, WB1, bout, (float*)d_out, DDIM, DDIM, DDIM, DDIM);
}

// Round 17
// 380.668 us; speedup vs baseline: 1.1769x; 1.0414x over previous
//
#include <hip/hip_runtime.h>
#include <cstdint>
#include <cstddef>

typedef __bf16 bf16;
typedef __bf16 bf16x8 __attribute__((ext_vector_type(8)));
typedef __bf16 bf16x4 __attribute__((ext_vector_type(4)));
typedef float f32x4 __attribute__((ext_vector_type(4)));

#define BDIM 4
#define TDIM 2048
#define DDIM 2048
#define HDIM 8
#define DHD 256
#define MTOT 8192
#define NCHUNK 128
#define LCHUNK 16

// async 16B global->LDS; LDS dest = wave-uniform base + lane*16
__device__ __forceinline__ void stage16(const bf16* g, bf16* l) {
  __builtin_amdgcn_global_load_lds(
      (const __attribute__((address_space(1))) void*)g,
      (__attribute__((address_space(3))) void*)l, 16, 0, 0);
}

// intrinsic barrier (no implicit drain); BARE asm waitcnt (no "memory"
// clobber -> no compiler-inserted full drain; round-6 lesson).
#define BARX() __builtin_amdgcn_s_barrier()
#define SCHB() __builtin_amdgcn_sched_barrier(0)
#define WAITVM(N) asm volatile("s_waitcnt vmcnt(" #N ")")

__device__ __forceinline__ float sigmoid_f(float x) {
  return __fdividef(1.f, 1.f + __expf(-x));
}
__device__ __forceinline__ float gelu_tanh(float v) {
  float u = 0.7978845608028654f * (v + 0.044715f * v * v * v);
  u = fminf(fmaxf(u, -15.f), 15.f);
  float t = __expf(2.f * u);                       // tanh(u) = (t-1)/(t+1)
  return 0.5f * v * (1.f + __fdividef(t - 1.f, t + 1.f));
}
__device__ __forceinline__ float softplus_f(float x) {
  return __logf(1.f + __expf(x));                  // x in [-1.2, 0.4] here
}

__device__ __forceinline__ void f2b_body(const float* __restrict__ src,
                                         bf16* __restrict__ dst, int vb) {
  size_t i = ((size_t)vb * 256 + threadIdx.x) * 8;
  const float4 a = *(const float4*)(src + i);
  const float4 b = *(const float4*)(src + i + 4);
  bf16x8 r;
  r[0] = (bf16)a.x; r[1] = (bf16)a.y; r[2] = (bf16)a.z; r[3] = (bf16)a.w;
  r[4] = (bf16)b.x; r[5] = (bf16)b.y; r[6] = (bf16)b.z; r[7] = (bf16)b.w;
  *(bf16x8*)(dst + i) = r;
}

// ---------------------------------------------------------------------------
// fused prep: x->bf16 (8192 blk) | Wx (2048) | Wy (2048) | gate-transpose
// rider (1024 blk). Branch is block-uniform -> rider __syncthreads safe.
// ---------------------------------------------------------------------------
__global__ __launch_bounds__(256) void f2b3t(
    const float* __restrict__ x, bf16* __restrict__ xb,
    const float* __restrict__ Wx, bf16* __restrict__ WB1,
    const float* __restrict__ Wy, bf16* __restrict__ WB2,
    const float* __restrict__ gxw, const float* __restrict__ gaw,
    bf16* __restrict__ gxT, bf16* __restrict__ gaT) {
  __shared__ bf16 tile[32][33];
  int b = blockIdx.x;
  if (b < 8192) { f2b_body(x, xb, b); return; }
  if (b < 10240) { f2b_body(Wx, WB1, b - 8192); return; }
  if (b < 12288) { f2b_body(Wy, WB2, b - 10240); return; }
  int b2 = b - 12288;
  int zz = b2 >> 6;
  int h = zz >> 1;
  const float* src = (zz & 1) ? gaw : gxw;
  bf16* dst = (zz & 1) ? gaT : gxT;
  int j0 = (b2 & 7) * 32;
  int i0 = ((b2 >> 3) & 7) * 32;
  int r = threadIdx.x >> 5;
  int c = threadIdx.x & 31;
  for (int rr = r; rr < 32; rr += 8)
    tile[rr][c] = (bf16)src[(size_t)(h * DHD + i0 + rr) * DHD + j0 + c];
  __syncthreads();
  for (int rr = r; rr < 32; rr += 8)
    dst[(size_t)(h * DHD + j0 + rr) * DHD + i0 + c] = tile[c][rr];
}

// ---------------------------------------------------------------------------
// gemm256: round-7 kernel VERBATIM (measured 77.5-86 us, final GEMM).
// ---------------------------------------------------------------------------
template <typename TO, int EPI>
__global__ __launch_bounds__(512, 2) void gemm256(
    const bf16* __restrict__ A, const bf16* __restrict__ Bm,
    const float* __restrict__ bias, TO* __restrict__ C,
    int K, int lda, int ldb, int ldc) {
  const int gx = gridDim.x, gy = gridDim.y;
  const int nwg = gx * gy;
  const int did = blockIdx.x + gx * blockIdx.y;
  const int cpx = nwg >> 3;                       // chunk per XCD
  const int lid = (did & 7) * cpx + (did >> 3);
  const int n0 = (lid % gx) * 256;
  const int m0 = (lid / gx) * 256;

  __shared__ bf16 sA0[256 * 64];
  __shared__ bf16 sA1[256 * 64];
  __shared__ bf16 sB0[256 * 64];
  __shared__ bf16 sB1[256 * 64];
  const int tid = threadIdx.x;
  const int lane = tid & 63;
  const int wid = tid >> 6;         // 0..7
  const int wr = wid >> 2;          // M-half of tile (128 rows)
  const int wc = wid & 3;           // N-quarter (64 cols)
  const int quad = lane >> 4;
  const int l15 = lane & 15;

  const int sr = tid >> 3;                        // 0..63
  const int ks8 = ((tid & 7) ^ (sr & 7)) << 3;    // element offset in 64-wide row
  const bf16* Ag = A + (size_t)(m0 + sr) * lda + ks8;
  const bf16* Bg = Bm + (size_t)(n0 + sr) * ldb + ks8;

  const int swz0 = ((quad) ^ (l15 & 7)) << 3;
  const int swz1 = ((4 + quad) ^ (l15 & 7)) << 3;

  f32x4 acc[8][4];
#pragma unroll
  for (int i = 0; i < 8; ++i)
#pragma unroll
    for (int j = 0; j < 4; ++j)
#pragma unroll
      for (int r = 0; r < 4; ++r) acc[i][j][r] = 0.f;

  const int NT = K >> 6;

#define STG_A(ARR, H, TK)                                                     \
  do {                                                                        \
    _Pragma("unroll") for (int j_ = 0; j_ < 2; ++j_) {                        \
      const int c_ = (H) * 2 + j_;                                            \
      stage16(Ag + (size_t)(c_ * 64) * lda + (size_t)(TK) * 64,               \
              &ARR[(c_ * 64 + wid * 8) * 64]);                                \
    }                                                                         \
  } while (0)
#define STG_B(ARR, H, TK)                                                     \
  do {                                                                        \
    _Pragma("unroll") for (int j_ = 0; j_ < 2; ++j_) {                        \
      const int c_ = (H) * 2 + j_;                                            \
      stage16(Bg + (size_t)(c_ * 64) * ldb + (size_t)(TK) * 64,               \
              &ARR[(c_ * 64 + wid * 8) * 64]);                                \
    }                                                                         \
  } while (0)

  bf16x8 aq0[4][2], aq1[4][2], b0[2][2], b1[2][2];

#define RDA(DST, MH, ARR)                                                     \
  do {                                                                        \
    _Pragma("unroll") for (int mi_ = 0; mi_ < 4; ++mi_) {                     \
      const int arow_ = wr * 128 + (MH) * 64 + mi_ * 16 + l15;                \
      DST[mi_][0] = *(const bf16x8*)(&ARR[arow_ * 64] + swz0);                \
      DST[mi_][1] = *(const bf16x8*)(&ARR[arow_ * 64] + swz1);                \
    }                                                                         \
  } while (0)
#define RDB(DST, NH, ARR)                                                     \
  do {                                                                        \
    _Pragma("unroll") for (int ni_ = 0; ni_ < 2; ++ni_) {                     \
      const int brow_ = wc * 64 + (NH) * 32 + ni_ * 16 + l15;                 \
      DST[ni_][0] = *(const bf16x8*)(&ARR[brow_ * 64] + swz0);                \
      DST[ni_][1] = *(const bf16x8*)(&ARR[brow_ * 64] + swz1);                \
    }                                                                         \
  } while (0)
#define MFMAQ(MH, NH, AA, BB)                                                 \
  do {                                                                        \
    __builtin_amdgcn_s_setprio(1);                                            \
    _Pragma("unroll") for (int mi_ = 0; mi_ < 4; ++mi_)                       \
        _Pragma("unroll") for (int ni_ = 0; ni_ < 2; ++ni_) {                 \
      acc[(MH)*4 + mi_][(NH)*2 + ni_] = __builtin_amdgcn_mfma_f32_16x16x32_bf16( \
          AA[mi_][0], BB[ni_][0], acc[(MH)*4 + mi_][(NH)*2 + ni_], 0, 0, 0);  \
      acc[(MH)*4 + mi_][(NH)*2 + ni_] = __builtin_amdgcn_mfma_f32_16x16x32_bf16( \
          AA[mi_][1], BB[ni_][1], acc[(MH)*4 + mi_][(NH)*2 + ni_], 0, 0, 0);  \
    }                                                                         \
    __builtin_amdgcn_s_setprio(0);                                            \
  } while (0)

#define TILE(SAs, SBs, SAo, SBo, T)                                           \
  do {                                                                        \
    const int tn_ = ((T) + 1 < NT) ? (T) + 1 : NT - 1;                        \
    const int tnn_ = ((T) + 2 < NT) ? (T) + 2 : NT - 1;                       \
    /* ph1 */                                                                 \
    WAITVM(4);                                                                \
    SCHB();                                                                   \
    STG_B(SBo, 1, tn_);                                                       \
    RDB(b1, 1, SBs);                                                          \
    MFMAQ(0, 0, aq0, b0);                                                     \
    BARX();                                                                   \
    /* ph2 */                                                                 \
    STG_A(SAo, 1, tn_);                                                       \
    RDA(aq1, 1, SAs);                                                         \
    MFMAQ(0, 1, aq0, b1);                                                     \
    BARX();                                                                   \
    /* ph3 */                                                                 \
    STG_B(SBs, 0, tnn_);                                                      \
    MFMAQ(1, 0, aq1, b0);                                                     \
    BARX();                                                                   \
    /* ph4 */                                                                 \
    WAITVM(6);                                                                \
    SCHB();                                                                   \
    if (T + 1 < NT) {                                                         \
      RDA(aq0, 0, SAo);                                                       \
      RDB(b0, 0, SBo);                                                        \
    }                                                                         \
    STG_A(SAs, 0, tnn_);                                                      \
    MFMAQ(1, 1, aq1, b1);                                                     \
    BARX();                                                                   \
  } while (0)

  // prologue: tile0 fully + tile1 khalf0 (12 loads, chronological order)
  STG_B(sB0, 0, 0); STG_A(sA0, 0, 0);
  STG_B(sB0, 1, 0); STG_A(sA0, 1, 0);
  STG_B(sB1, 0, 1); STG_A(sA1, 0, 1);
  WAITVM(8);                          // retire HB0(0), HA0(0)
  SCHB();
  BARX();
  RDA(aq0, 0, sA0);                   // sub0(0)
  RDB(b0, 0, sB0);                    // nh0(0)

  for (int t = 0; t < NT; t += 2) {   // NT even (K%128==0)
    TILE(sA0, sB0, sA1, sB1, t);
    TILE(sA1, sB1, sA0, sB0, t + 1);
  }
  WAITVM(0);                          // drain tail stages (hygiene)

#undef STG_A
#undef STG_B
#undef RDA
#undef RDB
#undef MFMAQ
#undef TILE

  // epilogue: row-major store bursts — 4 consecutive stores per quad-row
  float bv[4];
#pragma unroll
  for (int nn = 0; nn < 4; ++nn) bv[nn] = bias[n0 + wc * 64 + nn * 16 + l15];
#pragma unroll
  for (int mm = 0; mm < 8; ++mm) {
#pragma unroll
    for (int r = 0; r < 4; ++r) {
      const int m = m0 + wr * 128 + mm * 16 + quad * 4 + r;
      TO* Crow = C + (size_t)m * ldc + n0 + wc * 64 + l15;
#pragma unroll
      for (int nn = 0; nn < 4; ++nn) {
        float v = acc[mm][nn][r] + bv[nn];
        if (EPI == 1) v = gelu_tanh(v);
        Crow[nn * 16] = (TO)v;
      }
    }
  }
}

// ---------------------------------------------------------------------------
// gemm128: round-10 kernel VERBATIM (dual-z = 151 us for both projections).
// ---------------------------------------------------------------------------
template <typename TO>
__global__ __launch_bounds__(256, 2) void gemm128(
    const bf16* __restrict__ A,
    const bf16* __restrict__ B0m, const bf16* __restrict__ B1m,
    const float* __restrict__ bias0, const float* __restrict__ bias1,
    TO* __restrict__ C0, TO* __restrict__ C1, int epi1,
    int K, int lda, int ldb, int ldc) {
  const bf16* Bm = blockIdx.z ? B1m : B0m;
  const float* bias = blockIdx.z ? bias1 : bias0;
  TO* C = blockIdx.z ? C1 : C0;
  const int EPI = blockIdx.z ? epi1 : 0;

  const int gx = gridDim.x, gy = gridDim.y;
  const int nwg = gx * gy;
  const int did = blockIdx.x + gx * blockIdx.y;
  const int cpx = nwg >> 3;                       // chunk per XCD
  const int lid = (did & 7) * cpx + (did >> 3);
  const int n0 = (lid % gx) * 128;
  const int m0 = (lid / gx) * 128;

  __shared__ bf16 sA0[128 * 64];
  __shared__ bf16 sA1[128 * 64];
  __shared__ bf16 sB0[128 * 64];
  __shared__ bf16 sB1[128 * 64];
  const int tid = threadIdx.x;
  const int lane = tid & 63;
  const int wid = tid >> 6;         // 0..3
  const int wr = wid >> 1;          // M-half (64 rows)
  const int wc = wid & 1;           // N-half (64 cols)
  const int quad = lane >> 4;
  const int l15 = lane & 15;

  const int sr = tid >> 3;                        // 0..31
  const int ks8 = ((tid & 7) ^ (sr & 7)) << 3;
  const bf16* Ag = A + (size_t)(m0 + sr) * lda + ks8;
  const bf16* Bg = Bm + (size_t)(n0 + sr) * ldb + ks8;

  const int swz0 = ((quad) ^ (l15 & 7)) << 3;
  const int swz1 = ((4 + quad) ^ (l15 & 7)) << 3;

  f32x4 acc[4][4];
#pragma unroll
  for (int i = 0; i < 4; ++i)
#pragma unroll
    for (int j = 0; j < 4; ++j)
#pragma unroll
      for (int r = 0; r < 4; ++r) acc[i][j][r] = 0.f;

  const int NT = K >> 6;

#define STG_A(ARR, TK)                                                        \
  do {                                                                        \
    _Pragma("unroll") for (int c_ = 0; c_ < 4; ++c_)                          \
        stage16(Ag + (size_t)(c_ * 32) * lda + (size_t)(TK) * 64,             \
                &ARR[(c_ * 32 + wid * 8) * 64]);                              \
  } while (0)
#define STG_B(ARR, TK)                                                        \
  do {                                                                        \
    _Pragma("unroll") for (int c_ = 0; c_ < 4; ++c_)                          \
        stage16(Bg + (size_t)(c_ * 32) * ldb + (size_t)(TK) * 64,             \
                &ARR[(c_ * 32 + wid * 8) * 64]);                              \
  } while (0)

  bf16x8 af[4][2], b0[2][2], b1[2][2];

#define RDA(ARR)                                                              \
  do {                                                                        \
    _Pragma("unroll") for (int mi_ = 0; mi_ < 4; ++mi_) {                     \
      const int arow_ = wr * 64 + mi_ * 16 + l15;                             \
      af[mi_][0] = *(const bf16x8*)(&ARR[arow_ * 64] + swz0);                 \
      af[mi_][1] = *(const bf16x8*)(&ARR[arow_ * 64] + swz1);                 \
    }                                                                         \
  } while (0)
#define RDB(DST, NH, ARR)                                                     \
  do {                                                                        \
    _Pragma("unroll") for (int ni_ = 0; ni_ < 2; ++ni_) {                     \
      const int brow_ = wc * 64 + (NH) * 32 + ni_ * 16 + l15;                 \
      DST[ni_][0] = *(const bf16x8*)(&ARR[brow_ * 64] + swz0);                \
      DST[ni_][1] = *(const bf16x8*)(&ARR[brow_ * 64] + swz1);                \
    }                                                                         \
  } while (0)
#define MFMAQ(NH, BB)                                                         \
  do {                                                                        \
    __builtin_amdgcn_s_setprio(1);                                            \
    _Pragma("unroll") for (int mi_ = 0; mi_ < 4; ++mi_)                       \
        _Pragma("unroll") for (int ni_ = 0; ni_ < 2; ++ni_) {                 \
      acc[mi_][(NH)*2 + ni_] = __builtin_amdgcn_mfma_f32_16x16x32_bf16(       \
          af[mi_][0], BB[ni_][0], acc[mi_][(NH)*2 + ni_], 0, 0, 0);           \
      acc[mi_][(NH)*2 + ni_] = __builtin_amdgcn_mfma_f32_16x16x32_bf16(       \
          af[mi_][1], BB[ni_][1], acc[mi_][(NH)*2 + ni_], 0, 0, 0);           \
    }                                                                         \
    __builtin_amdgcn_s_setprio(0);                                            \
  } while (0)

#define TILE(SAs, SBs, SAo, SBo, T)                                           \
  do {                                                                        \
    const int tn_ = ((T) + 1 < NT) ? (T) + 1 : NT - 1;                        \
    const int tnn_ = ((T) + 2 < NT) ? (T) + 2 : NT - 1;                       \
    /* ph1 */                                                                 \
    RDA(SAs);                                                                 \
    RDB(b0, 0, SBs);                                                          \
    STG_B(SBo, tn_);                                                          \
    MFMAQ(0, b0);                                                             \
    BARX();                                                                   \
    /* ph2 */                                                                 \
    RDB(b1, 1, SBs);                                                          \
    STG_A(SAs, tnn_);                                                         \
    MFMAQ(1, b1);                                                             \
    WAITVM(4);                                                                \
    BARX();                                                                   \
  } while (0)

  // prologue: tiles 0,1 (16 loads, chronological); WAITVM(4) leaves A(1)
  const int t1 = (NT > 1) ? 1 : 0;
  STG_B(sB0, 0); STG_A(sA0, 0);
  STG_B(sB1, t1); STG_A(sA1, t1);
  WAITVM(4);
  SCHB();
  BARX();

  for (int t = 0; t < NT; t += 2) {   // NT even (K%128==0)
    TILE(sA0, sB0, sA1, sB1, t);
    TILE(sA1, sB1, sA0, sB0, t + 1);
  }
  WAITVM(0);                          // drain tail stages (hygiene)

#undef STG_A
#undef STG_B
#undef RDA
#undef RDB
#undef MFMAQ
#undef TILE

  float bv[4];
#pragma unroll
  for (int nn = 0; nn < 4; ++nn) bv[nn] = bias[n0 + wc * 64 + nn * 16 + l15];
#pragma unroll
  for (int mm = 0; mm < 4; ++mm) {
#pragma unroll
    for (int r = 0; r < 4; ++r) {
      const int m = m0 + wr * 64 + mm * 16 + quad * 4 + r;
      TO* Crow = C + (size_t)m * ldc + n0 + wc * 64 + l15;
#pragma unroll
      for (int nn = 0; nn < 4; ++nn) {
        float v = acc[mm][nn][r] + bv[nn];
        if (EPI == 1) v = gelu_tanh(v);
        Crow[nn * 16] = (TO)v;
      }
    }
  }
}

// ---------------------------------------------------------------------------
// gate128: explicit NT=4 schedule (no clamp-tail redundant stages; the
// round-14/16 generic tail re-staged tile-3 three times = 96 MB wasted).
// Ledger: prologue {B0,A0,B1,A1}=16, WAITVM(8) retires B0,A0 -> tile0 ok.
//   t0: ph2 stage A2 (+4=12); WAITVM(4) retires B1,A1 -> tile1 certified.
//   t1: ph1 stage B2 (+4=8), ph2 stage A3 (+4=12); WAITVM(4) retires A2,B2.
//   t2: ph1 stage B3 (+4=8); WAITVM(0) -> tile3 certified. t3: no stages.
// WAR: each overwritten buffer's reads MFMA-consumed before prior barrier.
// ---------------------------------------------------------------------------
__global__ __launch_bounds__(256, 2) void gate128(
    const bf16* __restrict__ xconv,
    const bf16* __restrict__ gxT, const bf16* __restrict__ gaT,
    bf16* __restrict__ gxr, bf16* __restrict__ gar) {
  const int h = blockIdx.z >> 1;
  const int g = blockIdx.z & 1;
  const bf16* A = xconv + h * DHD;                           // lda = DDIM
  const bf16* Bm = (g ? gaT : gxT) + (size_t)h * DHD * DHD;  // ldb = DHD
  bf16* C = (g ? gar : gxr) + h * DHD;                       // ldc = DDIM

  const int gx = gridDim.x, gy = gridDim.y;
  const int nwg = gx * gy;                        // 128, %8==0
  const int did = blockIdx.x + gx * blockIdx.y;
  const int cpx = nwg >> 3;
  const int lid = (did & 7) * cpx + (did >> 3);
  const int n0 = (lid % gx) * 128;
  const int m0 = (lid / gx) * 128;

  __shared__ bf16 sA0[128 * 64];
  __shared__ bf16 sA1[128 * 64];
  __shared__ bf16 sB0[128 * 64];
  __shared__ bf16 sB1[128 * 64];
  const int tid = threadIdx.x;
  const int lane = tid & 63;
  const int wid = tid >> 6;
  const int wr = wid >> 1;
  const int wc = wid & 1;
  const int quad = lane >> 4;
  const int l15 = lane & 15;

  const int sr = tid >> 3;
  const int ks8 = ((tid & 7) ^ (sr & 7)) << 3;
  const bf16* Ag = A + (size_t)(m0 + sr) * DDIM + ks8;
  const bf16* Bg = Bm + (size_t)(n0 + sr) * DHD + ks8;

  const int swz0 = ((quad) ^ (l15 & 7)) << 3;
  const int swz1 = ((4 + quad) ^ (l15 & 7)) << 3;

  f32x4 acc[4][4];
#pragma unroll
  for (int i = 0; i < 4; ++i)
#pragma unroll
    for (int j = 0; j < 4; ++j)
#pragma unroll
      for (int r = 0; r < 4; ++r) acc[i][j][r] = 0.f;

#define STG_A(ARR, TK)                                                        \
  do {                                                                        \
    _Pragma("unroll") for (int c_ = 0; c_ < 4; ++c_)                          \
        stage16(Ag + (size_t)(c_ * 32) * DDIM + (size_t)(TK) * 64,            \
                &ARR[(c_ * 32 + wid * 8) * 64]);                              \
  } while (0)
#define STG_B(ARR, TK)                                                        \
  do {                                                                        \
    _Pragma("unroll") for (int c_ = 0; c_ < 4; ++c_)                          \
        stage16(Bg + (size_t)(c_ * 32) * DHD + (size_t)(TK) * 64,             \
                &ARR[(c_ * 32 + wid * 8) * 64]);                              \
  } while (0)

  bf16x8 af[4][2], b0[2][2], b1[2][2];

#define RDA(ARR)                                                              \
  do {                                                                        \
    _Pragma("unroll") for (int mi_ = 0; mi_ < 4; ++mi_) {                     \
      const int arow_ = wr * 64 + mi_ * 16 + l15;                             \
      af[mi_][0] = *(const bf16x8*)(&ARR[arow_ * 64] + swz0);                 \
      af[mi_][1] = *(const bf16x8*)(&ARR[arow_ * 64] + swz1);                 \
    }                                                                         \
  } while (0)
#define RDB(DST, NH, ARR)                                                     \
  do {                                                                        \
    _Pragma("unroll") for (int ni_ = 0; ni_ < 2; ++ni_) {                     \
      const int brow_ = wc * 64 + (NH) * 32 + ni_ * 16 + l15;                 \
      DST[ni_][0] = *(const bf16x8*)(&ARR[brow_ * 64] + swz0);                \
      DST[ni_][1] = *(const bf16x8*)(&ARR[brow_ * 64] + swz1);                \
    }                                                                         \
  } while (0)
#define MFMAQ(NH, BB)                                                         \
  do {                                                                        \
    __builtin_amdgcn_s_setprio(1);                                            \
    _Pragma("unroll") for (int mi_ = 0; mi_ < 4; ++mi_)                       \
        _Pragma("unroll") for (int ni_ = 0; ni_ < 2; ++ni_) {                 \
      acc[mi_][(NH)*2 + ni_] = __builtin_amdgcn_mfma_f32_16x16x32_bf16(       \
          af[mi_][0], BB[ni_][0], acc[mi_][(NH)*2 + ni_], 0, 0, 0);           \
      acc[mi_][(NH)*2 + ni_] = __builtin_amdgcn_mfma_f32_16x16x32_bf16(       \
          af[mi_][1], BB[ni_][1], acc[mi_][(NH)*2 + ni_], 0, 0, 0);           \
    }                                                                         \
    __builtin_amdgcn_s_setprio(0);                                            \
  } while (0)

  // prologue: tiles 0,1 fully staged
  STG_B(sB0, 0); STG_A(sA0, 0);
  STG_B(sB1, 1); STG_A(sA1, 1);
  WAITVM(8);                         // retire B0,A0 -> tile0 readable
  SCHB();
  BARX();
  // ---- t0 (buf0) ----
  RDA(sA0); RDB(b0, 0, sB0);
  MFMAQ(0, b0);
  BARX();
  RDB(b1, 1, sB0);
  STG_A(sA0, 2);                     // A2 (buf0 A reads done ph1)
  MFMAQ(1, b1);
  WAITVM(4);                         // retire B1,A1 -> tile1 certified
  BARX();
  // ---- t1 (buf1) ----
  RDA(sA1); RDB(b0, 0, sB1);
  STG_B(sB0, 2);                     // B2 (buf0 B reads done t0)
  MFMAQ(0, b0);
  BARX();
  RDB(b1, 1, sB1);
  STG_A(sA1, 3);                     // A3 (buf1 A reads done ph1)
  MFMAQ(1, b1);
  WAITVM(4);                         // retire A2,B2 -> tile2 certified
  BARX();
  // ---- t2 (buf0) ----
  RDA(sA0); RDB(b0, 0, sB0);
  STG_B(sB1, 3);                     // B3 (buf1 B reads done t1)
  MFMAQ(0, b0);
  BARX();
  RDB(b1, 1, sB0);
  MFMAQ(1, b1);
  WAITVM(0);                         // retire A3,B3 -> tile3 certified
  BARX();
  // ---- t3 (buf1) ----
  RDA(sA1); RDB(b0, 0, sB1);
  MFMAQ(0, b0);
  BARX();
  RDB(b1, 1, sB1);
  MFMAQ(1, b1);

#undef STG_A
#undef STG_B
#undef RDA
#undef RDB
#undef MFMAQ

#pragma unroll
  for (int mm = 0; mm < 4; ++mm) {
#pragma unroll
    for (int r = 0; r < 4; ++r) {
      const int m = m0 + wr * 64 + mm * 16 + quad * 4 + r;
      bf16* Crow = C + (size_t)m * DDIM + n0 + wc * 64 + l15;
#pragma unroll
      for (int nn = 0; nn < 4; ++nn)
        Crow[nn * 16] = (bf16)acc[mm][nn][r];
    }
  }
}

// ---------------------------------------------------------------------------
// depthwise causal conv, TW=4 (blocks 0..8191) + Wout f2b rider (2048 blocks;
// WB1 is dead after the dual projection GEMM). Weights loaded as float4
// pairs (G13: 40 scalar -> 10 vector VMEM issues per thread).
// ---------------------------------------------------------------------------
__global__ __launch_bounds__(256) void conv_kernel(
    const bf16* __restrict__ xp, const float* __restrict__ cw,
    const float* __restrict__ cb, const int* __restrict__ segp,
    bf16* __restrict__ xc,
    const float* __restrict__ Wout, bf16* __restrict__ WB1) {
  if (blockIdx.x >= 8192) {
    f2b_body(Wout, WB1, blockIdx.x - 8192);
    return;
  }
  int v = blockIdx.x * 256 + threadIdx.x;
  int dv = v & (DDIM / 8 - 1);
  int m = v >> 8;
  int d0 = dv * 8;
  int t = m & (TDIM - 1);
  int sp = segp[m];
  float acc[8];
  {
    const float4 c0 = *(const float4*)(cb + d0);
    const float4 c1 = *(const float4*)(cb + d0 + 4);
    acc[0] = c0.x; acc[1] = c0.y; acc[2] = c0.z; acc[3] = c0.w;
    acc[4] = c1.x; acc[5] = c1.y; acc[6] = c1.z; acc[7] = c1.w;
  }
#pragma unroll
  for (int i = 0; i < 4; ++i) {
    int shift = 3 - i;
    if (t >= shift && sp >= shift) {
      bf16x8 xv = *(const bf16x8*)&xp[(size_t)(m - shift) * DDIM + d0];
      const float4 w0 = *(const float4*)(cw + i * DDIM + d0);
      const float4 w1 = *(const float4*)(cw + i * DDIM + d0 + 4);
      acc[0] = fmaf((float)xv[0], w0.x, acc[0]);
      acc[1] = fmaf((float)xv[1], w0.y, acc[1]);
      acc[2] = fmaf((float)xv[2], w0.z, acc[2]);
      acc[3] = fmaf((float)xv[3], w0.w, acc[3]);
      acc[4] = fmaf((float)xv[4], w1.x, acc[4]);
      acc[5] = fmaf((float)xv[5], w1.y, acc[5]);
      acc[6] = fmaf((float)xv[6], w1.z, acc[6]);
      acc[7] = fmaf((float)xv[7], w1.w, acc[7]);
    }
  }
  bf16x8 o;
#pragma unroll
  for (int j = 0; j < 8; ++j) o[j] = (bf16)acc[j];
  *(bf16x8*)&xc[(size_t)m * DDIM + d0] = o;
}

// ---------------------------------------------------------------------------
// RG-LRU elementwise recompute, shared by scan phases
// ---------------------------------------------------------------------------
__device__ __forceinline__ void lru_elem(float pgx, float pga, float xc,
                                         float spv, bool reset,
                                         float& a, float& nr) {
  const float gx = sigmoid_f(pgx);
  const float ga = sigmoid_f(pga);
  const float la = -8.f * ga * spv;
  a = reset ? 0.f : __expf(la);
  const float mult = reset ? 1.f : sqrtf(fmaxf(1.f - __expf(2.f * la), 0.f));
  nr = xc * gx * mult;
}

// chunked scan phase 1 — VEC=4, LCHUNK=16 -> 1024 blocks = 4 blocks/CU
__global__ __launch_bounds__(256) void scan_phase1(
    const bf16* __restrict__ gxr, const bf16* __restrict__ gar,
    const bf16* __restrict__ xconv,
    const float* __restrict__ gxb, const float* __restrict__ gab,
    const float* __restrict__ apar, const int* __restrict__ segp,
    float* __restrict__ chA, float* __restrict__ chH) {
  int idx = blockIdx.x * 256 + threadIdx.x;     // B*NCHUNK*(DDIM/4) = 262144
  int dv = idx & (DDIM / 4 - 1);
  int c = (idx >> 9) & (NCHUNK - 1);
  int b = idx >> 16;
  int d0 = dv * 4;
  const float4 gx4 = *(const float4*)(gxb + d0);
  const float4 ga4 = *(const float4*)(gab + d0);
  const float4 ap4 = *(const float4*)(apar + d0);
  float gxbv[4] = {gx4.x, gx4.y, gx4.z, gx4.w};
  float gabv[4] = {ga4.x, ga4.y, ga4.z, ga4.w};
  float spv[4]  = {softplus_f(ap4.x), softplus_f(ap4.y),
                   softplus_f(ap4.z), softplus_f(ap4.w)};
  const int mrow = b * TDIM + c * LCHUNK;
  size_t base = (size_t)mrow * DDIM + d0;
  float A[4] = {1.f, 1.f, 1.f, 1.f}, hh[4] = {0.f, 0.f, 0.f, 0.f};
  for (int i = 0; i < LCHUNK; ++i) {
    size_t o = base + (size_t)i * DDIM;
    bf16x4 g1 = *(const bf16x4*)&gxr[o];
    bf16x4 g2 = *(const bf16x4*)&gar[o];
    bf16x4 xv = *(const bf16x4*)&xconv[o];
    bool rst = (segp[mrow + i] == 0);
#pragma unroll
    for (int j = 0; j < 4; ++j) {
      float a, nr;
      lru_elem((float)g1[j] + gxbv[j], (float)g2[j] + gabv[j], (float)xv[j],
               spv[j], rst, a, nr);
      hh[j] = fmaf(a, hh[j], nr);
      A[j] *= a;
    }
  }
  size_t ci = (size_t)(b * NCHUNK + c) * DDIM + d0;
  *(f32x4*)&chA[ci] = f32x4{A[0], A[1], A[2], A[3]};
  *(f32x4*)&chH[ci] = f32x4{hh[0], hh[1], hh[2], hh[3]};
}

__global__ __launch_bounds__(256) void scan_phase2(
    const float* __restrict__ chA, const float* __restrict__ chH,
    float* __restrict__ hst) {
  int idx = blockIdx.x * 64 + threadIdx.x;   // 64-thread blocks -> 128 CUs
  int d = idx & (DDIM - 1);
  int b = idx >> 11;
  float s = 0.f;
  for (int c = 0; c < NCHUNK; ++c) {
    int ci = (b * NCHUNK + c) * DDIM + d;
    hst[ci] = s;
    s = fmaf(chA[ci], s, chH[ci]);
  }
}

// phase 3 — VEC=4, LCHUNK=16: replay with chunk-start state; z = h*y over y
__global__ __launch_bounds__(256) void scan_phase3(
    const bf16* __restrict__ gxr, const bf16* __restrict__ gar,
    const bf16* __restrict__ xconv,
    const float* __restrict__ gxb, const float* __restrict__ gab,
    const float* __restrict__ apar, const int* __restrict__ segp,
    const float* __restrict__ hst, bf16* __restrict__ yz) {
  int idx = blockIdx.x * 256 + threadIdx.x;
  int dv = idx & (DDIM / 4 - 1);
  int c = (idx >> 9) & (NCHUNK - 1);
  int b = idx >> 16;
  int d0 = dv * 4;
  const float4 gx4 = *(const float4*)(gxb + d0);
  const float4 ga4 = *(const float4*)(gab + d0);
  const float4 ap4 = *(const float4*)(apar + d0);
  float gxbv[4] = {gx4.x, gx4.y, gx4.z, gx4.w};
  float gabv[4] = {ga4.x, ga4.y, ga4.z, ga4.w};
  float spv[4]  = {softplus_f(ap4.x), softplus_f(ap4.y),
                   softplus_f(ap4.z), softplus_f(ap4.w)};
  const int mrow = b * TDIM + c * LCHUNK;
  size_t base = (size_t)mrow * DDIM + d0;
  size_t ci = (size_t)(b * NCHUNK + c) * DDIM + d0;
  const float4 h4 = *(const float4*)(hst + ci);
  float hh[4] = {h4.x, h4.y, h4.z, h4.w};
  for (int i = 0; i < LCHUNK; ++i) {
    size_t o = base + (size_t)i * DDIM;
    bf16x4 g1 = *(const bf16x4*)&gxr[o];
    bf16x4 g2 = *(const bf16x4*)&gar[o];
    bf16x4 xv = *(const bf16x4*)&xconv[o];
    bf16x4 y4 = *(const bf16x4*)&yz[o];
    bool rst = (segp[mrow + i] == 0);
    bf16x4 out;
#pragma unroll
    for (int j = 0; j < 4; ++j) {
      float a, nr;
      lru_elem((float)g1[j] + gxbv[j], (float)g2[j] + gabv[j], (float)xv[j],
               spv[j], rst, a, nr);
      hh[j] = fmaf(a, hh[j], nr);
      out[j] = (bf16)(hh[j] * (float)y4[j]);
    }
    *(bf16x4*)&yz[o] = out;
  }
}

// ---------------------------------------------------------------------------
extern "C" void kernel_launch(void* const* d_in, const int* in_sizes, int n_in,
                              void* d_out, int out_size, void* d_ws, size_t ws_size,
                              hipStream_t stream) {
  const float* x    = (const float*)d_in[0];
  const int*   segp = (const int*)d_in[1];
  const float* Wy   = (const float*)d_in[2];
  const float* by   = (const float*)d_in[3];
  const float* Wx   = (const float*)d_in[4];
  const float* bx   = (const float*)d_in[5];
  const float* cw   = (const float*)d_in[6];
  const float* cb   = (const float*)d_in[7];
  const float* gxw  = (const float*)d_in[8];
  const float* gxb  = (const float*)d_in[9];
  const float* gaw  = (const float*)d_in[10];
  const float* gab  = (const float*)d_in[11];
  const float* apar = (const float*)d_in[12];
  const float* Wout = (const float*)d_in[13];
  const float* bout = (const float*)d_in[14];

  const size_t MD = (size_t)MTOT * DDIM;       // 16.78M elements
  const size_t WD = (size_t)DDIM * DDIM;       // 4.19M elements
  // d_out (fp32, 67 MB) as bf16 scratch until the final GEMM:
  bf16* xb    = (bf16*)d_out;                   // lower: xb -> xconv
  bf16* xproj = (bf16*)((char*)d_out + MD * 2); // upper: xproj -> gxr
  bf16* xconv = xb;
  bf16* gxr   = xproj;

  // ws layout: gar | W1 | WB1 | WB2(-> chA|chH after dual GEMM) | gxT gaT hst
  char* ws = (char*)d_ws;
  bf16*  gar = (bf16*)ws;                        // 33.5 MB
  bf16*  W1  = (bf16*)(ws + MD * 2);             // y -> z (33.5 MB)
  bf16*  WB1 = (bf16*)(ws + 2 * MD * 2);         // Wxb, later Woutb (8.4 MB)
  bf16*  WB2 = (bf16*)(ws + 2 * MD * 2 + WD * 2);// Wyb; dead after dual GEMM
  char*  tail = ws + 2 * MD * 2 + 2 * WD * 2;
  const size_t GW = (size_t)HDIM * DHD * DHD * 2;      // 1 MiB
  const size_t CH = (size_t)BDIM * NCHUNK * DDIM * 4;  // 4 MiB (LCHUNK=16)
  bf16*  gxT = (bf16*)tail;
  bf16*  gaT = (bf16*)(tail + GW);
  float* hst = (float*)(tail + 2 * GW);                // 4 MiB
  // chA/chH overlay the dead WB2 region (2*CH = 8 MiB == WD*2 bytes)
  float* chA = (float*)WB2;
  float* chH = (float*)((char*)WB2 + CH);

  dim3 blk(256);
  // fused prep: x + Wx + Wy conversions + gate-weight transpose rider
  f2b3t<<<dim3(13312), blk, 0, stream>>>(x, xb, Wx, WB1, Wy, WB2,
                                         gxw, gaw, gxT, gaT);

  // DUAL GEMM (z=0: xproj = x@Wx^T+bx ; z=1: y = gelu(x@Wy^T+by)) —
  // measured 151 us for both (rounds 10-16, MfmaUtil 41%).
  gemm128<bf16><<<dim3(16, 64, 2), blk, 0, stream>>>(
      xb, WB1, WB2, bx, by, xproj, W1, 1, DDIM, DDIM, DDIM, DDIM);

  // conv (xconv in-place over xb) + Wout->WB1 f2b rider (WB1 dead here)
  conv_kernel<<<dim3(8192 + 2048), blk, 0, stream>>>(
      xproj, cw, cb, segp, xconv, Wout, WB1);

  // gate pre-activations, explicit NT=4 schedule (no redundant tail stages)
  gate128<<<dim3(2, 64, 16), blk, 0, stream>>>(xconv, gxT, gaT, gxr, gar);

  // chunked scan, VEC=4, LCHUNK=16 (1024 blocks = 4 blocks/CU for ph1/3)
  scan_phase1<<<dim3(BDIM * NCHUNK * (DDIM / 4) / 256), blk, 0, stream>>>(
      gxr, gar, xconv, gxb, gab, apar, segp, chA, chH);
  scan_phase2<<<dim3(BDIM * DDIM / 64), dim3(64), 0, stream>>>(chA, chH, hst);
  scan_phase3<<<dim3(BDIM * NCHUNK * (DDIM / 4) / 256), blk, 0, stream>>>(
      gxr, gar, xconv, gxb, gab, apar, segp, hst, W1);

  // out = z @ Wout^T + bout — round-7 gemm256 (measured 77.5-86 us)
  gemm256<float, 0><<<dim3(8, 32), dim3(512), 0, stream>>>(
      W1, WB1, bout, (float*)d_out, DDIM, DDIM, DDIM, DDIM);
}

// Round 18
// 380.574 us; speedup vs baseline: 1.1772x; 1.0002x over previous
//
#include <hip/hip_runtime.h>
#include <cstdint>
#include <cstddef>

typedef __bf16 bf16;
typedef __bf16 bf16x8 __attribute__((ext_vector_type(8)));
typedef __bf16 bf16x4 __attribute__((ext_vector_type(4)));
typedef float f32x4 __attribute__((ext_vector_type(4)));

#define BDIM 4
#define TDIM 2048
#define DDIM 2048
#define HDIM 8
#define DHD 256
#define MTOT 8192
#define NCHUNK 128
#define LCHUNK 16

// async 16B global->LDS; LDS dest = wave-uniform base + lane*16
__device__ __forceinline__ void stage16(const bf16* g, bf16* l) {
  __builtin_amdgcn_global_load_lds(
      (const __attribute__((address_space(1))) void*)g,
      (__attribute__((address_space(3))) void*)l, 16, 0, 0);
}

// intrinsic barrier (no implicit drain); BARE asm waitcnt (no "memory"
// clobber -> no compiler-inserted full drain; round-6 lesson).
#define BARX() __builtin_amdgcn_s_barrier()
#define SCHB() __builtin_amdgcn_sched_barrier(0)
#define WAITVM(N) asm volatile("s_waitcnt vmcnt(" #N ")")

__device__ __forceinline__ float sigmoid_f(float x) {
  return __fdividef(1.f, 1.f + __expf(-x));
}
__device__ __forceinline__ float gelu_tanh(float v) {
  float u = 0.7978845608028654f * (v + 0.044715f * v * v * v);
  u = fminf(fmaxf(u, -15.f), 15.f);
  float t = __expf(2.f * u);                       // tanh(u) = (t-1)/(t+1)
  return 0.5f * v * (1.f + __fdividef(t - 1.f, t + 1.f));
}
__device__ __forceinline__ float softplus_f(float x) {
  return __logf(1.f + __expf(x));                  // x in [-1.2, 0.4] here
}

// fp32->bf16, 16 elems/thread (halved issue/block count vs 8/thread)
__device__ __forceinline__ void f2b_body16(const float* __restrict__ src,
                                           bf16* __restrict__ dst, int vb) {
  size_t i = ((size_t)vb * 256 + threadIdx.x) * 16;
  const float4 a0 = *(const float4*)(src + i);
  const float4 a1 = *(const float4*)(src + i + 4);
  const float4 a2 = *(const float4*)(src + i + 8);
  const float4 a3 = *(const float4*)(src + i + 12);
  bf16x8 r0, r1;
  r0[0] = (bf16)a0.x; r0[1] = (bf16)a0.y; r0[2] = (bf16)a0.z; r0[3] = (bf16)a0.w;
  r0[4] = (bf16)a1.x; r0[5] = (bf16)a1.y; r0[6] = (bf16)a1.z; r0[7] = (bf16)a1.w;
  r1[0] = (bf16)a2.x; r1[1] = (bf16)a2.y; r1[2] = (bf16)a2.z; r1[3] = (bf16)a2.w;
  r1[4] = (bf16)a3.x; r1[5] = (bf16)a3.y; r1[6] = (bf16)a3.z; r1[7] = (bf16)a3.w;
  *(bf16x8*)(dst + i) = r0;
  *(bf16x8*)(dst + i + 8) = r1;
}

// ---------------------------------------------------------------------------
// fused prep: x->bf16 (4096 blk) | Wx (1024) | Wy (1024) | gate-transpose
// rider (1024 blk). Branch is block-uniform -> rider __syncthreads safe.
// ---------------------------------------------------------------------------
__global__ __launch_bounds__(256) void f2b3t(
    const float* __restrict__ x, bf16* __restrict__ xb,
    const float* __restrict__ Wx, bf16* __restrict__ WB1,
    const float* __restrict__ Wy, bf16* __restrict__ WB2,
    const float* __restrict__ gxw, const float* __restrict__ gaw,
    bf16* __restrict__ gxT, bf16* __restrict__ gaT) {
  __shared__ bf16 tile[32][33];
  int b = blockIdx.x;
  if (b < 4096) { f2b_body16(x, xb, b); return; }
  if (b < 5120) { f2b_body16(Wx, WB1, b - 4096); return; }
  if (b < 6144) { f2b_body16(Wy, WB2, b - 5120); return; }
  int b2 = b - 6144;
  int zz = b2 >> 6;
  int h = zz >> 1;
  const float* src = (zz & 1) ? gaw : gxw;
  bf16* dst = (zz & 1) ? gaT : gxT;
  int j0 = (b2 & 7) * 32;
  int i0 = ((b2 >> 3) & 7) * 32;
  int r = threadIdx.x >> 5;
  int c = threadIdx.x & 31;
  for (int rr = r; rr < 32; rr += 8)
    tile[rr][c] = (bf16)src[(size_t)(h * DHD + i0 + rr) * DHD + j0 + c];
  __syncthreads();
  for (int rr = r; rr < 32; rr += 8)
    dst[(size_t)(h * DHD + j0 + rr) * DHD + i0 + c] = tile[c][rr];
}

// ---------------------------------------------------------------------------
// gemm256: round-7 kernel VERBATIM (measured 77.5-86 us, final GEMM).
// ---------------------------------------------------------------------------
template <typename TO, int EPI>
__global__ __launch_bounds__(512, 2) void gemm256(
    const bf16* __restrict__ A, const bf16* __restrict__ Bm,
    const float* __restrict__ bias, TO* __restrict__ C,
    int K, int lda, int ldb, int ldc) {
  const int gx = gridDim.x, gy = gridDim.y;
  const int nwg = gx * gy;
  const int did = blockIdx.x + gx * blockIdx.y;
  const int cpx = nwg >> 3;                       // chunk per XCD
  const int lid = (did & 7) * cpx + (did >> 3);
  const int n0 = (lid % gx) * 256;
  const int m0 = (lid / gx) * 256;

  __shared__ bf16 sA0[256 * 64];
  __shared__ bf16 sA1[256 * 64];
  __shared__ bf16 sB0[256 * 64];
  __shared__ bf16 sB1[256 * 64];
  const int tid = threadIdx.x;
  const int lane = tid & 63;
  const int wid = tid >> 6;         // 0..7
  const int wr = wid >> 2;          // M-half of tile (128 rows)
  const int wc = wid & 3;           // N-quarter (64 cols)
  const int quad = lane >> 4;
  const int l15 = lane & 15;

  const int sr = tid >> 3;                        // 0..63
  const int ks8 = ((tid & 7) ^ (sr & 7)) << 3;    // element offset in 64-wide row
  const bf16* Ag = A + (size_t)(m0 + sr) * lda + ks8;
  const bf16* Bg = Bm + (size_t)(n0 + sr) * ldb + ks8;

  const int swz0 = ((quad) ^ (l15 & 7)) << 3;
  const int swz1 = ((4 + quad) ^ (l15 & 7)) << 3;

  f32x4 acc[8][4];
#pragma unroll
  for (int i = 0; i < 8; ++i)
#pragma unroll
    for (int j = 0; j < 4; ++j)
#pragma unroll
      for (int r = 0; r < 4; ++r) acc[i][j][r] = 0.f;

  const int NT = K >> 6;

#define STG_A(ARR, H, TK)                                                     \
  do {                                                                        \
    _Pragma("unroll") for (int j_ = 0; j_ < 2; ++j_) {                        \
      const int c_ = (H) * 2 + j_;                                            \
      stage16(Ag + (size_t)(c_ * 64) * lda + (size_t)(TK) * 64,               \
              &ARR[(c_ * 64 + wid * 8) * 64]);                                \
    }                                                                         \
  } while (0)
#define STG_B(ARR, H, TK)                                                     \
  do {                                                                        \
    _Pragma("unroll") for (int j_ = 0; j_ < 2; ++j_) {                        \
      const int c_ = (H) * 2 + j_;                                            \
      stage16(Bg + (size_t)(c_ * 64) * ldb + (size_t)(TK) * 64,               \
              &ARR[(c_ * 64 + wid * 8) * 64]);                                \
    }                                                                         \
  } while (0)

  bf16x8 aq0[4][2], aq1[4][2], b0[2][2], b1[2][2];

#define RDA(DST, MH, ARR)                                                     \
  do {                                                                        \
    _Pragma("unroll") for (int mi_ = 0; mi_ < 4; ++mi_) {                     \
      const int arow_ = wr * 128 + (MH) * 64 + mi_ * 16 + l15;                \
      DST[mi_][0] = *(const bf16x8*)(&ARR[arow_ * 64] + swz0);                \
      DST[mi_][1] = *(const bf16x8*)(&ARR[arow_ * 64] + swz1);                \
    }                                                                         \
  } while (0)
#define RDB(DST, NH, ARR)                                                     \
  do {                                                                        \
    _Pragma("unroll") for (int ni_ = 0; ni_ < 2; ++ni_) {                     \
      const int brow_ = wc * 64 + (NH) * 32 + ni_ * 16 + l15;                 \
      DST[ni_][0] = *(const bf16x8*)(&ARR[brow_ * 64] + swz0);                \
      DST[ni_][1] = *(const bf16x8*)(&ARR[brow_ * 64] + swz1);                \
    }                                                                         \
  } while (0)
#define MFMAQ(MH, NH, AA, BB)                                                 \
  do {                                                                        \
    __builtin_amdgcn_s_setprio(1);                                            \
    _Pragma("unroll") for (int mi_ = 0; mi_ < 4; ++mi_)                       \
        _Pragma("unroll") for (int ni_ = 0; ni_ < 2; ++ni_) {                 \
      acc[(MH)*4 + mi_][(NH)*2 + ni_] = __builtin_amdgcn_mfma_f32_16x16x32_bf16( \
          AA[mi_][0], BB[ni_][0], acc[(MH)*4 + mi_][(NH)*2 + ni_], 0, 0, 0);  \
      acc[(MH)*4 + mi_][(NH)*2 + ni_] = __builtin_amdgcn_mfma_f32_16x16x32_bf16( \
          AA[mi_][1], BB[ni_][1], acc[(MH)*4 + mi_][(NH)*2 + ni_], 0, 0, 0);  \
    }                                                                         \
    __builtin_amdgcn_s_setprio(0);                                            \
  } while (0)

#define TILE(SAs, SBs, SAo, SBo, T)                                           \
  do {                                                                        \
    const int tn_ = ((T) + 1 < NT) ? (T) + 1 : NT - 1;                        \
    const int tnn_ = ((T) + 2 < NT) ? (T) + 2 : NT - 1;                       \
    /* ph1 */                                                                 \
    WAITVM(4);                                                                \
    SCHB();                                                                   \
    STG_B(SBo, 1, tn_);                                                       \
    RDB(b1, 1, SBs);                                                          \
    MFMAQ(0, 0, aq0, b0);                                                     \
    BARX();                                                                   \
    /* ph2 */                                                                 \
    STG_A(SAo, 1, tn_);                                                       \
    RDA(aq1, 1, SAs);                                                         \
    MFMAQ(0, 1, aq0, b1);                                                     \
    BARX();                                                                   \
    /* ph3 */                                                                 \
    STG_B(SBs, 0, tnn_);                                                      \
    MFMAQ(1, 0, aq1, b0);                                                     \
    BARX();                                                                   \
    /* ph4 */                                                                 \
    WAITVM(6);                                                                \
    SCHB();                                                                   \
    if (T + 1 < NT) {                                                         \
      RDA(aq0, 0, SAo);                                                       \
      RDB(b0, 0, SBo);                                                        \
    }                                                                         \
    STG_A(SAs, 0, tnn_);                                                      \
    MFMAQ(1, 1, aq1, b1);                                                     \
    BARX();                                                                   \
  } while (0)

  // prologue: tile0 fully + tile1 khalf0 (12 loads, chronological order)
  STG_B(sB0, 0, 0); STG_A(sA0, 0, 0);
  STG_B(sB0, 1, 0); STG_A(sA0, 1, 0);
  STG_B(sB1, 0, 1); STG_A(sA1, 0, 1);
  WAITVM(8);                          // retire HB0(0), HA0(0)
  SCHB();
  BARX();
  RDA(aq0, 0, sA0);                   // sub0(0)
  RDB(b0, 0, sB0);                    // nh0(0)

  for (int t = 0; t < NT; t += 2) {   // NT even (K%128==0)
    TILE(sA0, sB0, sA1, sB1, t);
    TILE(sA1, sB1, sA0, sB0, t + 1);
  }
  WAITVM(0);                          // drain tail stages (hygiene)

#undef STG_A
#undef STG_B
#undef RDA
#undef RDB
#undef MFMAQ
#undef TILE

  // epilogue: row-major store bursts — 4 consecutive stores per quad-row
  float bv[4];
#pragma unroll
  for (int nn = 0; nn < 4; ++nn) bv[nn] = bias[n0 + wc * 64 + nn * 16 + l15];
#pragma unroll
  for (int mm = 0; mm < 8; ++mm) {
#pragma unroll
    for (int r = 0; r < 4; ++r) {
      const int m = m0 + wr * 128 + mm * 16 + quad * 4 + r;
      TO* Crow = C + (size_t)m * ldc + n0 + wc * 64 + l15;
#pragma unroll
      for (int nn = 0; nn < 4; ++nn) {
        float v = acc[mm][nn][r] + bv[nn];
        if (EPI == 1) v = gelu_tanh(v);
        Crow[nn * 16] = (TO)v;
      }
    }
  }
}

// ---------------------------------------------------------------------------
// gemm128: round-10 kernel VERBATIM (dual-z = 151 us for both projections).
// ---------------------------------------------------------------------------
template <typename TO>
__global__ __launch_bounds__(256, 2) void gemm128(
    const bf16* __restrict__ A,
    const bf16* __restrict__ B0m, const bf16* __restrict__ B1m,
    const float* __restrict__ bias0, const float* __restrict__ bias1,
    TO* __restrict__ C0, TO* __restrict__ C1, int epi1,
    int K, int lda, int ldb, int ldc) {
  const bf16* Bm = blockIdx.z ? B1m : B0m;
  const float* bias = blockIdx.z ? bias1 : bias0;
  TO* C = blockIdx.z ? C1 : C0;
  const int EPI = blockIdx.z ? epi1 : 0;

  const int gx = gridDim.x, gy = gridDim.y;
  const int nwg = gx * gy;
  const int did = blockIdx.x + gx * blockIdx.y;
  const int cpx = nwg >> 3;                       // chunk per XCD
  const int lid = (did & 7) * cpx + (did >> 3);
  const int n0 = (lid % gx) * 128;
  const int m0 = (lid / gx) * 128;

  __shared__ bf16 sA0[128 * 64];
  __shared__ bf16 sA1[128 * 64];
  __shared__ bf16 sB0[128 * 64];
  __shared__ bf16 sB1[128 * 64];
  const int tid = threadIdx.x;
  const int lane = tid & 63;
  const int wid = tid >> 6;         // 0..3
  const int wr = wid >> 1;          // M-half (64 rows)
  const int wc = wid & 1;           // N-half (64 cols)
  const int quad = lane >> 4;
  const int l15 = lane & 15;

  const int sr = tid >> 3;                        // 0..31
  const int ks8 = ((tid & 7) ^ (sr & 7)) << 3;
  const bf16* Ag = A + (size_t)(m0 + sr) * lda + ks8;
  const bf16* Bg = Bm + (size_t)(n0 + sr) * ldb + ks8;

  const int swz0 = ((quad) ^ (l15 & 7)) << 3;
  const int swz1 = ((4 + quad) ^ (l15 & 7)) << 3;

  f32x4 acc[4][4];
#pragma unroll
  for (int i = 0; i < 4; ++i)
#pragma unroll
    for (int j = 0; j < 4; ++j)
#pragma unroll
      for (int r = 0; r < 4; ++r) acc[i][j][r] = 0.f;

  const int NT = K >> 6;

#define STG_A(ARR, TK)                                                        \
  do {                                                                        \
    _Pragma("unroll") for (int c_ = 0; c_ < 4; ++c_)                          \
        stage16(Ag + (size_t)(c_ * 32) * lda + (size_t)(TK) * 64,             \
                &ARR[(c_ * 32 + wid * 8) * 64]);                              \
  } while (0)
#define STG_B(ARR, TK)                                                        \
  do {                                                                        \
    _Pragma("unroll") for (int c_ = 0; c_ < 4; ++c_)                          \
        stage16(Bg + (size_t)(c_ * 32) * ldb + (size_t)(TK) * 64,             \
                &ARR[(c_ * 32 + wid * 8) * 64]);                              \
  } while (0)

  bf16x8 af[4][2], b0[2][2], b1[2][2];

#define RDA(ARR)                                                              \
  do {                                                                        \
    _Pragma("unroll") for (int mi_ = 0; mi_ < 4; ++mi_) {                     \
      const int arow_ = wr * 64 + mi_ * 16 + l15;                             \
      af[mi_][0] = *(const bf16x8*)(&ARR[arow_ * 64] + swz0);                 \
      af[mi_][1] = *(const bf16x8*)(&ARR[arow_ * 64] + swz1);                 \
    }                                                                         \
  } while (0)
#define RDB(DST, NH, ARR)                                                     \
  do {                                                                        \
    _Pragma("unroll") for (int ni_ = 0; ni_ < 2; ++ni_) {                     \
      const int brow_ = wc * 64 + (NH) * 32 + ni_ * 16 + l15;                 \
      DST[ni_][0] = *(const bf16x8*)(&ARR[brow_ * 64] + swz0);                \
      DST[ni_][1] = *(const bf16x8*)(&ARR[brow_ * 64] + swz1);                \
    }                                                                         \
  } while (0)
#define MFMAQ(NH, BB)                                                         \
  do {                                                                        \
    __builtin_amdgcn_s_setprio(1);                                            \
    _Pragma("unroll") for (int mi_ = 0; mi_ < 4; ++mi_)                       \
        _Pragma("unroll") for (int ni_ = 0; ni_ < 2; ++ni_) {                 \
      acc[mi_][(NH)*2 + ni_] = __builtin_amdgcn_mfma_f32_16x16x32_bf16(       \
          af[mi_][0], BB[ni_][0], acc[mi_][(NH)*2 + ni_], 0, 0, 0);           \
      acc[mi_][(NH)*2 + ni_] = __builtin_amdgcn_mfma_f32_16x16x32_bf16(       \
          af[mi_][1], BB[ni_][1], acc[mi_][(NH)*2 + ni_], 0, 0, 0);           \
    }                                                                         \
    __builtin_amdgcn_s_setprio(0);                                            \
  } while (0)

#define TILE(SAs, SBs, SAo, SBo, T)                                           \
  do {                                                                        \
    const int tn_ = ((T) + 1 < NT) ? (T) + 1 : NT - 1;                        \
    const int tnn_ = ((T) + 2 < NT) ? (T) + 2 : NT - 1;                       \
    /* ph1 */                                                                 \
    RDA(SAs);                                                                 \
    RDB(b0, 0, SBs);                                                          \
    STG_B(SBo, tn_);                                                          \
    MFMAQ(0, b0);                                                             \
    BARX();                                                                   \
    /* ph2 */                                                                 \
    RDB(b1, 1, SBs);                                                          \
    STG_A(SAs, tnn_);                                                         \
    MFMAQ(1, b1);                                                             \
    WAITVM(4);                                                                \
    BARX();                                                                   \
  } while (0)

  // prologue: tiles 0,1 (16 loads, chronological); WAITVM(4) leaves A(1)
  const int t1 = (NT > 1) ? 1 : 0;
  STG_B(sB0, 0); STG_A(sA0, 0);
  STG_B(sB1, t1); STG_A(sA1, t1);
  WAITVM(4);
  SCHB();
  BARX();

  for (int t = 0; t < NT; t += 2) {   // NT even (K%128==0)
    TILE(sA0, sB0, sA1, sB1, t);
    TILE(sA1, sB1, sA0, sB0, t + 1);
  }
  WAITVM(0);                          // drain tail stages (hygiene)

#undef STG_A
#undef STG_B
#undef RDA
#undef RDB
#undef MFMAQ
#undef TILE

  float bv[4];
#pragma unroll
  for (int nn = 0; nn < 4; ++nn) bv[nn] = bias[n0 + wc * 64 + nn * 16 + l15];
#pragma unroll
  for (int mm = 0; mm < 4; ++mm) {
#pragma unroll
    for (int r = 0; r < 4; ++r) {
      const int m = m0 + wr * 64 + mm * 16 + quad * 4 + r;
      TO* Crow = C + (size_t)m * ldc + n0 + wc * 64 + l15;
#pragma unroll
      for (int nn = 0; nn < 4; ++nn) {
        float v = acc[mm][nn][r] + bv[nn];
        if (EPI == 1) v = gelu_tanh(v);
        Crow[nn * 16] = (TO)v;
      }
    }
  }
}

// ---------------------------------------------------------------------------
// gate128: explicit NT=4 schedule VERBATIM (round 17).
// ---------------------------------------------------------------------------
__global__ __launch_bounds__(256, 2) void gate128(
    const bf16* __restrict__ xconv,
    const bf16* __restrict__ gxT, const bf16* __restrict__ gaT,
    bf16* __restrict__ gxr, bf16* __restrict__ gar) {
  const int h = blockIdx.z >> 1;
  const int g = blockIdx.z & 1;
  const bf16* A = xconv + h * DHD;                           // lda = DDIM
  const bf16* Bm = (g ? gaT : gxT) + (size_t)h * DHD * DHD;  // ldb = DHD
  bf16* C = (g ? gar : gxr) + h * DHD;                       // ldc = DDIM

  const int gx = gridDim.x, gy = gridDim.y;
  const int nwg = gx * gy;                        // 128, %8==0
  const int did = blockIdx.x + gx * blockIdx.y;
  const int cpx = nwg >> 3;
  const int lid = (did & 7) * cpx + (did >> 3);
  const int n0 = (lid % gx) * 128;
  const int m0 = (lid / gx) * 128;

  __shared__ bf16 sA0[128 * 64];
  __shared__ bf16 sA1[128 * 64];
  __shared__ bf16 sB0[128 * 64];
  __shared__ bf16 sB1[128 * 64];
  const int tid = threadIdx.x;
  const int lane = tid & 63;
  const int wid = tid >> 6;
  const int wr = wid >> 1;
  const int wc = wid & 1;
  const int quad = lane >> 4;
  const int l15 = lane & 15;

  const int sr = tid >> 3;
  const int ks8 = ((tid & 7) ^ (sr & 7)) << 3;
  const bf16* Ag = A + (size_t)(m0 + sr) * DDIM + ks8;
  const bf16* Bg = Bm + (size_t)(n0 + sr) * DHD + ks8;

  const int swz0 = ((quad) ^ (l15 & 7)) << 3;
  const int swz1 = ((4 + quad) ^ (l15 & 7)) << 3;

  f32x4 acc[4][4];
#pragma unroll
  for (int i = 0; i < 4; ++i)
#pragma unroll
    for (int j = 0; j < 4; ++j)
#pragma unroll
      for (int r = 0; r < 4; ++r) acc[i][j][r] = 0.f;

#define STG_A(ARR, TK)                                                        \
  do {                                                                        \
    _Pragma("unroll") for (int c_ = 0; c_ < 4; ++c_)                          \
        stage16(Ag + (size_t)(c_ * 32) * DDIM + (size_t)(TK) * 64,            \
                &ARR[(c_ * 32 + wid * 8) * 64]);                              \
  } while (0)
#define STG_B(ARR, TK)                                                        \
  do {                                                                        \
    _Pragma("unroll") for (int c_ = 0; c_ < 4; ++c_)                          \
        stage16(Bg + (size_t)(c_ * 32) * DHD + (size_t)(TK) * 64,             \
                &ARR[(c_ * 32 + wid * 8) * 64]);                              \
  } while (0)

  bf16x8 af[4][2], b0[2][2], b1[2][2];

#define RDA(ARR)                                                              \
  do {                                                                        \
    _Pragma("unroll") for (int mi_ = 0; mi_ < 4; ++mi_) {                     \
      const int arow_ = wr * 64 + mi_ * 16 + l15;                             \
      af[mi_][0] = *(const bf16x8*)(&ARR[arow_ * 64] + swz0);                 \
      af[mi_][1] = *(const bf16x8*)(&ARR[arow_ * 64] + swz1);                 \
    }                                                                         \
  } while (0)
#define RDB(DST, NH, ARR)                                                     \
  do {                                                                        \
    _Pragma("unroll") for (int ni_ = 0; ni_ < 2; ++ni_) {                     \
      const int brow_ = wc * 64 + (NH) * 32 + ni_ * 16 + l15;                 \
      DST[ni_][0] = *(const bf16x8*)(&ARR[brow_ * 64] + swz0);                \
      DST[ni_][1] = *(const bf16x8*)(&ARR[brow_ * 64] + swz1);                \
    }                                                                         \
  } while (0)
#define MFMAQ(NH, BB)                                                         \
  do {                                                                        \
    __builtin_amdgcn_s_setprio(1);                                            \
    _Pragma("unroll") for (int mi_ = 0; mi_ < 4; ++mi_)                       \
        _Pragma("unroll") for (int ni_ = 0; ni_ < 2; ++ni_) {                 \
      acc[mi_][(NH)*2 + ni_] = __builtin_amdgcn_mfma_f32_16x16x32_bf16(       \
          af[mi_][0], BB[ni_][0], acc[mi_][(NH)*2 + ni_], 0, 0, 0);           \
      acc[mi_][(NH)*2 + ni_] = __builtin_amdgcn_mfma_f32_16x16x32_bf16(       \
          af[mi_][1], BB[ni_][1], acc[mi_][(NH)*2 + ni_], 0, 0, 0);           \
    }                                                                         \
    __builtin_amdgcn_s_setprio(0);                                            \
  } while (0)

  // prologue: tiles 0,1 fully staged
  STG_B(sB0, 0); STG_A(sA0, 0);
  STG_B(sB1, 1); STG_A(sA1, 1);
  WAITVM(8);                         // retire B0,A0 -> tile0 readable
  SCHB();
  BARX();
  // ---- t0 (buf0) ----
  RDA(sA0); RDB(b0, 0, sB0);
  MFMAQ(0, b0);
  BARX();
  RDB(b1, 1, sB0);
  STG_A(sA0, 2);                     // A2 (buf0 A reads done ph1)
  MFMAQ(1, b1);
  WAITVM(4);                         // retire B1,A1 -> tile1 certified
  BARX();
  // ---- t1 (buf1) ----
  RDA(sA1); RDB(b0, 0, sB1);
  STG_B(sB0, 2);                     // B2 (buf0 B reads done t0)
  MFMAQ(0, b0);
  BARX();
  RDB(b1, 1, sB1);
  STG_A(sA1, 3);                     // A3 (buf1 A reads done ph1)
  MFMAQ(1, b1);
  WAITVM(4);                         // retire A2,B2 -> tile2 certified
  BARX();
  // ---- t2 (buf0) ----
  RDA(sA0); RDB(b0, 0, sB0);
  STG_B(sB1, 3);                     // B3 (buf1 B reads done t1)
  MFMAQ(0, b0);
  BARX();
  RDB(b1, 1, sB0);
  MFMAQ(1, b1);
  WAITVM(0);                         // retire A3,B3 -> tile3 certified
  BARX();
  // ---- t3 (buf1) ----
  RDA(sA1); RDB(b0, 0, sB1);
  MFMAQ(0, b0);
  BARX();
  RDB(b1, 1, sB1);
  MFMAQ(1, b1);

#undef STG_A
#undef STG_B
#undef RDA
#undef RDB
#undef MFMAQ

#pragma unroll
  for (int mm = 0; mm < 4; ++mm) {
#pragma unroll
    for (int r = 0; r < 4; ++r) {
      const int m = m0 + wr * 64 + mm * 16 + quad * 4 + r;
      bf16* Crow = C + (size_t)m * DDIM + n0 + wc * 64 + l15;
#pragma unroll
      for (int nn = 0; nn < 4; ++nn)
        Crow[nn * 16] = (bf16)acc[mm][nn][r];
    }
  }
}

// ---------------------------------------------------------------------------
// depthwise causal conv, TW=4 (blocks 0..8191) + Wout f2b rider (1024 blocks,
// 16 elems/thread; WB1 dead after the dual projection GEMM). Weights as
// float4 pairs (G13).
// ---------------------------------------------------------------------------
__global__ __launch_bounds__(256) void conv_kernel(
    const bf16* __restrict__ xp, const float* __restrict__ cw,
    const float* __restrict__ cb, const int* __restrict__ segp,
    bf16* __restrict__ xc,
    const float* __restrict__ Wout, bf16* __restrict__ WB1) {
  if (blockIdx.x >= 8192) {
    f2b_body16(Wout, WB1, blockIdx.x - 8192);
    return;
  }
  int v = blockIdx.x * 256 + threadIdx.x;
  int dv = v & (DDIM / 8 - 1);
  int m = v >> 8;
  int d0 = dv * 8;
  int t = m & (TDIM - 1);
  int sp = segp[m];
  float acc[8];
  {
    const float4 c0 = *(const float4*)(cb + d0);
    const float4 c1 = *(const float4*)(cb + d0 + 4);
    acc[0] = c0.x; acc[1] = c0.y; acc[2] = c0.z; acc[3] = c0.w;
    acc[4] = c1.x; acc[5] = c1.y; acc[6] = c1.z; acc[7] = c1.w;
  }
#pragma unroll
  for (int i = 0; i < 4; ++i) {
    int shift = 3 - i;
    if (t >= shift && sp >= shift) {
      bf16x8 xv = *(const bf16x8*)&xp[(size_t)(m - shift) * DDIM + d0];
      const float4 w0 = *(const float4*)(cw + i * DDIM + d0);
      const float4 w1 = *(const float4*)(cw + i * DDIM + d0 + 4);
      acc[0] = fmaf((float)xv[0], w0.x, acc[0]);
      acc[1] = fmaf((float)xv[1], w0.y, acc[1]);
      acc[2] = fmaf((float)xv[2], w0.z, acc[2]);
      acc[3] = fmaf((float)xv[3], w0.w, acc[3]);
      acc[4] = fmaf((float)xv[4], w1.x, acc[4]);
      acc[5] = fmaf((float)xv[5], w1.y, acc[5]);
      acc[6] = fmaf((float)xv[6], w1.z, acc[6]);
      acc[7] = fmaf((float)xv[7], w1.w, acc[7]);
    }
  }
  bf16x8 o;
#pragma unroll
  for (int j = 0; j < 8; ++j) o[j] = (bf16)acc[j];
  *(bf16x8*)&xc[(size_t)m * DDIM + d0] = o;
}

// ---------------------------------------------------------------------------
// RG-LRU elementwise recompute, shared by scan phases
// ---------------------------------------------------------------------------
__device__ __forceinline__ void lru_elem(float pgx, float pga, float xc,
                                         float spv, bool reset,
                                         float& a, float& nr) {
  const float gx = sigmoid_f(pgx);
  const float ga = sigmoid_f(pga);
  const float la = -8.f * ga * spv;
  a = reset ? 0.f : __expf(la);
  const float mult = reset ? 1.f : sqrtf(fmaxf(1.f - __expf(2.f * la), 0.f));
  nr = xc * gx * mult;
}

// chunked scan phase 1 — VEC=4, LCHUNK=16 -> 1024 blocks = 4 blocks/CU
__global__ __launch_bounds__(256) void scan_phase1(
    const bf16* __restrict__ gxr, const bf16* __restrict__ gar,
    const bf16* __restrict__ xconv,
    const float* __restrict__ gxb, const float* __restrict__ gab,
    const float* __restrict__ apar, const int* __restrict__ segp,
    float* __restrict__ chA, float* __restrict__ chH) {
  int idx = blockIdx.x * 256 + threadIdx.x;     // B*NCHUNK*(DDIM/4) = 262144
  int dv = idx & (DDIM / 4 - 1);
  int c = (idx >> 9) & (NCHUNK - 1);
  int b = idx >> 16;
  int d0 = dv * 4;
  const float4 gx4 = *(const float4*)(gxb + d0);
  const float4 ga4 = *(const float4*)(gab + d0);
  const float4 ap4 = *(const float4*)(apar + d0);
  float gxbv[4] = {gx4.x, gx4.y, gx4.z, gx4.w};
  float gabv[4] = {ga4.x, ga4.y, ga4.z, ga4.w};
  float spv[4]  = {softplus_f(ap4.x), softplus_f(ap4.y),
                   softplus_f(ap4.z), softplus_f(ap4.w)};
  const int mrow = b * TDIM + c * LCHUNK;
  size_t base = (size_t)mrow * DDIM + d0;
  float A[4] = {1.f, 1.f, 1.f, 1.f}, hh[4] = {0.f, 0.f, 0.f, 0.f};
  for (int i = 0; i < LCHUNK; ++i) {
    size_t o = base + (size_t)i * DDIM;
    bf16x4 g1 = *(const bf16x4*)&gxr[o];
    bf16x4 g2 = *(const bf16x4*)&gar[o];
    bf16x4 xv = *(const bf16x4*)&xconv[o];
    bool rst = (segp[mrow + i] == 0);
#pragma unroll
    for (int j = 0; j < 4; ++j) {
      float a, nr;
      lru_elem((float)g1[j] + gxbv[j], (float)g2[j] + gabv[j], (float)xv[j],
               spv[j], rst, a, nr);
      hh[j] = fmaf(a, hh[j], nr);
      A[j] *= a;
    }
  }
  size_t ci = (size_t)(b * NCHUNK + c) * DDIM + d0;
  *(f32x4*)&chA[ci] = f32x4{A[0], A[1], A[2], A[3]};
  *(f32x4*)&chH[ci] = f32x4{hh[0], hh[1], hh[2], hh[3]};
}

__global__ __launch_bounds__(256) void scan_phase2(
    const float* __restrict__ chA, const float* __restrict__ chH,
    float* __restrict__ hst) {
  int idx = blockIdx.x * 64 + threadIdx.x;   // 64-thread blocks -> 128 CUs
  int d = idx & (DDIM - 1);
  int b = idx >> 11;
  float s = 0.f;
  for (int c = 0; c < NCHUNK; ++c) {
    int ci = (b * NCHUNK + c) * DDIM + d;
    hst[ci] = s;
    s = fmaf(chA[ci], s, chH[ci]);
  }
}

// phase 3 — VEC=4, LCHUNK=16: replay with chunk-start state; z = h*y over y
__global__ __launch_bounds__(256) void scan_phase3(
    const bf16* __restrict__ gxr, const bf16* __restrict__ gar,
    const bf16* __restrict__ xconv,
    const float* __restrict__ gxb, const float* __restrict__ gab,
    const float* __restrict__ apar, const int* __restrict__ segp,
    const float* __restrict__ hst, bf16* __restrict__ yz) {
  int idx = blockIdx.x * 256 + threadIdx.x;
  int dv = idx & (DDIM / 4 - 1);
  int c = (idx >> 9) & (NCHUNK - 1);
  int b = idx >> 16;
  int d0 = dv * 4;
  const float4 gx4 = *(const float4*)(gxb + d0);
  const float4 ga4 = *(const float4*)(gab + d0);
  const float4 ap4 = *(const float4*)(apar + d0);
  float gxbv[4] = {gx4.x, gx4.y, gx4.z, gx4.w};
  float gabv[4] = {ga4.x, ga4.y, ga4.z, ga4.w};
  float spv[4]  = {softplus_f(ap4.x), softplus_f(ap4.y),
                   softplus_f(ap4.z), softplus_f(ap4.w)};
  const int mrow = b * TDIM + c * LCHUNK;
  size_t base = (size_t)mrow * DDIM + d0;
  size_t ci = (size_t)(b * NCHUNK + c) * DDIM + d0;
  const float4 h4 = *(const float4*)(hst + ci);
  float hh[4] = {h4.x, h4.y, h4.z, h4.w};
  for (int i = 0; i < LCHUNK; ++i) {
    size_t o = base + (size_t)i * DDIM;
    bf16x4 g1 = *(const bf16x4*)&gxr[o];
    bf16x4 g2 = *(const bf16x4*)&gar[o];
    bf16x4 xv = *(const bf16x4*)&xconv[o];
    bf16x4 y4 = *(const bf16x4*)&yz[o];
    bool rst = (segp[mrow + i] == 0);
    bf16x4 out;
#pragma unroll
    for (int j = 0; j < 4; ++j) {
      float a, nr;
      lru_elem((float)g1[j] + gxbv[j], (float)g2[j] + gabv[j], (float)xv[j],
               spv[j], rst, a, nr);
      hh[j] = fmaf(a, hh[j], nr);
      out[j] = (bf16)(hh[j] * (float)y4[j]);
    }
    *(bf16x4*)&yz[o] = out;
  }
}

// ---------------------------------------------------------------------------
extern "C" void kernel_launch(void* const* d_in, const int* in_sizes, int n_in,
                              void* d_out, int out_size, void* d_ws, size_t ws_size,
                              hipStream_t stream) {
  const float* x    = (const float*)d_in[0];
  const int*   segp = (const int*)d_in[1];
  const float* Wy   = (const float*)d_in[2];
  const float* by   = (const float*)d_in[3];
  const float* Wx   = (const float*)d_in[4];
  const float* bx   = (const float*)d_in[5];
  const float* cw   = (const float*)d_in[6];
  const float* cb   = (const float*)d_in[7];
  const float* gxw  = (const float*)d_in[8];
  const float* gxb  = (const float*)d_in[9];
  const float* gaw  = (const float*)d_in[10];
  const float* gab  = (const float*)d_in[11];
  const float* apar = (const float*)d_in[12];
  const float* Wout = (const float*)d_in[13];
  const float* bout = (const float*)d_in[14];

  const size_t MD = (size_t)MTOT * DDIM;       // 16.78M elements
  const size_t WD = (size_t)DDIM * DDIM;       // 4.19M elements
  // d_out (fp32, 67 MB) as bf16 scratch until the final GEMM:
  bf16* xb    = (bf16*)d_out;                   // lower: xb -> xconv
  bf16* xproj = (bf16*)((char*)d_out + MD * 2); // upper: xproj -> gxr
  bf16* xconv = xb;
  bf16* gxr   = xproj;

  // ws layout: gar | W1 | WB1 | WB2(-> chA|chH after dual GEMM) | gxT gaT hst
  char* ws = (char*)d_ws;
  bf16*  gar = (bf16*)ws;                        // 33.5 MB
  bf16*  W1  = (bf16*)(ws + MD * 2);             // y -> z (33.5 MB)
  bf16*  WB1 = (bf16*)(ws + 2 * MD * 2);         // Wxb, later Woutb (8.4 MB)
  bf16*  WB2 = (bf16*)(ws + 2 * MD * 2 + WD * 2);// Wyb; dead after dual GEMM
  char*  tail = ws + 2 * MD * 2 + 2 * WD * 2;
  const size_t GW = (size_t)HDIM * DHD * DHD * 2;      // 1 MiB
  const size_t CH = (size_t)BDIM * NCHUNK * DDIM * 4;  // 4 MiB (LCHUNK=16)
  bf16*  gxT = (bf16*)tail;
  bf16*  gaT = (bf16*)(tail + GW);
  float* hst = (float*)(tail + 2 * GW);                // 4 MiB
  // chA/chH overlay the dead WB2 region (2*CH = 8 MiB == WD*2 bytes)
  float* chA = (float*)WB2;
  float* chH = (float*)((char*)WB2 + CH);

  dim3 blk(256);
  // fused prep: x + Wx + Wy conversions (16 elem/thread) + transpose rider
  f2b3t<<<dim3(7168), blk, 0, stream>>>(x, xb, Wx, WB1, Wy, WB2,
                                        gxw, gaw, gxT, gaT);

  // DUAL GEMM (z=0: xproj = x@Wx^T+bx ; z=1: y = gelu(x@Wy^T+by)) —
  // measured 151 us for both (rounds 10-17, MfmaUtil 41%).
  gemm128<bf16><<<dim3(16, 64, 2), blk, 0, stream>>>(
      xb, WB1, WB2, bx, by, xproj, W1, 1, DDIM, DDIM, DDIM, DDIM);

  // conv (xconv in-place over xb) + Wout->WB1 f2b rider (WB1 dead here)
  conv_kernel<<<dim3(8192 + 1024), blk, 0, stream>>>(
      xproj, cw, cb, segp, xconv, Wout, WB1);

  // gate pre-activations, explicit NT=4 schedule (no redundant tail stages)
  gate128<<<dim3(2, 64, 16), blk, 0, stream>>>(xconv, gxT, gaT, gxr, gar);

  // chunked scan, VEC=4, LCHUNK=16 (1024 blocks = 4 blocks/CU for ph1/3)
  scan_phase1<<<dim3(BDIM * NCHUNK * (DDIM / 4) / 256), blk, 0, stream>>>(
      gxr, gar, xconv, gxb, gab, apar, segp, chA, chH);
  scan_phase2<<<dim3(BDIM * DDIM / 64), dim3(64), 0, stream>>>(chA, chH, hst);
  scan_phase3<<<dim3(BDIM * NCHUNK * (DDIM / 4) / 256), blk, 0, stream>>>(
      gxr, gar, xconv, gxb, gab, apar, segp, hst, W1);

  // out = z @ Wout^T + bout — round-7 gemm256 (measured 77.5-86 us warm)
  gemm256<float, 0><<<dim3(8, 32), dim3(512), 0, stream>>>(
      W1, WB1, bout, (float*)d_out, DDIM, DDIM, DDIM, DDIM);
}